// Round 1
// baseline (416.657 us; speedup 1.0000x reference)
//
#include <hip/hip_runtime.h>

typedef __bf16 bf16x8 __attribute__((ext_vector_type(8)));
typedef float  f32x4  __attribute__((ext_vector_type(4)));
typedef unsigned short ushortx8 __attribute__((ext_vector_type(8)));

static __device__ __forceinline__ unsigned short f2bf(float f) {
  unsigned int u = __builtin_bit_cast(unsigned int, f);
  u += 0x7FFFu + ((u >> 16) & 1u);
  return (unsigned short)(u >> 16);
}
static __device__ __forceinline__ float bf2f(unsigned short h) {
  unsigned int u = ((unsigned int)h) << 16;
  return __builtin_bit_cast(float, u);
}

// ---------------- cast X fp32 -> bf16 ----------------
__global__ __launch_bounds__(256) void cast_x_kernel(const float* __restrict__ x,
                                                     unsigned short* __restrict__ o) {
  long i = ((long)blockIdx.x * 256 + threadIdx.x) * 8;
  float4 f0 = *(const float4*)(x + i);
  float4 f1 = *(const float4*)(x + i + 4);
  ushortx8 u;
  u[0] = f2bf(f0.x); u[1] = f2bf(f0.y); u[2] = f2bf(f0.z); u[3] = f2bf(f0.w);
  u[4] = f2bf(f1.x); u[5] = f2bf(f1.y); u[6] = f2bf(f1.z); u[7] = f2bf(f1.w);
  *(ushortx8*)(o + i) = u;
}

// ---------------- transpose (+cast) : src [R][C] -> dst [C][R] bf16 ----------------
static __device__ __forceinline__ unsigned short to_bf(float v) { return f2bf(v); }
static __device__ __forceinline__ unsigned short to_bf(unsigned short v) { return v; }

template <typename SrcT>
__global__ __launch_bounds__(256) void tpose_kernel(const SrcT* __restrict__ src,
                                                    unsigned short* __restrict__ dst,
                                                    int R, int C) {
  size_t moff = (size_t)blockIdx.z * (size_t)R * (size_t)C;
  src += moff; dst += moff;
  __shared__ unsigned short t[32][33];
  int c = blockIdx.x * 32 + threadIdx.x;
#pragma unroll
  for (int i = 0; i < 4; ++i) {
    int r = blockIdx.y * 32 + threadIdx.y + i * 8;
    t[threadIdx.y + i * 8][threadIdx.x] = to_bf(src[(size_t)r * C + c]);
  }
  __syncthreads();
  int rr = blockIdx.y * 32 + threadIdx.x;
#pragma unroll
  for (int i = 0; i < 4; ++i) {
    int cc = blockIdx.x * 32 + threadIdx.y + i * 8;
    dst[(size_t)cc * R + rr] = t[threadIdx.x][threadIdx.y + i * 8];
  }
}

// ---------------- GEMM: C[M=4096][N=1024] = A(bf16 [M][K=1024]) * B (BT bf16 [N][K]) ----------------
// MODE 0: write fp32 to outF row-major. MODE 1: write bf16 q/k/v in [B,NH,S,HD], select by blockIdx.z.
template <int MODE>
__global__ __launch_bounds__(256) void gemm_kernel(
    const unsigned short* __restrict__ A,
    const unsigned short* __restrict__ BT0,
    const unsigned short* __restrict__ BT1,
    const unsigned short* __restrict__ BT2,
    float* __restrict__ outF,
    unsigned short* __restrict__ outQ,
    unsigned short* __restrict__ outK,
    unsigned short* __restrict__ outV) {
  const int K = 1024, N = 1024;
  int z = blockIdx.z;
  const unsigned short* BT = (MODE == 0 || z == 0) ? BT0 : (z == 1 ? BT1 : BT2);
  int m0 = blockIdx.y * 64, n0 = blockIdx.x * 64;
  int t = threadIdx.x;
  int lane = t & 63;
  int wave = t >> 6;
  int wy = wave >> 1, wx = wave & 1;
  int n16 = lane & 15, quad = lane >> 4;
  __shared__ __align__(16) unsigned short sA[64 * 40];  // +8 pad breaks bank stride
  __shared__ __align__(16) unsigned short sB[64 * 40];
  int srow = t >> 2, schunk = t & 3;
  const unsigned short* gA = A + (size_t)(m0 + srow) * K + schunk * 8;
  const unsigned short* gB = BT + (size_t)(n0 + srow) * K + schunk * 8;
  f32x4 acc[2][2];
#pragma unroll
  for (int i = 0; i < 2; ++i)
#pragma unroll
    for (int j = 0; j < 2; ++j) acc[i][j] = f32x4{0.f, 0.f, 0.f, 0.f};

  for (int kk = 0; kk < K; kk += 32) {
    __syncthreads();
    *(uint4*)(&sA[srow * 40 + schunk * 8]) = *(const uint4*)(gA + kk);
    *(uint4*)(&sB[srow * 40 + schunk * 8]) = *(const uint4*)(gB + kk);
    __syncthreads();
    bf16x8 a[2], b[2];
    a[0] = *(const bf16x8*)(&sA[(wy * 32 + n16) * 40 + quad * 8]);
    a[1] = *(const bf16x8*)(&sA[(wy * 32 + 16 + n16) * 40 + quad * 8]);
    b[0] = *(const bf16x8*)(&sB[(wx * 32 + n16) * 40 + quad * 8]);
    b[1] = *(const bf16x8*)(&sB[(wx * 32 + 16 + n16) * 40 + quad * 8]);
#pragma unroll
    for (int mt = 0; mt < 2; ++mt)
#pragma unroll
      for (int nt = 0; nt < 2; ++nt)
        acc[mt][nt] = __builtin_amdgcn_mfma_f32_16x16x32_bf16(a[mt], b[nt], acc[mt][nt], 0, 0, 0);
  }

#pragma unroll
  for (int mt = 0; mt < 2; ++mt)
#pragma unroll
    for (int nt = 0; nt < 2; ++nt)
#pragma unroll
      for (int r = 0; r < 4; ++r) {
        int row = m0 + wy * 32 + mt * 16 + quad * 4 + r;
        int col = n0 + wx * 32 + nt * 16 + n16;
        float v = acc[mt][nt][r];
        if (MODE == 0) {
          outF[(size_t)row * N + col] = v;
        } else {
          unsigned short* dst = (z == 0) ? outQ : (z == 1 ? outK : outV);
          int b = row >> 11, s = row & 2047, h = col >> 6, d = col & 63;
          dst[(((size_t)b * 16 + h) * 2048 + s) * 64 + d] = f2bf(v);
        }
      }
}

// ---------------- RoPE in-place on Q,K (bf16, [B,NH,S,HD]) ----------------
__global__ __launch_bounds__(256) void rope_kernel(unsigned short* __restrict__ Q,
                                                   unsigned short* __restrict__ Kk,
                                                   const int* __restrict__ pos_ids,
                                                   const float* __restrict__ cosb,
                                                   const float* __restrict__ sinb) {
  int tid = blockIdx.x * 256 + threadIdx.x;  // 2*16*2048*32 threads
  int d = tid & 31;
  int s = (tid >> 5) & 2047;
  int bh = tid >> 16;
  int b = bh >> 4;
  size_t base = ((size_t)bh * 2048 + s) * 64;
  int pos = pos_ids[b * 2048 + s];
  float c0 = cosb[pos * 64 + d], s0 = sinb[pos * 64 + d];
  float c1 = cosb[pos * 64 + d + 32], s1 = sinb[pos * 64 + d + 32];
  {
    float x0 = bf2f(Q[base + d]), x1 = bf2f(Q[base + d + 32]);
    Q[base + d] = f2bf(x0 * c0 - x1 * s0);
    Q[base + d + 32] = f2bf(x1 * c1 + x0 * s1);
  }
  {
    float x0 = bf2f(Kk[base + d]), x1 = bf2f(Kk[base + d + 32]);
    Kk[base + d] = f2bf(x0 * c0 - x1 * s0);
    Kk[base + d + 32] = f2bf(x1 * c1 + x0 * s1);
  }
}

// ---------------- Flash attention: 1 wave per (bh, 32-row q-tile) ----------------
// Q,K bf16 [B*NH, S, 64]; VT bf16 [B*NH, 64, S]; O bf16 [B*S, NH*64]
__global__ __launch_bounds__(64) void attn_kernel(const unsigned short* __restrict__ Q,
                                                  const unsigned short* __restrict__ Kk,
                                                  const unsigned short* __restrict__ VT,
                                                  unsigned short* __restrict__ O) {
  int qt = blockIdx.x;  // 0..63
  int bh = blockIdx.y;  // 0..31
  int lane = threadIdx.x;
  int n16 = lane & 15, quad = lane >> 4;
  const unsigned short* Qb = Q + (size_t)bh * 2048 * 64;
  const unsigned short* Kb = Kk + (size_t)bh * 2048 * 64;
  const unsigned short* Vb = VT + (size_t)bh * 64 * 2048;

  bf16x8 aQ[2][2];
#pragma unroll
  for (int mt = 0; mt < 2; ++mt)
#pragma unroll
    for (int kb = 0; kb < 2; ++kb)
      aQ[mt][kb] = *(const bf16x8*)(Qb + (size_t)(qt * 32 + mt * 16 + n16) * 64 + kb * 32 + quad * 8);

  f32x4 o[2][4];
  float mst[2][4], lst[2][4];
#pragma unroll
  for (int mt = 0; mt < 2; ++mt) {
#pragma unroll
    for (int ct = 0; ct < 4; ++ct) o[mt][ct] = f32x4{0.f, 0.f, 0.f, 0.f};
#pragma unroll
    for (int r = 0; r < 4; ++r) { mst[mt][r] = -1e30f; lst[mt][r] = 0.f; }
  }

  __shared__ __align__(16) unsigned short sp[32 * 32];

  for (int kt = 0; kt <= qt; ++kt) {
    bf16x8 bK[2][2];
#pragma unroll
    for (int ns = 0; ns < 2; ++ns)
#pragma unroll
      for (int kb = 0; kb < 2; ++kb)
        bK[ns][kb] = *(const bf16x8*)(Kb + (size_t)(kt * 32 + ns * 16 + n16) * 64 + kb * 32 + quad * 8);

    f32x4 sc[2][2];
#pragma unroll
    for (int mt = 0; mt < 2; ++mt)
#pragma unroll
      for (int ns = 0; ns < 2; ++ns) {
        f32x4 z0 = f32x4{0.f, 0.f, 0.f, 0.f};
        z0 = __builtin_amdgcn_mfma_f32_16x16x32_bf16(aQ[mt][0], bK[ns][0], z0, 0, 0, 0);
        sc[mt][ns] = __builtin_amdgcn_mfma_f32_16x16x32_bf16(aQ[mt][1], bK[ns][1], z0, 0, 0, 0);
      }

    bool diag = (kt == qt);
#pragma unroll
    for (int mt = 0; mt < 2; ++mt) {
#pragma unroll
      for (int r = 0; r < 4; ++r) {
        float s0 = sc[mt][0][r] * 0.125f;
        float s1 = sc[mt][1][r] * 0.125f;
        if (diag) {
          int rg = mt * 16 + quad * 4 + r;
          if (n16 > rg) s0 = -3e38f;
          if (16 + n16 > rg) s1 = -3e38f;
        }
        float rm = fmaxf(s0, s1);
#pragma unroll
        for (int off = 1; off < 16; off <<= 1) rm = fmaxf(rm, __shfl_xor(rm, off));
        float mn = fmaxf(mst[mt][r], rm);
        float al = __expf(mst[mt][r] - mn);
        float p0 = __expf(s0 - mn), p1 = __expf(s1 - mn);
        float rs = p0 + p1;
#pragma unroll
        for (int off = 1; off < 16; off <<= 1) rs += __shfl_xor(rs, off);
        lst[mt][r] = lst[mt][r] * al + rs;
        mst[mt][r] = mn;
#pragma unroll
        for (int ct = 0; ct < 4; ++ct) o[mt][ct][r] *= al;
        sp[(mt * 16 + quad * 4 + r) * 32 + n16] = f2bf(p0);
        sp[(mt * 16 + quad * 4 + r) * 32 + 16 + n16] = f2bf(p1);
      }
    }
    __syncthreads();
    bf16x8 aP[2];
    aP[0] = *(const bf16x8*)(&sp[(size_t)n16 * 32 + quad * 8]);
    aP[1] = *(const bf16x8*)(&sp[(size_t)(16 + n16) * 32 + quad * 8]);
    bf16x8 bV[4];
#pragma unroll
    for (int ct = 0; ct < 4; ++ct)
      bV[ct] = *(const bf16x8*)(Vb + (size_t)(ct * 16 + n16) * 2048 + kt * 32 + quad * 8);
#pragma unroll
    for (int mt = 0; mt < 2; ++mt)
#pragma unroll
      for (int ct = 0; ct < 4; ++ct)
        o[mt][ct] = __builtin_amdgcn_mfma_f32_16x16x32_bf16(aP[mt], bV[ct], o[mt][ct], 0, 0, 0);
    __syncthreads();
  }

  int b = bh >> 4, h = bh & 15;
#pragma unroll
  for (int mt = 0; mt < 2; ++mt)
#pragma unroll
    for (int ct = 0; ct < 4; ++ct)
#pragma unroll
      for (int r = 0; r < 4; ++r) {
        int s_ = qt * 32 + mt * 16 + quad * 4 + r;
        float v = o[mt][ct][r] / lst[mt][r];
        O[((size_t)b * 2048 + s_) * 1024 + h * 64 + ct * 16 + n16] = f2bf(v);
      }
}

// ---------------- launch ----------------
extern "C" void kernel_launch(void* const* d_in, const int* in_sizes, int n_in,
                              void* d_out, int out_size, void* d_ws, size_t ws_size,
                              hipStream_t stream) {
  const float* X    = (const float*)d_in[0];
  // d_in[1] = attention_mask (pure causal; implemented structurally)
  const int*   pos  = (const int*)d_in[2];
  const float* cosb = (const float*)d_in[3];
  const float* sinb = (const float*)d_in[4];
  const float* Wq   = (const float*)d_in[5];
  const float* Wk   = (const float*)d_in[6];
  const float* Wv   = (const float*)d_in[7];
  const float* Wo   = (const float*)d_in[8];
  float* out = (float*)d_out;

  char* ws = (char*)d_ws;
  const size_t SZ_X   = 4096UL * 1024 * 2;   // 8 MiB bf16
  const size_t SZ_W   = 1024UL * 1024 * 2;   // 2 MiB bf16
  unsigned short* Xbf = (unsigned short*)(ws);
  unsigned short* WTq = (unsigned short*)(ws + SZ_X);
  unsigned short* WTk = (unsigned short*)(ws + SZ_X + SZ_W);
  unsigned short* WTv = (unsigned short*)(ws + SZ_X + 2 * SZ_W);
  unsigned short* WTo = (unsigned short*)(ws + SZ_X + 3 * SZ_W);
  unsigned short* Qbf = (unsigned short*)(ws + SZ_X + 4 * SZ_W);
  unsigned short* Kbf = (unsigned short*)(ws + 2 * SZ_X + 4 * SZ_W);
  unsigned short* Vbf = (unsigned short*)(ws + 3 * SZ_X + 4 * SZ_W);
  unsigned short* VTr = (unsigned short*)(ws + 4 * SZ_X + 4 * SZ_W);
  unsigned short* Obf = (unsigned short*)(ws + 5 * SZ_X + 4 * SZ_W);

  dim3 tb(32, 8);

  cast_x_kernel<<<2048, 256, 0, stream>>>(X, Xbf);
  tpose_kernel<float><<<dim3(32, 32, 1), tb, 0, stream>>>(Wq, WTq, 1024, 1024);
  tpose_kernel<float><<<dim3(32, 32, 1), tb, 0, stream>>>(Wk, WTk, 1024, 1024);
  tpose_kernel<float><<<dim3(32, 32, 1), tb, 0, stream>>>(Wv, WTv, 1024, 1024);
  tpose_kernel<float><<<dim3(32, 32, 1), tb, 0, stream>>>(Wo, WTo, 1024, 1024);

  gemm_kernel<1><<<dim3(16, 64, 3), 256, 0, stream>>>(Xbf, WTq, WTk, WTv,
                                                      nullptr, Qbf, Kbf, Vbf);

  rope_kernel<<<8192, 256, 0, stream>>>(Qbf, Kbf, pos, cosb, sinb);

  tpose_kernel<unsigned short><<<dim3(2, 64, 32), tb, 0, stream>>>(Vbf, VTr, 2048, 64);

  attn_kernel<<<dim3(64, 32), 64, 0, stream>>>(Qbf, Kbf, VTr, Obf);

  gemm_kernel<0><<<dim3(16, 64, 1), 256, 0, stream>>>(Obf, WTo, nullptr, nullptr,
                                                      out, nullptr, nullptr, nullptr);
}

// Round 2
// 308.806 us; speedup vs baseline: 1.3493x; 1.3493x over previous
//
#include <hip/hip_runtime.h>

typedef __bf16 bf16x8 __attribute__((ext_vector_type(8)));
typedef float  f32x4  __attribute__((ext_vector_type(4)));
typedef unsigned short ushortx8 __attribute__((ext_vector_type(8)));

static __device__ __forceinline__ unsigned short f2bf(float f) {
  unsigned int u = __builtin_bit_cast(unsigned int, f);
  u += 0x7FFFu + ((u >> 16) & 1u);
  return (unsigned short)(u >> 16);
}
static __device__ __forceinline__ float bf2f(unsigned short h) {
  unsigned int u = ((unsigned int)h) << 16;
  return __builtin_bit_cast(float, u);
}

// ---------------- cast X fp32 -> bf16 ----------------
__global__ __launch_bounds__(256) void cast_x_kernel(const float* __restrict__ x,
                                                     unsigned short* __restrict__ o) {
  long i = ((long)blockIdx.x * 256 + threadIdx.x) * 8;
  float4 f0 = *(const float4*)(x + i);
  float4 f1 = *(const float4*)(x + i + 4);
  ushortx8 u;
  u[0] = f2bf(f0.x); u[1] = f2bf(f0.y); u[2] = f2bf(f0.z); u[3] = f2bf(f0.w);
  u[4] = f2bf(f1.x); u[5] = f2bf(f1.y); u[6] = f2bf(f1.z); u[7] = f2bf(f1.w);
  *(ushortx8*)(o + i) = u;
}

// ---------------- transpose (+cast) : src [R][C] -> dst [C][R] bf16 ----------------
static __device__ __forceinline__ unsigned short to_bf(float v) { return f2bf(v); }
static __device__ __forceinline__ unsigned short to_bf(unsigned short v) { return v; }

template <typename SrcT>
__global__ __launch_bounds__(256) void tpose_kernel(const SrcT* __restrict__ src,
                                                    unsigned short* __restrict__ dst,
                                                    int R, int C) {
  size_t moff = (size_t)blockIdx.z * (size_t)R * (size_t)C;
  src += moff; dst += moff;
  __shared__ unsigned short t[32][33];
  int c = blockIdx.x * 32 + threadIdx.x;
#pragma unroll
  for (int i = 0; i < 4; ++i) {
    int r = blockIdx.y * 32 + threadIdx.y + i * 8;
    t[threadIdx.y + i * 8][threadIdx.x] = to_bf(src[(size_t)r * C + c]);
  }
  __syncthreads();
  int rr = blockIdx.y * 32 + threadIdx.x;
#pragma unroll
  for (int i = 0; i < 4; ++i) {
    int cc = blockIdx.x * 32 + threadIdx.y + i * 8;
    dst[(size_t)cc * R + rr] = t[threadIdx.x][threadIdx.y + i * 8];
  }
}

// ---------------- GEMM: C[M=4096][N=1024] = A(bf16 [M][K=1024]) * B (BT bf16 [N][K]) ----------------
template <int MODE>
__global__ __launch_bounds__(256) void gemm_kernel(
    const unsigned short* __restrict__ A,
    const unsigned short* __restrict__ BT0,
    const unsigned short* __restrict__ BT1,
    const unsigned short* __restrict__ BT2,
    float* __restrict__ outF,
    unsigned short* __restrict__ outQ,
    unsigned short* __restrict__ outK,
    unsigned short* __restrict__ outV) {
  const int K = 1024, N = 1024;
  int z = blockIdx.z;
  const unsigned short* BT = (MODE == 0 || z == 0) ? BT0 : (z == 1 ? BT1 : BT2);
  int m0 = blockIdx.y * 64, n0 = blockIdx.x * 64;
  int t = threadIdx.x;
  int lane = t & 63;
  int wave = t >> 6;
  int wy = wave >> 1, wx = wave & 1;
  int n16 = lane & 15, quad = lane >> 4;
  __shared__ __align__(16) unsigned short sA[64 * 40];
  __shared__ __align__(16) unsigned short sB[64 * 40];
  int srow = t >> 2, schunk = t & 3;
  const unsigned short* gA = A + (size_t)(m0 + srow) * K + schunk * 8;
  const unsigned short* gB = BT + (size_t)(n0 + srow) * K + schunk * 8;
  f32x4 acc[2][2];
#pragma unroll
  for (int i = 0; i < 2; ++i)
#pragma unroll
    for (int j = 0; j < 2; ++j) acc[i][j] = f32x4{0.f, 0.f, 0.f, 0.f};

  for (int kk = 0; kk < K; kk += 32) {
    __syncthreads();
    *(uint4*)(&sA[srow * 40 + schunk * 8]) = *(const uint4*)(gA + kk);
    *(uint4*)(&sB[srow * 40 + schunk * 8]) = *(const uint4*)(gB + kk);
    __syncthreads();
    bf16x8 a[2], b[2];
    a[0] = *(const bf16x8*)(&sA[(wy * 32 + n16) * 40 + quad * 8]);
    a[1] = *(const bf16x8*)(&sA[(wy * 32 + 16 + n16) * 40 + quad * 8]);
    b[0] = *(const bf16x8*)(&sB[(wx * 32 + n16) * 40 + quad * 8]);
    b[1] = *(const bf16x8*)(&sB[(wx * 32 + 16 + n16) * 40 + quad * 8]);
#pragma unroll
    for (int mt = 0; mt < 2; ++mt)
#pragma unroll
      for (int nt = 0; nt < 2; ++nt)
        acc[mt][nt] = __builtin_amdgcn_mfma_f32_16x16x32_bf16(a[mt], b[nt], acc[mt][nt], 0, 0, 0);
  }

#pragma unroll
  for (int mt = 0; mt < 2; ++mt)
#pragma unroll
    for (int nt = 0; nt < 2; ++nt)
#pragma unroll
      for (int r = 0; r < 4; ++r) {
        int row = m0 + wy * 32 + mt * 16 + quad * 4 + r;
        int col = n0 + wx * 32 + nt * 16 + n16;
        float v = acc[mt][nt][r];
        if (MODE == 0) {
          outF[(size_t)row * N + col] = v;
        } else {
          unsigned short* dst = (z == 0) ? outQ : (z == 1 ? outK : outV);
          int b = row >> 11, s = row & 2047, h = col >> 6, d = col & 63;
          dst[(((size_t)b * 16 + h) * 2048 + s) * 64 + d] = f2bf(v);
        }
      }
}

// ---------------- RoPE in-place on Q,K (bf16, [B,NH,S,HD]) ----------------
__global__ __launch_bounds__(256) void rope_kernel(unsigned short* __restrict__ Q,
                                                   unsigned short* __restrict__ Kk,
                                                   const int* __restrict__ pos_ids,
                                                   const float* __restrict__ cosb,
                                                   const float* __restrict__ sinb) {
  int tid = blockIdx.x * 256 + threadIdx.x;
  int d = tid & 31;
  int s = (tid >> 5) & 2047;
  int bh = tid >> 16;
  int b = bh >> 4;
  size_t base = ((size_t)bh * 2048 + s) * 64;
  int pos = pos_ids[b * 2048 + s];
  float c0 = cosb[pos * 64 + d], s0 = sinb[pos * 64 + d];
  float c1 = cosb[pos * 64 + d + 32], s1 = sinb[pos * 64 + d + 32];
  {
    float x0 = bf2f(Q[base + d]), x1 = bf2f(Q[base + d + 32]);
    Q[base + d] = f2bf(x0 * c0 - x1 * s0);
    Q[base + d + 32] = f2bf(x1 * c1 + x0 * s1);
  }
  {
    float x0 = bf2f(Kk[base + d]), x1 = bf2f(Kk[base + d + 32]);
    Kk[base + d] = f2bf(x0 * c0 - x1 * s0);
    Kk[base + d + 32] = f2bf(x1 * c1 + x0 * s1);
  }
}

// ---------------- Flash attention v2: 4 waves/block, 64 q-rows/block, LDS K/V ----------------
// Q,K bf16 [B*NH, S, 64]; VT bf16 [B*NH, 64, S]; O bf16 [B*S, NH*64]
// grid: (bh=32, qt=32). Wave w handles q-rows qt*64 + w*16 .. +15.
#define KSTR 72  // 64 + 8 pad (shorts): breaks the 128B bank stride, keeps 16B align
__global__ __launch_bounds__(256, 4) void attn_kernel(const unsigned short* __restrict__ Q,
                                                      const unsigned short* __restrict__ Kk,
                                                      const unsigned short* __restrict__ VT,
                                                      unsigned short* __restrict__ O) {
  int bh = blockIdx.x;
  int qt = blockIdx.y;
  int t = threadIdx.x;
  int lane = t & 63;
  int w = t >> 6;
  int n16 = lane & 15, quad = lane >> 4;
  const unsigned short* Qb = Q + (size_t)bh * 2048 * 64;
  const unsigned short* Kb = Kk + (size_t)bh * 2048 * 64;
  const unsigned short* Vb = VT + (size_t)bh * 64 * 2048;

  __shared__ __align__(16) unsigned short sK[64 * KSTR];
  __shared__ __align__(16) unsigned short sV[64 * KSTR];
  __shared__ __align__(16) unsigned short sP[4 * 16 * KSTR];
  unsigned short* spW = sP + w * 16 * KSTR;

  // Q A-fragments, held for the whole loop. A[m=n16][k=quad*8+j], kb in {0,1}.
  bf16x8 aQ[2];
#pragma unroll
  for (int kb = 0; kb < 2; ++kb)
    aQ[kb] = *(const bf16x8*)(Qb + (size_t)(qt * 64 + w * 16 + n16) * 64 + kb * 32 + quad * 8);

  f32x4 o[4];
  float mst[4], lst[4];
#pragma unroll
  for (int ct = 0; ct < 4; ++ct) o[ct] = f32x4{0.f, 0.f, 0.f, 0.f};
#pragma unroll
  for (int r = 0; r < 4; ++r) { mst[r] = -3e38f; lst[r] = 0.f; }

  const float SCL2 = 0.125f * 1.44269504088896340736f;  // SCALE * log2(e)

  int r0 = t >> 3, c8 = (t & 7) * 8;          // staging coords: thread -> (row, 16B chunk)
  for (int kt = 0; kt <= qt; ++kt) {
    __syncthreads();  // previous iter's sK/sV reads complete
#pragma unroll
    for (int i = 0; i < 2; ++i) {
      int row = r0 + i * 32;
      *(uint4*)(&sK[row * KSTR + c8]) = *(const uint4*)(Kb + (size_t)(kt * 64 + row) * 64 + c8);
      *(uint4*)(&sV[row * KSTR + c8]) = *(const uint4*)(Vb + (size_t)row * 2048 + kt * 64 + c8);
    }
    __syncthreads();

    // QK^T: 4 n-subtiles of 16 cols, K-split 2
    f32x4 sc[4];
#pragma unroll
    for (int ns = 0; ns < 4; ++ns) {
      bf16x8 b0 = *(const bf16x8*)(&sK[(ns * 16 + n16) * KSTR + quad * 8]);
      bf16x8 b1 = *(const bf16x8*)(&sK[(ns * 16 + n16) * KSTR + 32 + quad * 8]);
      f32x4 z = f32x4{0.f, 0.f, 0.f, 0.f};
      z = __builtin_amdgcn_mfma_f32_16x16x32_bf16(aQ[0], b0, z, 0, 0, 0);
      sc[ns] = __builtin_amdgcn_mfma_f32_16x16x32_bf16(aQ[1], b1, z, 0, 0, 0);
    }

    bool diag = (kt == qt);
#pragma unroll
    for (int r = 0; r < 4; ++r) {
      int rg = w * 16 + quad * 4 + r;  // q-row within 64-row q-tile
      float s[4];
#pragma unroll
      for (int ns = 0; ns < 4; ++ns) {
        s[ns] = sc[ns][r] * SCL2;
        if (diag && (ns * 16 + n16 > rg)) s[ns] = -3e38f;
      }
      float rm = fmaxf(fmaxf(s[0], s[1]), fmaxf(s[2], s[3]));
#pragma unroll
      for (int off = 1; off < 16; off <<= 1) rm = fmaxf(rm, __shfl_xor(rm, off));
      float mn = fmaxf(mst[r], rm);
      float al = exp2f(mst[r] - mn);
      float p[4], rs = 0.f;
#pragma unroll
      for (int ns = 0; ns < 4; ++ns) { p[ns] = exp2f(s[ns] - mn); rs += p[ns]; }
#pragma unroll
      for (int off = 1; off < 16; off <<= 1) rs += __shfl_xor(rs, off);
      lst[r] = lst[r] * al + rs;
      mst[r] = mn;
#pragma unroll
      for (int ct = 0; ct < 4; ++ct) o[ct][r] *= al;
#pragma unroll
      for (int ns = 0; ns < 4; ++ns)
        spW[(quad * 4 + r) * KSTR + ns * 16 + n16] = f2bf(p[ns]);
    }
    // P is per-wave: only need LDS ops drained, not a block barrier.
    __builtin_amdgcn_s_waitcnt(0xC07F);  // vmcnt(63) expcnt(7) lgkmcnt(0)

    bf16x8 aP[2];
    aP[0] = *(const bf16x8*)(&spW[n16 * KSTR + quad * 8]);
    aP[1] = *(const bf16x8*)(&spW[n16 * KSTR + 32 + quad * 8]);
#pragma unroll
    for (int ct = 0; ct < 4; ++ct) {
      bf16x8 v0 = *(const bf16x8*)(&sV[(ct * 16 + n16) * KSTR + quad * 8]);
      bf16x8 v1 = *(const bf16x8*)(&sV[(ct * 16 + n16) * KSTR + 32 + quad * 8]);
      o[ct] = __builtin_amdgcn_mfma_f32_16x16x32_bf16(aP[0], v0, o[ct], 0, 0, 0);
      o[ct] = __builtin_amdgcn_mfma_f32_16x16x32_bf16(aP[1], v1, o[ct], 0, 0, 0);
    }
  }

  int b = bh >> 4, h = bh & 15;
#pragma unroll
  for (int ct = 0; ct < 4; ++ct)
#pragma unroll
    for (int r = 0; r < 4; ++r) {
      int s_ = qt * 64 + w * 16 + quad * 4 + r;
      float v = o[ct][r] / lst[r];
      O[((size_t)b * 2048 + s_) * 1024 + h * 64 + ct * 16 + n16] = f2bf(v);
    }
}

// ---------------- launch ----------------
extern "C" void kernel_launch(void* const* d_in, const int* in_sizes, int n_in,
                              void* d_out, int out_size, void* d_ws, size_t ws_size,
                              hipStream_t stream) {
  const float* X    = (const float*)d_in[0];
  const int*   pos  = (const int*)d_in[2];
  const float* cosb = (const float*)d_in[3];
  const float* sinb = (const float*)d_in[4];
  const float* Wq   = (const float*)d_in[5];
  const float* Wk   = (const float*)d_in[6];
  const float* Wv   = (const float*)d_in[7];
  const float* Wo   = (const float*)d_in[8];
  float* out = (float*)d_out;

  char* ws = (char*)d_ws;
  const size_t SZ_X   = 4096UL * 1024 * 2;
  const size_t SZ_W   = 1024UL * 1024 * 2;
  unsigned short* Xbf = (unsigned short*)(ws);
  unsigned short* WTq = (unsigned short*)(ws + SZ_X);
  unsigned short* WTk = (unsigned short*)(ws + SZ_X + SZ_W);
  unsigned short* WTv = (unsigned short*)(ws + SZ_X + 2 * SZ_W);
  unsigned short* WTo = (unsigned short*)(ws + SZ_X + 3 * SZ_W);
  unsigned short* Qbf = (unsigned short*)(ws + SZ_X + 4 * SZ_W);
  unsigned short* Kbf = (unsigned short*)(ws + 2 * SZ_X + 4 * SZ_W);
  unsigned short* Vbf = (unsigned short*)(ws + 3 * SZ_X + 4 * SZ_W);
  unsigned short* VTr = (unsigned short*)(ws + 4 * SZ_X + 4 * SZ_W);
  unsigned short* Obf = (unsigned short*)(ws + 5 * SZ_X + 4 * SZ_W);

  dim3 tb(32, 8);

  cast_x_kernel<<<2048, 256, 0, stream>>>(X, Xbf);
  tpose_kernel<float><<<dim3(32, 32, 1), tb, 0, stream>>>(Wq, WTq, 1024, 1024);
  tpose_kernel<float><<<dim3(32, 32, 1), tb, 0, stream>>>(Wk, WTk, 1024, 1024);
  tpose_kernel<float><<<dim3(32, 32, 1), tb, 0, stream>>>(Wv, WTv, 1024, 1024);
  tpose_kernel<float><<<dim3(32, 32, 1), tb, 0, stream>>>(Wo, WTo, 1024, 1024);

  gemm_kernel<1><<<dim3(16, 64, 3), 256, 0, stream>>>(Xbf, WTq, WTk, WTv,
                                                      nullptr, Qbf, Kbf, Vbf);

  rope_kernel<<<8192, 256, 0, stream>>>(Qbf, Kbf, pos, cosb, sinb);

  tpose_kernel<unsigned short><<<dim3(2, 64, 32), tb, 0, stream>>>(Vbf, VTr, 2048, 64);

  attn_kernel<<<dim3(32, 32), 256, 0, stream>>>(Qbf, Kbf, VTr, Obf);

  gemm_kernel<0><<<dim3(16, 64, 1), 256, 0, stream>>>(Obf, WTo, nullptr, nullptr,
                                                      out, nullptr, nullptr, nullptr);
}

// Round 3
// 285.614 us; speedup vs baseline: 1.4588x; 1.0812x over previous
//
#include <hip/hip_runtime.h>

typedef __bf16 bf16x8 __attribute__((ext_vector_type(8)));
typedef float  f32x4  __attribute__((ext_vector_type(4)));
typedef unsigned short ushortx8 __attribute__((ext_vector_type(8)));

static __device__ __forceinline__ unsigned short f2bf(float f) {
  unsigned int u = __builtin_bit_cast(unsigned int, f);
  u += 0x7FFFu + ((u >> 16) & 1u);
  return (unsigned short)(u >> 16);
}

#define GLL16(gp, lp) __builtin_amdgcn_global_load_lds(                       \
    (const __attribute__((address_space(1))) void*)(gp),                      \
    (__attribute__((address_space(3))) void*)(lp), 16, 0, 0)

// ---------------- cast X fp32 -> bf16 ----------------
__global__ __launch_bounds__(256) void cast_x_kernel(const float* __restrict__ x,
                                                     unsigned short* __restrict__ o) {
  long i = ((long)blockIdx.x * 256 + threadIdx.x) * 8;
  float4 f0 = *(const float4*)(x + i);
  float4 f1 = *(const float4*)(x + i + 4);
  ushortx8 u;
  u[0] = f2bf(f0.x); u[1] = f2bf(f0.y); u[2] = f2bf(f0.z); u[3] = f2bf(f0.w);
  u[4] = f2bf(f1.x); u[5] = f2bf(f1.y); u[6] = f2bf(f1.z); u[7] = f2bf(f1.w);
  *(ushortx8*)(o + i) = u;
}

// ---------------- transpose (+cast) : src [R][C] -> dst [C][R] bf16 ----------------
static __device__ __forceinline__ unsigned short to_bf(float v) { return f2bf(v); }
static __device__ __forceinline__ unsigned short to_bf(unsigned short v) { return v; }

template <typename SrcT>
__global__ __launch_bounds__(256) void tpose_kernel(const SrcT* __restrict__ src,
                                                    unsigned short* __restrict__ dst,
                                                    int R, int C) {
  size_t moff = (size_t)blockIdx.z * (size_t)R * (size_t)C;
  src += moff; dst += moff;
  __shared__ unsigned short t[32][33];
  int c = blockIdx.x * 32 + threadIdx.x;
#pragma unroll
  for (int i = 0; i < 4; ++i) {
    int r = blockIdx.y * 32 + threadIdx.y + i * 8;
    t[threadIdx.y + i * 8][threadIdx.x] = to_bf(src[(size_t)r * C + c]);
  }
  __syncthreads();
  int rr = blockIdx.y * 32 + threadIdx.x;
#pragma unroll
  for (int i = 0; i < 4; ++i) {
    int cc = blockIdx.x * 32 + threadIdx.y + i * 8;
    dst[(size_t)cc * R + rr] = t[threadIdx.x][threadIdx.y + i * 8];
  }
}

// ---------------- GEMM m97-style: 128x128 tile, BK=64, global_load_lds ----------------
// C[M=4096][N=1024] = A(bf16 [M][K=1024]) * BT(bf16 [N][K])^T
// MODE 0: fp32 row-major to outF.  MODE 1: bf16 [B,NH,S,HD] Q/K/V by blockIdx.z,
//         with RoPE fused into the epilogue for z<2.
template <int MODE>
__global__ __launch_bounds__(256) void gemm128_kernel(
    const unsigned short* __restrict__ A,
    const unsigned short* __restrict__ BT0,
    const unsigned short* __restrict__ BT1,
    const unsigned short* __restrict__ BT2,
    float* __restrict__ outF,
    unsigned short* __restrict__ outQ,
    unsigned short* __restrict__ outK,
    unsigned short* __restrict__ outV,
    const int* __restrict__ pos_ids,
    const float* __restrict__ cosb,
    const float* __restrict__ sinb) {
  const int K = 1024, N = 1024;
  int z = blockIdx.z;
  const unsigned short* BT = (MODE == 0 || z == 0) ? BT0 : (z == 1 ? BT1 : BT2);
  int n0 = blockIdx.x * 128, m0 = blockIdx.y * 128;
  int t = threadIdx.x, lane = t & 63, w = t >> 6;
  int wy = w >> 1, wx = w & 1;
  int n16 = lane & 15, quad = lane >> 4;
  __shared__ __align__(16) unsigned short sA[128 * 64];
  __shared__ __align__(16) unsigned short sB[128 * 64];

  int srow = w * 32 + (lane >> 3);
  const char* gA = (const char*)(A + (size_t)(m0 + srow) * K) + (lane & 7) * 16;
  const char* gB = (const char*)(BT + (size_t)(n0 + srow) * K) + (lane & 7) * 16;

  f32x4 acc[4][4];
#pragma unroll
  for (int i = 0; i < 4; ++i)
#pragma unroll
    for (int j = 0; j < 4; ++j) acc[i][j] = f32x4{0.f, 0.f, 0.f, 0.f};

  for (int kk = 0; kk < K; kk += 64) {
    __syncthreads();  // prev-iter LDS reads done
#pragma unroll
    for (int i = 0; i < 4; ++i) {
      GLL16(gA + (size_t)kk * 2 + (size_t)i * 8 * K * 2, sA + (w * 32 + i * 8) * 64);
      GLL16(gB + (size_t)kk * 2 + (size_t)i * 8 * K * 2, sB + (w * 32 + i * 8) * 64);
    }
    __syncthreads();  // vmcnt(0) drain: tiles visible
#pragma unroll
    for (int kb = 0; kb < 2; ++kb) {
      bf16x8 a[4], b[4];
#pragma unroll
      for (int i = 0; i < 4; ++i) {
        a[i] = *(const bf16x8*)(&sA[(wy * 64 + i * 16 + n16) * 64 + kb * 32 + quad * 8]);
        b[i] = *(const bf16x8*)(&sB[(wx * 64 + i * 16 + n16) * 64 + kb * 32 + quad * 8]);
      }
#pragma unroll
      for (int mt = 0; mt < 4; ++mt)
#pragma unroll
        for (int nt = 0; nt < 4; ++nt)
          acc[mt][nt] = __builtin_amdgcn_mfma_f32_16x16x32_bf16(a[mt], b[nt], acc[mt][nt], 0, 0, 0);
    }
  }

  // ---- fused RoPE on Q/K (z<2): wave's 64-col span == one head; pair (d,d+32) = (nt, nt+2)
  if (MODE == 1 && z < 2) {
#pragma unroll
    for (int mt = 0; mt < 4; ++mt)
#pragma unroll
      for (int r = 0; r < 4; ++r) {
        int row = m0 + wy * 64 + mt * 16 + quad * 4 + r;
        int b = row >> 11, s = row & 2047;
        int pos = pos_ids[b * 2048 + s];
        const float* cb = cosb + (size_t)pos * 64;
        const float* sb = sinb + (size_t)pos * 64;
#pragma unroll
        for (int nt = 0; nt < 2; ++nt) {
          int d0 = nt * 16 + n16;
          float c0 = cb[d0], s0 = sb[d0], c1 = cb[d0 + 32], s1 = sb[d0 + 32];
          float x0 = acc[mt][nt][r], x1 = acc[mt][nt + 2][r];
          acc[mt][nt][r]     = x0 * c0 - x1 * s0;
          acc[mt][nt + 2][r] = x1 * c1 + x0 * s1;
        }
      }
  }

#pragma unroll
  for (int mt = 0; mt < 4; ++mt)
#pragma unroll
    for (int nt = 0; nt < 4; ++nt)
#pragma unroll
      for (int r = 0; r < 4; ++r) {
        int row = m0 + wy * 64 + mt * 16 + quad * 4 + r;
        int col = n0 + wx * 64 + nt * 16 + n16;
        float v = acc[mt][nt][r];
        if (MODE == 0) {
          outF[(size_t)row * N + col] = v;
        } else {
          unsigned short* dst = (z == 0) ? outQ : (z == 1 ? outK : outV);
          int b = row >> 11, s = row & 2047, h = col >> 6, d = col & 63;
          dst[(((size_t)b * 16 + h) * 2048 + s) * 64 + d] = f2bf(v);
        }
      }
}

// ---------------- Flash attention v3 ----------------
// Q,K bf16 [B*NH, S, 64]; VT bf16 [B*NH, 64, S]; O bf16 [B*S, NH*64]
// grid (bh=32, 32); qt reversed for LPT scheduling. 4 waves, 16 q-rows each.
#define KSTR 72
__global__ __launch_bounds__(256) void attn_kernel(const unsigned short* __restrict__ Q,
                                                   const unsigned short* __restrict__ Kk,
                                                   const unsigned short* __restrict__ VT,
                                                   unsigned short* __restrict__ O) {
  int bh = blockIdx.x;
  int qt = (int)(gridDim.y - 1 - blockIdx.y);  // longest blocks first
  int t = threadIdx.x;
  int lane = t & 63;
  int w = t >> 6;
  int n16 = lane & 15, quad = lane >> 4;
  const unsigned short* Qb = Q + (size_t)bh * 2048 * 64;
  const unsigned short* Kb = Kk + (size_t)bh * 2048 * 64;
  const unsigned short* Vb = VT + (size_t)bh * 64 * 2048;

  __shared__ __align__(16) unsigned short sK[64 * 64];
  __shared__ __align__(16) unsigned short sV[64 * 64];
  __shared__ __align__(16) unsigned short sP[4 * 16 * KSTR];
  unsigned short* spW = sP + w * 16 * KSTR;

  bf16x8 aQ[2];
#pragma unroll
  for (int kb = 0; kb < 2; ++kb)
    aQ[kb] = *(const bf16x8*)(Qb + (size_t)(qt * 64 + w * 16 + n16) * 64 + kb * 32 + quad * 8);

  f32x4 o[4];
  float mst[4], lst[4];
#pragma unroll
  for (int ct = 0; ct < 4; ++ct) o[ct] = f32x4{0.f, 0.f, 0.f, 0.f};
#pragma unroll
  for (int r = 0; r < 4; ++r) { mst[r] = -3e38f; lst[r] = 0.f; }

  const float SCL2 = 0.125f * 1.44269504088896340736f;  // SCALE * log2(e)
  int r8 = lane >> 3, c16 = (lane & 7) * 16;  // staging: lane -> (row-in-8, 16B chunk)

  for (int kt = 0; kt <= qt; ++kt) {
    __syncthreads();
#pragma unroll
    for (int i = 0; i < 2; ++i) {
      int row = w * 16 + i * 8 + r8;
      GLL16((const char*)(Kb + (size_t)(kt * 64 + row) * 64) + c16, sK + (w * 16 + i * 8) * 64);
      GLL16((const char*)(Vb + (size_t)row * 2048 + kt * 64) + c16, sV + (w * 16 + i * 8) * 64);
    }
    __syncthreads();

    f32x4 sc[4];
#pragma unroll
    for (int ns = 0; ns < 4; ++ns) {
      bf16x8 b0 = *(const bf16x8*)(&sK[(ns * 16 + n16) * 64 + quad * 8]);
      bf16x8 b1 = *(const bf16x8*)(&sK[(ns * 16 + n16) * 64 + 32 + quad * 8]);
      f32x4 zv = f32x4{0.f, 0.f, 0.f, 0.f};
      zv = __builtin_amdgcn_mfma_f32_16x16x32_bf16(aQ[0], b0, zv, 0, 0, 0);
      sc[ns] = __builtin_amdgcn_mfma_f32_16x16x32_bf16(aQ[1], b1, sc[ns] = zv, 0, 0, 0);
    }

    float s[4][4];
#pragma unroll
    for (int r = 0; r < 4; ++r)
#pragma unroll
      for (int ns = 0; ns < 4; ++ns) s[r][ns] = sc[ns][r] * SCL2;
    if (kt == qt) {  // wave-uniform: mask only on the diagonal tile
#pragma unroll
      for (int r = 0; r < 4; ++r) {
        int rg = w * 16 + quad * 4 + r;
#pragma unroll
        for (int ns = 0; ns < 4; ++ns)
          if (ns * 16 + n16 > rg) s[r][ns] = -3e38f;
      }
    }
    float rm[4], mn[4], al[4], rs[4], p[4][4];
#pragma unroll
    for (int r = 0; r < 4; ++r)
      rm[r] = fmaxf(fmaxf(s[r][0], s[r][1]), fmaxf(s[r][2], s[r][3]));
#pragma unroll
    for (int off = 1; off < 16; off <<= 1)  // 4 independent chains in flight
#pragma unroll
      for (int r = 0; r < 4; ++r) rm[r] = fmaxf(rm[r], __shfl_xor(rm[r], off));
#pragma unroll
    for (int r = 0; r < 4; ++r) {
      mn[r] = fmaxf(mst[r], rm[r]);
      al[r] = exp2f(mst[r] - mn[r]);
      mst[r] = mn[r];
      rs[r] = 0.f;
#pragma unroll
      for (int ns = 0; ns < 4; ++ns) { p[r][ns] = exp2f(s[r][ns] - mn[r]); rs[r] += p[r][ns]; }
    }
#pragma unroll
    for (int off = 1; off < 16; off <<= 1)
#pragma unroll
      for (int r = 0; r < 4; ++r) rs[r] += __shfl_xor(rs[r], off);
#pragma unroll
    for (int r = 0; r < 4; ++r) lst[r] = lst[r] * al[r] + rs[r];
#pragma unroll
    for (int ct = 0; ct < 4; ++ct)
#pragma unroll
      for (int r = 0; r < 4; ++r) o[ct][r] *= al[r];
#pragma unroll
    for (int r = 0; r < 4; ++r)
#pragma unroll
      for (int ns = 0; ns < 4; ++ns)
        spW[(quad * 4 + r) * KSTR + ns * 16 + n16] = f2bf(p[r][ns]);
    __builtin_amdgcn_s_waitcnt(0xC07F);  // lgkmcnt(0) only: sP is per-wave

    bf16x8 aP[2];
    aP[0] = *(const bf16x8*)(&spW[n16 * KSTR + quad * 8]);
    aP[1] = *(const bf16x8*)(&spW[n16 * KSTR + 32 + quad * 8]);
#pragma unroll
    for (int ct = 0; ct < 4; ++ct) {
      bf16x8 v0 = *(const bf16x8*)(&sV[(ct * 16 + n16) * 64 + quad * 8]);
      bf16x8 v1 = *(const bf16x8*)(&sV[(ct * 16 + n16) * 64 + 32 + quad * 8]);
      o[ct] = __builtin_amdgcn_mfma_f32_16x16x32_bf16(aP[0], v0, o[ct], 0, 0, 0);
      o[ct] = __builtin_amdgcn_mfma_f32_16x16x32_bf16(aP[1], v1, o[ct], 0, 0, 0);
    }
  }

  int b = bh >> 4, h = bh & 15;
#pragma unroll
  for (int ct = 0; ct < 4; ++ct)
#pragma unroll
    for (int r = 0; r < 4; ++r) {
      int s_ = qt * 64 + w * 16 + quad * 4 + r;
      float v = o[ct][r] / lst[r];
      O[((size_t)b * 2048 + s_) * 1024 + h * 64 + ct * 16 + n16] = f2bf(v);
    }
}

// ---------------- launch ----------------
extern "C" void kernel_launch(void* const* d_in, const int* in_sizes, int n_in,
                              void* d_out, int out_size, void* d_ws, size_t ws_size,
                              hipStream_t stream) {
  const float* X    = (const float*)d_in[0];
  const int*   pos  = (const int*)d_in[2];
  const float* cosb = (const float*)d_in[3];
  const float* sinb = (const float*)d_in[4];
  const float* Wq   = (const float*)d_in[5];
  const float* Wk   = (const float*)d_in[6];
  const float* Wv   = (const float*)d_in[7];
  const float* Wo   = (const float*)d_in[8];
  float* out = (float*)d_out;

  char* ws = (char*)d_ws;
  const size_t SZ_X = 4096UL * 1024 * 2;
  const size_t SZ_W = 1024UL * 1024 * 2;
  unsigned short* Xbf = (unsigned short*)(ws);
  unsigned short* WTq = (unsigned short*)(ws + SZ_X);
  unsigned short* WTk = (unsigned short*)(ws + SZ_X + SZ_W);
  unsigned short* WTv = (unsigned short*)(ws + SZ_X + 2 * SZ_W);
  unsigned short* WTo = (unsigned short*)(ws + SZ_X + 3 * SZ_W);
  unsigned short* Qbf = (unsigned short*)(ws + SZ_X + 4 * SZ_W);
  unsigned short* Kbf = (unsigned short*)(ws + 2 * SZ_X + 4 * SZ_W);
  unsigned short* Vbf = (unsigned short*)(ws + 3 * SZ_X + 4 * SZ_W);
  unsigned short* VTr = (unsigned short*)(ws + 4 * SZ_X + 4 * SZ_W);
  unsigned short* Obf = (unsigned short*)(ws + 5 * SZ_X + 4 * SZ_W);

  dim3 tb(32, 8);

  cast_x_kernel<<<2048, 256, 0, stream>>>(X, Xbf);
  tpose_kernel<float><<<dim3(32, 32, 1), tb, 0, stream>>>(Wq, WTq, 1024, 1024);
  tpose_kernel<float><<<dim3(32, 32, 1), tb, 0, stream>>>(Wk, WTk, 1024, 1024);
  tpose_kernel<float><<<dim3(32, 32, 1), tb, 0, stream>>>(Wv, WTv, 1024, 1024);
  tpose_kernel<float><<<dim3(32, 32, 1), tb, 0, stream>>>(Wo, WTo, 1024, 1024);

  // QKV projections + fused RoPE (z: 0=Q,1=K,2=V)
  gemm128_kernel<1><<<dim3(8, 32, 3), 256, 0, stream>>>(Xbf, WTq, WTk, WTv,
                                                        nullptr, Qbf, Kbf, Vbf,
                                                        pos, cosb, sinb);

  tpose_kernel<unsigned short><<<dim3(2, 64, 32), tb, 0, stream>>>(Vbf, VTr, 2048, 64);

  attn_kernel<<<dim3(32, 32), 256, 0, stream>>>(Qbf, Kbf, VTr, Obf);

  gemm128_kernel<0><<<dim3(8, 32, 1), 256, 0, stream>>>(Obf, WTo, nullptr, nullptr,
                                                        out, nullptr, nullptr, nullptr,
                                                        nullptr, nullptr, nullptr);
}

// Round 4
// 267.879 us; speedup vs baseline: 1.5554x; 1.0662x over previous
//
#include <hip/hip_runtime.h>

typedef __bf16 bf16x8 __attribute__((ext_vector_type(8)));
typedef float  f32x4  __attribute__((ext_vector_type(4)));
typedef unsigned short ushortx8 __attribute__((ext_vector_type(8)));

static __device__ __forceinline__ unsigned short f2bf(float f) {
  unsigned int u = __builtin_bit_cast(unsigned int, f);
  u += 0x7FFFu + ((u >> 16) & 1u);
  return (unsigned short)(u >> 16);
}

#define GLL16(gp, lp) __builtin_amdgcn_global_load_lds(                       \
    (const __attribute__((address_space(1))) void*)(gp),                      \
    (__attribute__((address_space(3))) void*)(lp), 16, 0, 0)

// ---------------- cast X fp32 -> bf16 ----------------
__global__ __launch_bounds__(256) void cast_x_kernel(const float* __restrict__ x,
                                                     unsigned short* __restrict__ o) {
  long i = ((long)blockIdx.x * 256 + threadIdx.x) * 8;
  float4 f0 = *(const float4*)(x + i);
  float4 f1 = *(const float4*)(x + i + 4);
  ushortx8 u;
  u[0] = f2bf(f0.x); u[1] = f2bf(f0.y); u[2] = f2bf(f0.z); u[3] = f2bf(f0.w);
  u[4] = f2bf(f1.x); u[5] = f2bf(f1.y); u[6] = f2bf(f1.z); u[7] = f2bf(f1.w);
  *(ushortx8*)(o + i) = u;
}

// ---------------- transpose (+cast) : src [R][C] -> dst [C][R] bf16 ----------------
static __device__ __forceinline__ unsigned short to_bf(float v) { return f2bf(v); }
static __device__ __forceinline__ unsigned short to_bf(unsigned short v) { return v; }

template <typename SrcT>
__global__ __launch_bounds__(256) void tpose_kernel(const SrcT* __restrict__ src,
                                                    unsigned short* __restrict__ dst,
                                                    int R, int C) {
  size_t moff = (size_t)blockIdx.z * (size_t)R * (size_t)C;
  src += moff; dst += moff;
  __shared__ unsigned short t[32][33];
  int c = blockIdx.x * 32 + threadIdx.x;
#pragma unroll
  for (int i = 0; i < 4; ++i) {
    int r = blockIdx.y * 32 + threadIdx.y + i * 8;
    t[threadIdx.y + i * 8][threadIdx.x] = to_bf(src[(size_t)r * C + c]);
  }
  __syncthreads();
  int rr = blockIdx.y * 32 + threadIdx.x;
#pragma unroll
  for (int i = 0; i < 4; ++i) {
    int cc = blockIdx.x * 32 + threadIdx.y + i * 8;
    dst[(size_t)cc * R + rr] = t[threadIdx.x][threadIdx.y + i * 8];
  }
}

// ---------------- GEMM m97-style: 128x128 tile, BK=64, global_load_lds, XOR-swizzled LDS ----
// LDS slot (row, c) holds global 16B-chunk (c ^ (row&7)); reads XOR the chunk index.
template <int MODE>
__global__ __launch_bounds__(256) void gemm128_kernel(
    const unsigned short* __restrict__ A,
    const unsigned short* __restrict__ BT0,
    const unsigned short* __restrict__ BT1,
    const unsigned short* __restrict__ BT2,
    float* __restrict__ outF,
    unsigned short* __restrict__ outQ,
    unsigned short* __restrict__ outK,
    unsigned short* __restrict__ outV,
    const int* __restrict__ pos_ids,
    const float* __restrict__ cosb,
    const float* __restrict__ sinb) {
  const int K = 1024, N = 1024;
  int z = blockIdx.z;
  const unsigned short* BT = (MODE == 0 || z == 0) ? BT0 : (z == 1 ? BT1 : BT2);
  int n0 = blockIdx.x * 128, m0 = blockIdx.y * 128;
  int t = threadIdx.x, lane = t & 63, w = t >> 6;
  int wy = w >> 1, wx = w & 1;
  int n16 = lane & 15, quad = lane >> 4;
  __shared__ __align__(16) unsigned short sA[128 * 64];
  __shared__ __align__(16) unsigned short sB[128 * 64];

  int r8 = lane >> 3, c8 = lane & 7;
  int srow = w * 32 + r8;
  const char* gA = (const char*)(A + (size_t)(m0 + srow) * K) + (c8 ^ r8) * 16;
  const char* gB = (const char*)(BT + (size_t)(n0 + srow) * K) + (c8 ^ r8) * 16;

  f32x4 acc[4][4];
#pragma unroll
  for (int i = 0; i < 4; ++i)
#pragma unroll
    for (int j = 0; j < 4; ++j) acc[i][j] = f32x4{0.f, 0.f, 0.f, 0.f};

  for (int kk = 0; kk < K; kk += 64) {
    __syncthreads();
#pragma unroll
    for (int i = 0; i < 4; ++i) {
      GLL16(gA + (size_t)kk * 2 + (size_t)i * 8 * K * 2, sA + (w * 32 + i * 8) * 64);
      GLL16(gB + (size_t)kk * 2 + (size_t)i * 8 * K * 2, sB + (w * 32 + i * 8) * 64);
    }
    __syncthreads();
#pragma unroll
    for (int kb = 0; kb < 2; ++kb) {
      bf16x8 a[4], b[4];
#pragma unroll
      for (int i = 0; i < 4; ++i) {
        int ra = wy * 64 + i * 16 + n16;
        int rb = wx * 64 + i * 16 + n16;
        int cs = ((kb * 4 + quad) ^ (n16 & 7)) * 8;
        a[i] = *(const bf16x8*)(&sA[ra * 64 + cs]);
        b[i] = *(const bf16x8*)(&sB[rb * 64 + cs]);
      }
#pragma unroll
      for (int mt = 0; mt < 4; ++mt)
#pragma unroll
        for (int nt = 0; nt < 4; ++nt)
          acc[mt][nt] = __builtin_amdgcn_mfma_f32_16x16x32_bf16(a[mt], b[nt], acc[mt][nt], 0, 0, 0);
    }
  }

  // fused RoPE on Q/K (z<2): wave's 64-col span == one head; pair (d,d+32) = (nt, nt+2)
  if (MODE == 1 && z < 2) {
#pragma unroll
    for (int mt = 0; mt < 4; ++mt)
#pragma unroll
      for (int r = 0; r < 4; ++r) {
        int row = m0 + wy * 64 + mt * 16 + quad * 4 + r;
        int b = row >> 11, s = row & 2047;
        int pos = pos_ids[b * 2048 + s];
        const float* cb = cosb + (size_t)pos * 64;
        const float* sb = sinb + (size_t)pos * 64;
#pragma unroll
        for (int nt = 0; nt < 2; ++nt) {
          int d0 = nt * 16 + n16;
          float c0 = cb[d0], s0 = sb[d0], c1 = cb[d0 + 32], s1 = sb[d0 + 32];
          float x0 = acc[mt][nt][r], x1 = acc[mt][nt + 2][r];
          acc[mt][nt][r]     = x0 * c0 - x1 * s0;
          acc[mt][nt + 2][r] = x1 * c1 + x0 * s1;
        }
      }
  }

#pragma unroll
  for (int mt = 0; mt < 4; ++mt)
#pragma unroll
    for (int nt = 0; nt < 4; ++nt)
#pragma unroll
      for (int r = 0; r < 4; ++r) {
        int row = m0 + wy * 64 + mt * 16 + quad * 4 + r;
        int col = n0 + wx * 64 + nt * 16 + n16;
        float v = acc[mt][nt][r];
        if (MODE == 0) {
          outF[(size_t)row * N + col] = v;
        } else {
          unsigned short* dst = (z == 0) ? outQ : (z == 1 ? outK : outV);
          int b = row >> 11, s = row & 2047, h = col >> 6, d = col & 63;
          dst[(((size_t)b * 16 + h) * 2048 + s) * 64 + d] = f2bf(v);
        }
      }
}

// ---------------- Flash attention v4: paired q-tiles, dbuf K/V prefetch, swizzled LDS ----
// Q,K bf16 [B*NH, S, 64]; VT bf16 [B*NH, 64, S]; O bf16 [B*S, NH*64]
// grid (pair=16, bh=32). Block handles qt=pair and qt=31-pair -> exactly 33 iters each.
__global__ __launch_bounds__(256) void attn_kernel(const unsigned short* __restrict__ Q,
                                                   const unsigned short* __restrict__ Kk,
                                                   const unsigned short* __restrict__ VT,
                                                   unsigned short* __restrict__ O) {
  int pair = blockIdx.x;  // 0..15
  int bh = blockIdx.y;    // 0..31
  int t = threadIdx.x;
  int lane = t & 63;
  int w = t >> 6;
  int n16 = lane & 15, quad = lane >> 4;
  int r8 = lane >> 3, c8 = lane & 7;
  const unsigned short* Qb = Q + (size_t)bh * 2048 * 64;
  const unsigned short* Kb = Kk + (size_t)bh * 2048 * 64;
  const unsigned short* Vb = VT + (size_t)bh * 64 * 2048;

  __shared__ __align__(16) unsigned short sK[2][64 * 64];
  __shared__ __align__(16) unsigned short sV[2][64 * 64];
  __shared__ __align__(16) unsigned short sP[4][16 * 64];
  unsigned short* spW = sP[w];

  const float SCL2 = 0.125f * 1.44269504088896340736f;  // SCALE * log2(e)
  int b_ = bh >> 4, h_ = bh & 15;

  for (int pp = 0; pp < 2; ++pp) {
    int qt = pp ? 31 - pair : pair;
    int nk = qt + 1;

    bf16x8 aQ[2];
#pragma unroll
    for (int kb = 0; kb < 2; ++kb)
      aQ[kb] = *(const bf16x8*)(Qb + (size_t)(qt * 64 + w * 16 + n16) * 64 + kb * 32 + quad * 8);

    f32x4 o[4];
    float mst[4], lst[4];
#pragma unroll
    for (int ct = 0; ct < 4; ++ct) o[ct] = f32x4{0.f, 0.f, 0.f, 0.f};
#pragma unroll
    for (int r = 0; r < 4; ++r) { mst[r] = -3e38f; lst[r] = 0.f; }

    __syncthreads();  // pass A's last reads complete before re-staging buf 0
    // stage tile 0 into buf 0 (swizzled: lane fetches global chunk c8^r8)
    {
      const unsigned short* kg = Kb + (size_t)(w * 16) * 64;
      const unsigned short* vg = Vb + (size_t)(w * 16) * 2048;
#pragma unroll
      for (int i = 0; i < 2; ++i) {
        GLL16(kg + (size_t)(i * 8 + r8) * 64 + (c8 ^ r8) * 8, &sK[0][(w * 16 + i * 8) * 64]);
        GLL16(vg + (size_t)(i * 8 + r8) * 2048 + (c8 ^ r8) * 8, &sV[0][(w * 16 + i * 8) * 64]);
      }
    }

    for (int kt = 0; kt < nk; ++kt) {
      int buf = kt & 1;
      __syncthreads();  // drains this tile's GLL (in flight since last iter's compute)
      if (kt + 1 < nk) {  // prefetch next tile into other buffer, hidden under compute
        const unsigned short* kg = Kb + (size_t)((kt + 1) * 64 + w * 16) * 64;
        const unsigned short* vg = Vb + (size_t)(w * 16) * 2048 + (kt + 1) * 64;
#pragma unroll
        for (int i = 0; i < 2; ++i) {
          GLL16(kg + (size_t)(i * 8 + r8) * 64 + (c8 ^ r8) * 8, &sK[buf ^ 1][(w * 16 + i * 8) * 64]);
          GLL16(vg + (size_t)(i * 8 + r8) * 2048 + (c8 ^ r8) * 8, &sV[buf ^ 1][(w * 16 + i * 8) * 64]);
        }
      }

      // QK^T: 4 n-subtiles x 2 k-blocks
      f32x4 sc[4];
#pragma unroll
      for (int ns = 0; ns < 4; ++ns) {
        const unsigned short* kr = &sK[buf][(ns * 16 + n16) * 64];
        bf16x8 b0 = *(const bf16x8*)(kr + ((quad ^ (n16 & 7)) * 8));
        bf16x8 b1 = *(const bf16x8*)(kr + (((4 + quad) ^ (n16 & 7)) * 8));
        f32x4 zv = f32x4{0.f, 0.f, 0.f, 0.f};
        zv = __builtin_amdgcn_mfma_f32_16x16x32_bf16(aQ[0], b0, zv, 0, 0, 0);
        sc[ns] = __builtin_amdgcn_mfma_f32_16x16x32_bf16(aQ[1], b1, zv, 0, 0, 0);
      }

      float p[4][4];
#pragma unroll
      for (int r = 0; r < 4; ++r)
#pragma unroll
        for (int ns = 0; ns < 4; ++ns) p[r][ns] = sc[ns][r] * SCL2;
      if (kt == nk - 1) {  // wave-uniform: mask only the diagonal tile
        int rowg = qt * 64 + w * 16 + quad * 4;
#pragma unroll
        for (int r = 0; r < 4; ++r)
#pragma unroll
          for (int ns = 0; ns < 4; ++ns)
            if (kt * 64 + ns * 16 + n16 > rowg + r) p[r][ns] = -3e38f;
      }
      float rm[4], al[4], rs[4];
#pragma unroll
      for (int r = 0; r < 4; ++r)
        rm[r] = fmaxf(fmaxf(p[r][0], p[r][1]), fmaxf(p[r][2], p[r][3]));
#pragma unroll
      for (int off = 1; off < 16; off <<= 1)
#pragma unroll
        for (int r = 0; r < 4; ++r) rm[r] = fmaxf(rm[r], __shfl_xor(rm[r], off));
#pragma unroll
      for (int r = 0; r < 4; ++r) {
        float mn = fmaxf(mst[r], rm[r]);
        al[r] = exp2f(mst[r] - mn);
        mst[r] = mn;
        rs[r] = 0.f;
#pragma unroll
        for (int ns = 0; ns < 4; ++ns) { p[r][ns] = exp2f(p[r][ns] - mn); rs[r] += p[r][ns]; }
      }
#pragma unroll
      for (int off = 1; off < 16; off <<= 1)
#pragma unroll
        for (int r = 0; r < 4; ++r) rs[r] += __shfl_xor(rs[r], off);
#pragma unroll
      for (int r = 0; r < 4; ++r) lst[r] = lst[r] * al[r] + rs[r];
#pragma unroll
      for (int ct = 0; ct < 4; ++ct)
#pragma unroll
        for (int r = 0; r < 4; ++r) o[ct][r] *= al[r];

      // write P swizzled: slot(row,c) holds chunk c^(row&7)
#pragma unroll
      for (int r = 0; r < 4; ++r) {
        int roww = quad * 4 + r;
#pragma unroll
        for (int ns = 0; ns < 4; ++ns) {
          int cslot = (2 * ns + (n16 >> 3)) ^ (roww & 7);
          spW[roww * 64 + cslot * 8 + (n16 & 7)] = f2bf(p[r][ns]);
        }
      }
      __builtin_amdgcn_s_waitcnt(0xC07F);  // lgkmcnt(0) only: sP per-wave; prefetch stays in flight

      bf16x8 aP[2];
#pragma unroll
      for (int kb = 0; kb < 2; ++kb)
        aP[kb] = *(const bf16x8*)(&spW[n16 * 64 + (((kb * 4 + quad) ^ (n16 & 7)) * 8)]);
#pragma unroll
      for (int ct = 0; ct < 4; ++ct) {
        const unsigned short* vr = &sV[buf][(ct * 16 + n16) * 64];
        bf16x8 v0 = *(const bf16x8*)(vr + ((quad ^ (n16 & 7)) * 8));
        bf16x8 v1 = *(const bf16x8*)(vr + (((4 + quad) ^ (n16 & 7)) * 8));
        o[ct] = __builtin_amdgcn_mfma_f32_16x16x32_bf16(aP[0], v0, o[ct], 0, 0, 0);
        o[ct] = __builtin_amdgcn_mfma_f32_16x16x32_bf16(aP[1], v1, o[ct], 0, 0, 0);
      }
    }

#pragma unroll
    for (int ct = 0; ct < 4; ++ct)
#pragma unroll
      for (int r = 0; r < 4; ++r) {
        int s_ = qt * 64 + w * 16 + quad * 4 + r;
        float v = o[ct][r] / lst[r];
        O[((size_t)b_ * 2048 + s_) * 1024 + h_ * 64 + ct * 16 + n16] = f2bf(v);
      }
  }
}

// ---------------- launch ----------------
extern "C" void kernel_launch(void* const* d_in, const int* in_sizes, int n_in,
                              void* d_out, int out_size, void* d_ws, size_t ws_size,
                              hipStream_t stream) {
  const float* X    = (const float*)d_in[0];
  const int*   pos  = (const int*)d_in[2];
  const float* cosb = (const float*)d_in[3];
  const float* sinb = (const float*)d_in[4];
  const float* Wq   = (const float*)d_in[5];
  const float* Wk   = (const float*)d_in[6];
  const float* Wv   = (const float*)d_in[7];
  const float* Wo   = (const float*)d_in[8];
  float* out = (float*)d_out;

  char* ws = (char*)d_ws;
  const size_t SZ_X = 4096UL * 1024 * 2;
  const size_t SZ_W = 1024UL * 1024 * 2;
  unsigned short* Xbf = (unsigned short*)(ws);
  unsigned short* WTq = (unsigned short*)(ws + SZ_X);
  unsigned short* WTk = (unsigned short*)(ws + SZ_X + SZ_W);
  unsigned short* WTv = (unsigned short*)(ws + SZ_X + 2 * SZ_W);
  unsigned short* WTo = (unsigned short*)(ws + SZ_X + 3 * SZ_W);
  unsigned short* Qbf = (unsigned short*)(ws + SZ_X + 4 * SZ_W);
  unsigned short* Kbf = (unsigned short*)(ws + 2 * SZ_X + 4 * SZ_W);
  unsigned short* Vbf = (unsigned short*)(ws + 3 * SZ_X + 4 * SZ_W);
  unsigned short* VTr = (unsigned short*)(ws + 4 * SZ_X + 4 * SZ_W);
  unsigned short* Obf = (unsigned short*)(ws + 5 * SZ_X + 4 * SZ_W);

  dim3 tb(32, 8);

  cast_x_kernel<<<2048, 256, 0, stream>>>(X, Xbf);
  tpose_kernel<float><<<dim3(32, 32, 1), tb, 0, stream>>>(Wq, WTq, 1024, 1024);
  tpose_kernel<float><<<dim3(32, 32, 1), tb, 0, stream>>>(Wk, WTk, 1024, 1024);
  tpose_kernel<float><<<dim3(32, 32, 1), tb, 0, stream>>>(Wv, WTv, 1024, 1024);
  tpose_kernel<float><<<dim3(32, 32, 1), tb, 0, stream>>>(Wo, WTo, 1024, 1024);

  // QKV projections + fused RoPE (z: 0=Q,1=K,2=V)
  gemm128_kernel<1><<<dim3(8, 32, 3), 256, 0, stream>>>(Xbf, WTq, WTk, WTv,
                                                        nullptr, Qbf, Kbf, Vbf,
                                                        pos, cosb, sinb);

  tpose_kernel<unsigned short><<<dim3(2, 64, 32), tb, 0, stream>>>(Vbf, VTr, 2048, 64);

  attn_kernel<<<dim3(16, 32), 256, 0, stream>>>(Qbf, Kbf, VTr, Obf);

  gemm128_kernel<0><<<dim3(8, 32, 1), 256, 0, stream>>>(Obf, WTo, nullptr, nullptr,
                                                        out, nullptr, nullptr, nullptr,
                                                        nullptr, nullptr, nullptr);
}

// Round 5
// 253.160 us; speedup vs baseline: 1.6458x; 1.0581x over previous
//
#include <hip/hip_runtime.h>

typedef __bf16 bf16x8 __attribute__((ext_vector_type(8)));
typedef float  f32x4  __attribute__((ext_vector_type(4)));
typedef unsigned short ushortx8 __attribute__((ext_vector_type(8)));

static __device__ __forceinline__ unsigned short f2bf(float f) {
  unsigned int u = __builtin_bit_cast(unsigned int, f);
  u += 0x7FFFu + ((u >> 16) & 1u);
  return (unsigned short)(u >> 16);
}
static __device__ __forceinline__ unsigned short f2bf_fast(float f) {  // round-half-up, 2 insts
  unsigned int u = __builtin_bit_cast(unsigned int, f);
  return (unsigned short)((u + 0x8000u) >> 16);
}

#define GLL16(gp, lp) __builtin_amdgcn_global_load_lds(                       \
    (const __attribute__((address_space(1))) void*)(gp),                      \
    (__attribute__((address_space(3))) void*)(lp), 16, 0, 0)

// ---------------- cast X fp32 -> bf16 ----------------
__global__ __launch_bounds__(256) void cast_x_kernel(const float* __restrict__ x,
                                                     unsigned short* __restrict__ o) {
  long i = ((long)blockIdx.x * 256 + threadIdx.x) * 8;
  float4 f0 = *(const float4*)(x + i);
  float4 f1 = *(const float4*)(x + i + 4);
  ushortx8 u;
  u[0] = f2bf(f0.x); u[1] = f2bf(f0.y); u[2] = f2bf(f0.z); u[3] = f2bf(f0.w);
  u[4] = f2bf(f1.x); u[5] = f2bf(f1.y); u[6] = f2bf(f1.z); u[7] = f2bf(f1.w);
  *(ushortx8*)(o + i) = u;
}

// ---------------- merged weight transpose: 4 matrices fp32 [1024][1024] -> bf16 [C][R] ----
__global__ __launch_bounds__(256) void tpose_w_kernel(const float* __restrict__ W0,
                                                      const float* __restrict__ W1,
                                                      const float* __restrict__ W2,
                                                      const float* __restrict__ W3,
                                                      unsigned short* __restrict__ D0,
                                                      unsigned short* __restrict__ D1,
                                                      unsigned short* __restrict__ D2,
                                                      unsigned short* __restrict__ D3) {
  int z = blockIdx.z;
  const float* src = (z == 0) ? W0 : (z == 1) ? W1 : (z == 2) ? W2 : W3;
  unsigned short* dst = (z == 0) ? D0 : (z == 1) ? D1 : (z == 2) ? D2 : D3;
  const int R = 1024, C = 1024;
  __shared__ unsigned short t[32][33];
  int c = blockIdx.x * 32 + threadIdx.x;
#pragma unroll
  for (int i = 0; i < 4; ++i) {
    int r = blockIdx.y * 32 + threadIdx.y + i * 8;
    t[threadIdx.y + i * 8][threadIdx.x] = f2bf(src[(size_t)r * C + c]);
  }
  __syncthreads();
  int rr = blockIdx.y * 32 + threadIdx.x;
#pragma unroll
  for (int i = 0; i < 4; ++i) {
    int cc = blockIdx.x * 32 + threadIdx.y + i * 8;
    dst[(size_t)cc * R + rr] = t[threadIdx.x][threadIdx.y + i * 8];
  }
}

// ---------------- transpose bf16: src [R][C] -> dst [C][R] (for V) ----------------
__global__ __launch_bounds__(256) void tpose_kernel(const unsigned short* __restrict__ src,
                                                    unsigned short* __restrict__ dst,
                                                    int R, int C) {
  size_t moff = (size_t)blockIdx.z * (size_t)R * (size_t)C;
  src += moff; dst += moff;
  __shared__ unsigned short t[32][33];
  int c = blockIdx.x * 32 + threadIdx.x;
#pragma unroll
  for (int i = 0; i < 4; ++i) {
    int r = blockIdx.y * 32 + threadIdx.y + i * 8;
    t[threadIdx.y + i * 8][threadIdx.x] = src[(size_t)r * C + c];
  }
  __syncthreads();
  int rr = blockIdx.y * 32 + threadIdx.x;
#pragma unroll
  for (int i = 0; i < 4; ++i) {
    int cc = blockIdx.x * 32 + threadIdx.y + i * 8;
    dst[(size_t)cc * R + rr] = t[threadIdx.x][threadIdx.y + i * 8];
  }
}

// ---------------- GEMM m97-style: 128x128 tile, BK=64, global_load_lds, XOR-swizzled LDS ----
template <int MODE>
__global__ __launch_bounds__(256) void gemm128_kernel(
    const unsigned short* __restrict__ A,
    const unsigned short* __restrict__ BT0,
    const unsigned short* __restrict__ BT1,
    const unsigned short* __restrict__ BT2,
    float* __restrict__ outF,
    unsigned short* __restrict__ outQ,
    unsigned short* __restrict__ outK,
    unsigned short* __restrict__ outV,
    const int* __restrict__ pos_ids,
    const float* __restrict__ cosb,
    const float* __restrict__ sinb) {
  const int K = 1024, N = 1024;
  int z = blockIdx.z;
  const unsigned short* BT = (MODE == 0 || z == 0) ? BT0 : (z == 1 ? BT1 : BT2);
  int n0 = blockIdx.x * 128, m0 = blockIdx.y * 128;
  int t = threadIdx.x, lane = t & 63, w = t >> 6;
  int wy = w >> 1, wx = w & 1;
  int n16 = lane & 15, quad = lane >> 4;
  __shared__ __align__(16) unsigned short sA[128 * 64];
  __shared__ __align__(16) unsigned short sB[128 * 64];

  int r8 = lane >> 3, c8 = lane & 7;
  int srow = w * 32 + r8;
  const char* gA = (const char*)(A + (size_t)(m0 + srow) * K) + (c8 ^ r8) * 16;
  const char* gB = (const char*)(BT + (size_t)(n0 + srow) * K) + (c8 ^ r8) * 16;

  f32x4 acc[4][4];
#pragma unroll
  for (int i = 0; i < 4; ++i)
#pragma unroll
    for (int j = 0; j < 4; ++j) acc[i][j] = f32x4{0.f, 0.f, 0.f, 0.f};

  for (int kk = 0; kk < K; kk += 64) {
    __syncthreads();
#pragma unroll
    for (int i = 0; i < 4; ++i) {
      GLL16(gA + (size_t)kk * 2 + (size_t)i * 8 * K * 2, sA + (w * 32 + i * 8) * 64);
      GLL16(gB + (size_t)kk * 2 + (size_t)i * 8 * K * 2, sB + (w * 32 + i * 8) * 64);
    }
    __syncthreads();
#pragma unroll
    for (int kb = 0; kb < 2; ++kb) {
      bf16x8 a[4], b[4];
#pragma unroll
      for (int i = 0; i < 4; ++i) {
        int ra = wy * 64 + i * 16 + n16;
        int rb = wx * 64 + i * 16 + n16;
        int cs = ((kb * 4 + quad) ^ (n16 & 7)) * 8;
        a[i] = *(const bf16x8*)(&sA[ra * 64 + cs]);
        b[i] = *(const bf16x8*)(&sB[rb * 64 + cs]);
      }
#pragma unroll
      for (int mt = 0; mt < 4; ++mt)
#pragma unroll
        for (int nt = 0; nt < 4; ++nt)
          acc[mt][nt] = __builtin_amdgcn_mfma_f32_16x16x32_bf16(a[mt], b[nt], acc[mt][nt], 0, 0, 0);
    }
  }

  if (MODE == 1 && z < 2) {  // fused RoPE on Q/K
#pragma unroll
    for (int mt = 0; mt < 4; ++mt)
#pragma unroll
      for (int r = 0; r < 4; ++r) {
        int row = m0 + wy * 64 + mt * 16 + quad * 4 + r;
        int b = row >> 11, s = row & 2047;
        int pos = pos_ids[b * 2048 + s];
        const float* cb = cosb + (size_t)pos * 64;
        const float* sb = sinb + (size_t)pos * 64;
#pragma unroll
        for (int nt = 0; nt < 2; ++nt) {
          int d0 = nt * 16 + n16;
          float c0 = cb[d0], s0 = sb[d0], c1 = cb[d0 + 32], s1 = sb[d0 + 32];
          float x0 = acc[mt][nt][r], x1 = acc[mt][nt + 2][r];
          acc[mt][nt][r]     = x0 * c0 - x1 * s0;
          acc[mt][nt + 2][r] = x1 * c1 + x0 * s1;
        }
      }
  }

#pragma unroll
  for (int mt = 0; mt < 4; ++mt)
#pragma unroll
    for (int nt = 0; nt < 4; ++nt)
#pragma unroll
      for (int r = 0; r < 4; ++r) {
        int row = m0 + wy * 64 + mt * 16 + quad * 4 + r;
        int col = n0 + wx * 64 + nt * 16 + n16;
        float v = acc[mt][nt][r];
        if (MODE == 0) {
          outF[(size_t)row * N + col] = v;
        } else {
          unsigned short* dst = (z == 0) ? outQ : (z == 1 ? outK : outV);
          int b = row >> 11, s = row & 2047, h = col >> 6, d = col & 63;
          dst[(((size_t)b * 16 + h) * 2048 + s) * 64 + d] = f2bf(v);
        }
      }
}

// ---------------- Flash attention v5: static dbuf (true async prefetch), deferred l-reduce ----
// Q,K bf16 [B*NH, S, 64]; VT bf16 [B*NH, 64, S]; O bf16 [B*S, NH*64]
// grid (pair=16, bh=32); block handles qt=pair and qt=31-pair -> 33 iters each.
__global__ __launch_bounds__(256) void attn_kernel(const unsigned short* __restrict__ Q,
                                                   const unsigned short* __restrict__ Kk,
                                                   const unsigned short* __restrict__ VT,
                                                   unsigned short* __restrict__ O) {
  int pair = blockIdx.x;
  int bh = blockIdx.y;
  int t = threadIdx.x;
  int lane = t & 63;
  int w = t >> 6;
  int n16 = lane & 15, quad = lane >> 4;
  int r8 = lane >> 3, c8 = lane & 7;
  const unsigned short* Qb = Q + (size_t)bh * 2048 * 64;
  const unsigned short* Kb = Kk + (size_t)bh * 2048 * 64;
  const unsigned short* Vb = VT + (size_t)bh * 64 * 2048;

  // statically distinct buffers: lets alias analysis keep prefetch loads in flight
  __shared__ __align__(16) unsigned short sK0[64 * 64];
  __shared__ __align__(16) unsigned short sK1[64 * 64];
  __shared__ __align__(16) unsigned short sV0[64 * 64];
  __shared__ __align__(16) unsigned short sV1[64 * 64];
  __shared__ __align__(16) unsigned short sP[4][16 * 64];
  unsigned short* spW = sP[w];

  const float SCL2 = 0.125f * 1.44269504088896340736f;  // SCALE * log2(e)
  int b_ = bh >> 4, h_ = bh & 15;

#define STAGE(kt_, SKB, SVB)                                                              \
  do {                                                                                    \
    const unsigned short* kg_ = Kb + (size_t)((kt_) * 64 + w * 16) * 64;                  \
    const unsigned short* vg_ = Vb + (size_t)(w * 16) * 2048 + (kt_) * 64;                \
    GLL16(kg_ + (size_t)r8 * 64 + (c8 ^ r8) * 8, &SKB[(w * 16) * 64]);                    \
    GLL16(kg_ + (size_t)(8 + r8) * 64 + (c8 ^ r8) * 8, &SKB[(w * 16 + 8) * 64]);          \
    GLL16(vg_ + (size_t)r8 * 2048 + (c8 ^ r8) * 8, &SVB[(w * 16) * 64]);                  \
    GLL16(vg_ + (size_t)(8 + r8) * 2048 + (c8 ^ r8) * 8, &SVB[(w * 16 + 8) * 64]);        \
  } while (0)

#define COMPUTE(kt_, SKB, SVB)                                                            \
  do {                                                                                    \
    f32x4 sc[4];                                                                          \
    _Pragma("unroll") for (int ns = 0; ns < 4; ++ns) {                                    \
      const unsigned short* kr = &SKB[(ns * 16 + n16) * 64];                              \
      bf16x8 bk0 = *(const bf16x8*)(kr + ((quad ^ (n16 & 7)) * 8));                       \
      bf16x8 bk1 = *(const bf16x8*)(kr + (((4 + quad) ^ (n16 & 7)) * 8));                 \
      f32x4 zv = f32x4{0.f, 0.f, 0.f, 0.f};                                               \
      zv = __builtin_amdgcn_mfma_f32_16x16x32_bf16(aQ[0], bk0, zv, 0, 0, 0);              \
      sc[ns] = __builtin_amdgcn_mfma_f32_16x16x32_bf16(aQ[1], bk1, zv, 0, 0, 0);          \
    }                                                                                     \
    float p[4][4];                                                                        \
    _Pragma("unroll") for (int r = 0; r < 4; ++r)                                         \
      _Pragma("unroll") for (int ns = 0; ns < 4; ++ns) p[r][ns] = sc[ns][r] * SCL2;       \
    if ((kt_) == nk - 1) {                                                                \
      int rowg = qt * 64 + w * 16 + quad * 4;                                             \
      _Pragma("unroll") for (int r = 0; r < 4; ++r)                                       \
        _Pragma("unroll") for (int ns = 0; ns < 4; ++ns)                                  \
          if ((kt_) * 64 + ns * 16 + n16 > rowg + r) p[r][ns] = -3e38f;                   \
    }                                                                                     \
    float rm[4], al[4];                                                                   \
    _Pragma("unroll") for (int r = 0; r < 4; ++r)                                         \
      rm[r] = fmaxf(fmaxf(p[r][0], p[r][1]), fmaxf(p[r][2], p[r][3]));                    \
    _Pragma("unroll") for (int off = 1; off < 16; off <<= 1)                              \
      _Pragma("unroll") for (int r = 0; r < 4; ++r)                                       \
        rm[r] = fmaxf(rm[r], __shfl_xor(rm[r], off));                                     \
    _Pragma("unroll") for (int r = 0; r < 4; ++r) {                                       \
      float mn = fmaxf(mst[r], rm[r]);                                                    \
      al[r] = exp2f(mst[r] - mn);                                                         \
      mst[r] = mn;                                                                        \
      float rs = 0.f;                                                                     \
      _Pragma("unroll") for (int ns = 0; ns < 4; ++ns) {                                  \
        p[r][ns] = exp2f(p[r][ns] - mn);                                                  \
        rs += p[r][ns];                                                                   \
      }                                                                                   \
      lst[r] = lst[r] * al[r] + rs; /* lane-partial; cross-lane reduce deferred */        \
    }                                                                                     \
    _Pragma("unroll") for (int r = 0; r < 4; ++r) {                                       \
      int roww = quad * 4 + r;                                                            \
      _Pragma("unroll") for (int ns = 0; ns < 4; ++ns) {                                  \
        int cslot = (2 * ns + (n16 >> 3)) ^ (roww & 7);                                   \
        spW[roww * 64 + cslot * 8 + (n16 & 7)] = f2bf_fast(p[r][ns]);                     \
      }                                                                                   \
    }                                                                                     \
    _Pragma("unroll") for (int ct = 0; ct < 4; ++ct)                                      \
      _Pragma("unroll") for (int r = 0; r < 4; ++r) o[ct][r] *= al[r];                    \
    __builtin_amdgcn_s_waitcnt(0xC07F); /* lgkmcnt(0) only; prefetch stays in flight */   \
    bf16x8 aP0 = *(const bf16x8*)(&spW[n16 * 64 + ((quad ^ (n16 & 7)) * 8)]);             \
    bf16x8 aP1 = *(const bf16x8*)(&spW[n16 * 64 + (((4 + quad) ^ (n16 & 7)) * 8)]);       \
    _Pragma("unroll") for (int ct = 0; ct < 4; ++ct) {                                    \
      const unsigned short* vr = &SVB[(ct * 16 + n16) * 64];                              \
      bf16x8 v0 = *(const bf16x8*)(vr + ((quad ^ (n16 & 7)) * 8));                        \
      bf16x8 v1 = *(const bf16x8*)(vr + (((4 + quad) ^ (n16 & 7)) * 8));                  \
      o[ct] = __builtin_amdgcn_mfma_f32_16x16x32_bf16(aP0, v0, o[ct], 0, 0, 0);           \
      o[ct] = __builtin_amdgcn_mfma_f32_16x16x32_bf16(aP1, v1, o[ct], 0, 0, 0);           \
    }                                                                                     \
  } while (0)

  for (int pp = 0; pp < 2; ++pp) {
    int qt = pp ? 31 - pair : pair;
    int nk = qt + 1;

    bf16x8 aQ[2];
#pragma unroll
    for (int kb = 0; kb < 2; ++kb)
      aQ[kb] = *(const bf16x8*)(Qb + (size_t)(qt * 64 + w * 16 + n16) * 64 + kb * 32 + quad * 8);

    f32x4 o[4];
    float mst[4], lst[4];
#pragma unroll
    for (int ct = 0; ct < 4; ++ct) o[ct] = f32x4{0.f, 0.f, 0.f, 0.f};
#pragma unroll
    for (int r = 0; r < 4; ++r) { mst[r] = -3e38f; lst[r] = 0.f; }

    __syncthreads();  // prior pass reads done before restaging buf0
    STAGE(0, sK0, sV0);

    int kt = 0;
    while (true) {
      __syncthreads();  // drain loads into sK0/sV0
      if (kt + 1 < nk) STAGE(kt + 1, sK1, sV1);
      COMPUTE(kt, sK0, sV0);
      if (++kt == nk) break;
      __syncthreads();  // drain loads into sK1/sV1
      if (kt + 1 < nk) STAGE(kt + 1, sK0, sV0);
      COMPUTE(kt, sK1, sV1);
      if (++kt == nk) break;
    }

    // deferred l reduction (once per pass, not per k-tile)
#pragma unroll
    for (int off = 1; off < 16; off <<= 1)
#pragma unroll
      for (int r = 0; r < 4; ++r) lst[r] += __shfl_xor(lst[r], off);

#pragma unroll
    for (int ct = 0; ct < 4; ++ct)
#pragma unroll
      for (int r = 0; r < 4; ++r) {
        int s_ = qt * 64 + w * 16 + quad * 4 + r;
        float v = o[ct][r] / lst[r];
        O[((size_t)b_ * 2048 + s_) * 1024 + h_ * 64 + ct * 16 + n16] = f2bf(v);
      }
  }
#undef STAGE
#undef COMPUTE
}

// ---------------- launch ----------------
extern "C" void kernel_launch(void* const* d_in, const int* in_sizes, int n_in,
                              void* d_out, int out_size, void* d_ws, size_t ws_size,
                              hipStream_t stream) {
  const float* X    = (const float*)d_in[0];
  const int*   pos  = (const int*)d_in[2];
  const float* cosb = (const float*)d_in[3];
  const float* sinb = (const float*)d_in[4];
  const float* Wq   = (const float*)d_in[5];
  const float* Wk   = (const float*)d_in[6];
  const float* Wv   = (const float*)d_in[7];
  const float* Wo   = (const float*)d_in[8];
  float* out = (float*)d_out;

  char* ws = (char*)d_ws;
  const size_t SZ_X = 4096UL * 1024 * 2;
  const size_t SZ_W = 1024UL * 1024 * 2;
  unsigned short* Xbf = (unsigned short*)(ws);
  unsigned short* WTq = (unsigned short*)(ws + SZ_X);
  unsigned short* WTk = (unsigned short*)(ws + SZ_X + SZ_W);
  unsigned short* WTv = (unsigned short*)(ws + SZ_X + 2 * SZ_W);
  unsigned short* WTo = (unsigned short*)(ws + SZ_X + 3 * SZ_W);
  unsigned short* Qbf = (unsigned short*)(ws + SZ_X + 4 * SZ_W);
  unsigned short* Kbf = (unsigned short*)(ws + 2 * SZ_X + 4 * SZ_W);
  unsigned short* Vbf = (unsigned short*)(ws + 3 * SZ_X + 4 * SZ_W);
  unsigned short* VTr = (unsigned short*)(ws + 4 * SZ_X + 4 * SZ_W);
  unsigned short* Obf = (unsigned short*)(ws + 5 * SZ_X + 4 * SZ_W);

  cast_x_kernel<<<2048, 256, 0, stream>>>(X, Xbf);
  tpose_w_kernel<<<dim3(32, 32, 4), dim3(32, 8), 0, stream>>>(Wq, Wk, Wv, Wo,
                                                              WTq, WTk, WTv, WTo);

  gemm128_kernel<1><<<dim3(8, 32, 3), 256, 0, stream>>>(Xbf, WTq, WTk, WTv,
                                                        nullptr, Qbf, Kbf, Vbf,
                                                        pos, cosb, sinb);

  tpose_kernel<<<dim3(2, 64, 32), dim3(32, 8), 0, stream>>>(Vbf, VTr, 2048, 64);

  attn_kernel<<<dim3(16, 32), 256, 0, stream>>>(Qbf, Kbf, VTr, Obf);

  gemm128_kernel<0><<<dim3(8, 32, 1), 256, 0, stream>>>(Obf, WTo, nullptr, nullptr,
                                                        out, nullptr, nullptr, nullptr,
                                                        nullptr, nullptr, nullptr);
}

// Round 6
// 234.408 us; speedup vs baseline: 1.7775x; 1.0800x over previous
//
#include <hip/hip_runtime.h>

typedef __bf16 bf16x8 __attribute__((ext_vector_type(8)));
typedef float  f32x4  __attribute__((ext_vector_type(4)));
typedef unsigned short ushortx8 __attribute__((ext_vector_type(8)));
typedef unsigned short ushortx4 __attribute__((ext_vector_type(4)));

static __device__ __forceinline__ unsigned short f2bf(float f) {
  unsigned int u = __builtin_bit_cast(unsigned int, f);
  u += 0x7FFFu + ((u >> 16) & 1u);
  return (unsigned short)(u >> 16);
}
static __device__ __forceinline__ unsigned short f2bf_fast(float f) {  // round-half-up
  unsigned int u = __builtin_bit_cast(unsigned int, f);
  return (unsigned short)((u + 0x8000u) >> 16);
}

#define GLL16(gp, lp) __builtin_amdgcn_global_load_lds(                       \
    (const __attribute__((address_space(1))) void*)(gp),                      \
    (__attribute__((address_space(3))) void*)(lp), 16, 0, 0)

// ---------------- cast X fp32 -> bf16 ----------------
__global__ __launch_bounds__(256) void cast_x_kernel(const float* __restrict__ x,
                                                     unsigned short* __restrict__ o) {
  long i = ((long)blockIdx.x * 256 + threadIdx.x) * 8;
  float4 f0 = *(const float4*)(x + i);
  float4 f1 = *(const float4*)(x + i + 4);
  ushortx8 u;
  u[0] = f2bf(f0.x); u[1] = f2bf(f0.y); u[2] = f2bf(f0.z); u[3] = f2bf(f0.w);
  u[4] = f2bf(f1.x); u[5] = f2bf(f1.y); u[6] = f2bf(f1.z); u[7] = f2bf(f1.w);
  *(ushortx8*)(o + i) = u;
}

// ---------------- merged weight transpose: 4 matrices fp32 [1024][1024] -> bf16 [C][R] ----
__global__ __launch_bounds__(256) void tpose_w_kernel(const float* __restrict__ W0,
                                                      const float* __restrict__ W1,
                                                      const float* __restrict__ W2,
                                                      const float* __restrict__ W3,
                                                      unsigned short* __restrict__ D0,
                                                      unsigned short* __restrict__ D1,
                                                      unsigned short* __restrict__ D2,
                                                      unsigned short* __restrict__ D3) {
  int z = blockIdx.z;
  const float* src = (z == 0) ? W0 : (z == 1) ? W1 : (z == 2) ? W2 : W3;
  unsigned short* dst = (z == 0) ? D0 : (z == 1) ? D1 : (z == 2) ? D2 : D3;
  const int R = 1024, C = 1024;
  __shared__ unsigned short t[32][33];
  int c = blockIdx.x * 32 + threadIdx.x;
#pragma unroll
  for (int i = 0; i < 4; ++i) {
    int r = blockIdx.y * 32 + threadIdx.y + i * 8;
    t[threadIdx.y + i * 8][threadIdx.x] = f2bf(src[(size_t)r * C + c]);
  }
  __syncthreads();
  int rr = blockIdx.y * 32 + threadIdx.x;
#pragma unroll
  for (int i = 0; i < 4; ++i) {
    int cc = blockIdx.x * 32 + threadIdx.y + i * 8;
    dst[(size_t)cc * R + rr] = t[threadIdx.x][threadIdx.y + i * 8];
  }
}

// ---------------- transpose bf16: src [R][C] -> dst [C][R] (for V) ----------------
__global__ __launch_bounds__(256) void tpose_kernel(const unsigned short* __restrict__ src,
                                                    unsigned short* __restrict__ dst,
                                                    int R, int C) {
  size_t moff = (size_t)blockIdx.z * (size_t)R * (size_t)C;
  src += moff; dst += moff;
  __shared__ unsigned short t[32][33];
  int c = blockIdx.x * 32 + threadIdx.x;
#pragma unroll
  for (int i = 0; i < 4; ++i) {
    int r = blockIdx.y * 32 + threadIdx.y + i * 8;
    t[threadIdx.y + i * 8][threadIdx.x] = src[(size_t)r * C + c];
  }
  __syncthreads();
  int rr = blockIdx.y * 32 + threadIdx.x;
#pragma unroll
  for (int i = 0; i < 4; ++i) {
    int cc = blockIdx.x * 32 + threadIdx.y + i * 8;
    dst[(size_t)cc * R + rr] = t[threadIdx.x][threadIdx.y + i * 8];
  }
}

// ---------------- GEMM m97-style: 128x128 tile, BK=64, global_load_lds, XOR-swizzled LDS ----
template <int MODE>
__global__ __launch_bounds__(256) void gemm128_kernel(
    const unsigned short* __restrict__ A,
    const unsigned short* __restrict__ BT0,
    const unsigned short* __restrict__ BT1,
    const unsigned short* __restrict__ BT2,
    float* __restrict__ outF,
    unsigned short* __restrict__ outQ,
    unsigned short* __restrict__ outK,
    unsigned short* __restrict__ outV,
    const int* __restrict__ pos_ids,
    const float* __restrict__ cosb,
    const float* __restrict__ sinb) {
  const int K = 1024, N = 1024;
  int z = blockIdx.z;
  const unsigned short* BT = (MODE == 0 || z == 0) ? BT0 : (z == 1 ? BT1 : BT2);
  int n0 = blockIdx.x * 128, m0 = blockIdx.y * 128;
  int t = threadIdx.x, lane = t & 63, w = t >> 6;
  int wy = w >> 1, wx = w & 1;
  int n16 = lane & 15, quad = lane >> 4;
  __shared__ __align__(16) unsigned short sA[128 * 64];
  __shared__ __align__(16) unsigned short sB[128 * 64];

  int r8 = lane >> 3, c8 = lane & 7;
  int srow = w * 32 + r8;
  const char* gA = (const char*)(A + (size_t)(m0 + srow) * K) + (c8 ^ r8) * 16;
  const char* gB = (const char*)(BT + (size_t)(n0 + srow) * K) + (c8 ^ r8) * 16;

  f32x4 acc[4][4];
#pragma unroll
  for (int i = 0; i < 4; ++i)
#pragma unroll
    for (int j = 0; j < 4; ++j) acc[i][j] = f32x4{0.f, 0.f, 0.f, 0.f};

  for (int kk = 0; kk < K; kk += 64) {
    __syncthreads();
#pragma unroll
    for (int i = 0; i < 4; ++i) {
      GLL16(gA + (size_t)kk * 2 + (size_t)i * 8 * K * 2, sA + (w * 32 + i * 8) * 64);
      GLL16(gB + (size_t)kk * 2 + (size_t)i * 8 * K * 2, sB + (w * 32 + i * 8) * 64);
    }
    __syncthreads();
#pragma unroll
    for (int kb = 0; kb < 2; ++kb) {
      bf16x8 a[4], b[4];
#pragma unroll
      for (int i = 0; i < 4; ++i) {
        int ra = wy * 64 + i * 16 + n16;
        int rb = wx * 64 + i * 16 + n16;
        int cs = ((kb * 4 + quad) ^ (n16 & 7)) * 8;
        a[i] = *(const bf16x8*)(&sA[ra * 64 + cs]);
        b[i] = *(const bf16x8*)(&sB[rb * 64 + cs]);
      }
#pragma unroll
      for (int mt = 0; mt < 4; ++mt)
#pragma unroll
        for (int nt = 0; nt < 4; ++nt)
          acc[mt][nt] = __builtin_amdgcn_mfma_f32_16x16x32_bf16(a[mt], b[nt], acc[mt][nt], 0, 0, 0);
    }
  }

  if (MODE == 1 && z < 2) {  // fused RoPE on Q/K
#pragma unroll
    for (int mt = 0; mt < 4; ++mt)
#pragma unroll
      for (int r = 0; r < 4; ++r) {
        int row = m0 + wy * 64 + mt * 16 + quad * 4 + r;
        int b = row >> 11, s = row & 2047;
        int pos = pos_ids[b * 2048 + s];
        const float* cb = cosb + (size_t)pos * 64;
        const float* sb = sinb + (size_t)pos * 64;
#pragma unroll
        for (int nt = 0; nt < 2; ++nt) {
          int d0 = nt * 16 + n16;
          float c0 = cb[d0], s0 = sb[d0], c1 = cb[d0 + 32], s1 = sb[d0 + 32];
          float x0 = acc[mt][nt][r], x1 = acc[mt][nt + 2][r];
          acc[mt][nt][r]     = x0 * c0 - x1 * s0;
          acc[mt][nt + 2][r] = x1 * c1 + x0 * s1;
        }
      }
  }

#pragma unroll
  for (int mt = 0; mt < 4; ++mt)
#pragma unroll
    for (int nt = 0; nt < 4; ++nt)
#pragma unroll
      for (int r = 0; r < 4; ++r) {
        int row = m0 + wy * 64 + mt * 16 + quad * 4 + r;
        int col = n0 + wx * 64 + nt * 16 + n16;
        float v = acc[mt][nt][r];
        if (MODE == 0) {
          outF[(size_t)row * N + col] = v;
        } else {
          unsigned short* dst = (z == 0) ? outQ : (z == 1 ? outK : outV);
          int b = row >> 11, s = row & 2047, h = col >> 6, d = col & 63;
          dst[(((size_t)b * 16 + h) * 2048 + s) * 64 + d] = f2bf(v);
        }
      }
}

// ---------------- Flash attention v6: S^T orientation (per-lane q-rows), 4 blk/CU ----
// Computes S^T = K·Q^T and O^T = V^T·P^T; lane (n16,quad) owns q-row n16, k = mt*16+quad*4+r.
// Q,K bf16 [B*NH, S, 64]; VT bf16 [B*NH, 64, S]; O bf16 [B*S, NH*64]
// grid (bh=32, qslot=32), qt = 31 - blockIdx.y (LPT). 4 waves x 16 q-rows.
__global__ __launch_bounds__(256) void attn_kernel(const unsigned short* __restrict__ Q,
                                                   const unsigned short* __restrict__ Kk,
                                                   const unsigned short* __restrict__ VT,
                                                   unsigned short* __restrict__ O) {
  int bh = blockIdx.x;
  int qt = (int)(gridDim.y - 1 - blockIdx.y);
  int t = threadIdx.x;
  int lane = t & 63;
  int w = t >> 6;
  int n16 = lane & 15, quad = lane >> 4;
  int r8 = lane >> 3, c8 = lane & 7;
  const unsigned short* Qb = Q + (size_t)bh * 2048 * 64;
  const unsigned short* Kb = Kk + (size_t)bh * 2048 * 64;
  const unsigned short* Vb = VT + (size_t)bh * 64 * 2048;

  __shared__ __align__(16) unsigned short sK0[64 * 64];
  __shared__ __align__(16) unsigned short sK1[64 * 64];
  __shared__ __align__(16) unsigned short sV0[64 * 64];
  __shared__ __align__(16) unsigned short sV1[64 * 64];
  __shared__ __align__(16) unsigned short sP[4][16 * 64];
  unsigned short* spW = sP[w];

  const float SCL2 = 0.125f * 1.44269504088896340736f;  // SCALE * log2(e)
  int b_ = bh >> 4, h_ = bh & 15;
  int nk = qt + 1;
  int qg = qt * 64 + w * 16 + n16;  // this lane's q-row

  // Q fragment: serves as MFMA B-operand (B[k=d][n=q]); same layout as A-frag.
  bf16x8 aQ[2];
#pragma unroll
  for (int kb = 0; kb < 2; ++kb)
    aQ[kb] = *(const bf16x8*)(Qb + (size_t)qg * 64 + kb * 32 + quad * 8);

  f32x4 o[4];
  float mst = -3e38f, lst = 0.f;
#pragma unroll
  for (int ct = 0; ct < 4; ++ct) o[ct] = f32x4{0.f, 0.f, 0.f, 0.f};

#define STAGE(kt_, SKB, SVB)                                                              \
  do {                                                                                    \
    const unsigned short* kg_ = Kb + (size_t)((kt_) * 64 + w * 16) * 64;                  \
    const unsigned short* vg_ = Vb + (size_t)(w * 16) * 2048 + (kt_) * 64;                \
    GLL16(kg_ + (size_t)r8 * 64 + (c8 ^ r8) * 8, &SKB[(w * 16) * 64]);                    \
    GLL16(kg_ + (size_t)(8 + r8) * 64 + (c8 ^ r8) * 8, &SKB[(w * 16 + 8) * 64]);          \
    GLL16(vg_ + (size_t)r8 * 2048 + (c8 ^ r8) * 8, &SVB[(w * 16) * 64]);                  \
    GLL16(vg_ + (size_t)(8 + r8) * 2048 + (c8 ^ r8) * 8, &SVB[(w * 16 + 8) * 64]);        \
  } while (0)

#define COMPUTE(kt_, SKB, SVB)                                                            \
  do {                                                                                    \
    f32x4 sc[4]; /* S^T tiles: D[m=k][n=q], A=K-frag, B=Q-frag */                         \
    _Pragma("unroll") for (int mt = 0; mt < 4; ++mt) {                                    \
      const unsigned short* kr = &SKB[(mt * 16 + n16) * 64];                              \
      bf16x8 ka0 = *(const bf16x8*)(kr + ((quad ^ (n16 & 7)) * 8));                       \
      bf16x8 ka1 = *(const bf16x8*)(kr + (((4 + quad) ^ (n16 & 7)) * 8));                 \
      f32x4 zv = f32x4{0.f, 0.f, 0.f, 0.f};                                               \
      zv = __builtin_amdgcn_mfma_f32_16x16x32_bf16(ka0, aQ[0], zv, 0, 0, 0);              \
      sc[mt] = __builtin_amdgcn_mfma_f32_16x16x32_bf16(ka1, aQ[1], zv, 0, 0, 0);          \
    }                                                                                     \
    float p[4][4];                                                                        \
    _Pragma("unroll") for (int mt = 0; mt < 4; ++mt)                                      \
      _Pragma("unroll") for (int r = 0; r < 4; ++r) p[mt][r] = sc[mt][r] * SCL2;          \
    if ((kt_) == nk - 1) { /* diagonal tile: mask k > q */                                \
      int kb0 = (kt_) * 64 + quad * 4;                                                    \
      _Pragma("unroll") for (int mt = 0; mt < 4; ++mt)                                    \
        _Pragma("unroll") for (int r = 0; r < 4; ++r)                                     \
          if (kb0 + mt * 16 + r > qg) p[mt][r] = -3e38f;                                  \
    }                                                                                     \
    float rm = p[0][0];                                                                   \
    _Pragma("unroll") for (int mt = 0; mt < 4; ++mt)                                      \
      _Pragma("unroll") for (int r = 0; r < 4; ++r) rm = fmaxf(rm, p[mt][r]);             \
    rm = fmaxf(rm, __shfl_xor(rm, 16));                                                   \
    rm = fmaxf(rm, __shfl_xor(rm, 32));                                                   \
    float mn = fmaxf(mst, rm);                                                            \
    float al = exp2f(mst - mn);                                                           \
    mst = mn;                                                                             \
    float rs = 0.f;                                                                       \
    _Pragma("unroll") for (int mt = 0; mt < 4; ++mt)                                      \
      _Pragma("unroll") for (int r = 0; r < 4; ++r) {                                     \
        p[mt][r] = exp2f(p[mt][r] - mn);                                                  \
        rs += p[mt][r];                                                                   \
      }                                                                                   \
    lst = lst * al + rs; /* lane-partial over this quad's k; cross-quad deferred */       \
    _Pragma("unroll") for (int ct = 0; ct < 4; ++ct)                                      \
      _Pragma("unroll") for (int r = 0; r < 4; ++r) o[ct][r] *= al;                       \
    /* P store: row=q(n16), k contiguous; 16B-chunk XOR swizzle; 4 x b64 */               \
    _Pragma("unroll") for (int mt = 0; mt < 4; ++mt) {                                    \
      ushortx4 u;                                                                         \
      _Pragma("unroll") for (int r = 0; r < 4; ++r) u[r] = f2bf_fast(p[mt][r]);           \
      int ch = (mt * 2 + (quad >> 1)) ^ (n16 & 7);                                        \
      *(ushortx4*)(&spW[n16 * 64 + ch * 8 + (quad & 1) * 4]) = u;                         \
    }                                                                                     \
    __builtin_amdgcn_s_waitcnt(0xC07F); /* lgkmcnt(0); GLL prefetch (vmcnt) in flight */  \
    bf16x8 aP0 = *(const bf16x8*)(&spW[n16 * 64 + ((quad ^ (n16 & 7)) * 8)]);             \
    bf16x8 aP1 = *(const bf16x8*)(&spW[n16 * 64 + (((4 + quad) ^ (n16 & 7)) * 8)]);       \
    _Pragma("unroll") for (int ct = 0; ct < 4; ++ct) {                                    \
      const unsigned short* vr = &SVB[(ct * 16 + n16) * 64];                              \
      bf16x8 va0 = *(const bf16x8*)(vr + ((quad ^ (n16 & 7)) * 8));                       \
      bf16x8 va1 = *(const bf16x8*)(vr + (((4 + quad) ^ (n16 & 7)) * 8));                 \
      o[ct] = __builtin_amdgcn_mfma_f32_16x16x32_bf16(va0, aP0, o[ct], 0, 0, 0);          \
      o[ct] = __builtin_amdgcn_mfma_f32_16x16x32_bf16(va1, aP1, o[ct], 0, 0, 0);          \
    }                                                                                     \
  } while (0)

  STAGE(0, sK0, sV0);
  int kt = 0;
  while (true) {
    __syncthreads();  // drain loads into sK0/sV0
    if (kt + 1 < nk) STAGE(kt + 1, sK1, sV1);
    COMPUTE(kt, sK0, sV0);
    if (++kt == nk) break;
    __syncthreads();  // drain loads into sK1/sV1
    if (kt + 1 < nk) STAGE(kt + 1, sK0, sV0);
    COMPUTE(kt, sK1, sV1);
    if (++kt == nk) break;
  }
#undef STAGE
#undef COMPUTE

  // deferred cross-quad l reduction (quads hold disjoint k-partials)
  lst += __shfl_xor(lst, 16);
  lst += __shfl_xor(lst, 32);
  float inv = 1.0f / lst;

  // O^T in C-layout: row=d=ct*16+quad*4+r, col=q=n16 -> 4 consecutive d per lane: b64 stores
#pragma unroll
  for (int ct = 0; ct < 4; ++ct) {
    ushortx4 u;
#pragma unroll
    for (int r = 0; r < 4; ++r) u[r] = f2bf(o[ct][r] * inv);
    size_t addr = ((size_t)b_ * 2048 + qg) * 1024 + h_ * 64 + ct * 16 + quad * 4;
    *(ushortx4*)(&O[addr]) = u;
  }
}

// ---------------- launch ----------------
extern "C" void kernel_launch(void* const* d_in, const int* in_sizes, int n_in,
                              void* d_out, int out_size, void* d_ws, size_t ws_size,
                              hipStream_t stream) {
  const float* X    = (const float*)d_in[0];
  const int*   pos  = (const int*)d_in[2];
  const float* cosb = (const float*)d_in[3];
  const float* sinb = (const float*)d_in[4];
  const float* Wq   = (const float*)d_in[5];
  const float* Wk   = (const float*)d_in[6];
  const float* Wv   = (const float*)d_in[7];
  const float* Wo   = (const float*)d_in[8];
  float* out = (float*)d_out;

  char* ws = (char*)d_ws;
  const size_t SZ_X = 4096UL * 1024 * 2;
  const size_t SZ_W = 1024UL * 1024 * 2;
  unsigned short* Xbf = (unsigned short*)(ws);
  unsigned short* WTq = (unsigned short*)(ws + SZ_X);
  unsigned short* WTk = (unsigned short*)(ws + SZ_X + SZ_W);
  unsigned short* WTv = (unsigned short*)(ws + SZ_X + 2 * SZ_W);
  unsigned short* WTo = (unsigned short*)(ws + SZ_X + 3 * SZ_W);
  unsigned short* Qbf = (unsigned short*)(ws + SZ_X + 4 * SZ_W);
  unsigned short* Kbf = (unsigned short*)(ws + 2 * SZ_X + 4 * SZ_W);
  unsigned short* Vbf = (unsigned short*)(ws + 3 * SZ_X + 4 * SZ_W);
  unsigned short* VTr = (unsigned short*)(ws + 4 * SZ_X + 4 * SZ_W);
  unsigned short* Obf = (unsigned short*)(ws + 5 * SZ_X + 4 * SZ_W);

  cast_x_kernel<<<2048, 256, 0, stream>>>(X, Xbf);
  tpose_w_kernel<<<dim3(32, 32, 4), dim3(32, 8), 0, stream>>>(Wq, Wk, Wv, Wo,
                                                              WTq, WTk, WTv, WTo);

  gemm128_kernel<1><<<dim3(8, 32, 3), 256, 0, stream>>>(Xbf, WTq, WTk, WTv,
                                                        nullptr, Qbf, Kbf, Vbf,
                                                        pos, cosb, sinb);

  tpose_kernel<<<dim3(2, 64, 32), dim3(32, 8), 0, stream>>>(Vbf, VTr, 2048, 64);

  attn_kernel<<<dim3(32, 32), 256, 0, stream>>>(Qbf, Kbf, VTr, Obf);

  gemm128_kernel<0><<<dim3(8, 32, 1), 256, 0, stream>>>(Obf, WTo, nullptr, nullptr,
                                                        out, nullptr, nullptr, nullptr,
                                                        nullptr, nullptr, nullptr);
}

// Round 7
// 229.978 us; speedup vs baseline: 1.8117x; 1.0193x over previous
//
#include <hip/hip_runtime.h>

typedef __bf16 bf16x8 __attribute__((ext_vector_type(8)));
typedef float  f32x4  __attribute__((ext_vector_type(4)));
typedef unsigned short ushortx8 __attribute__((ext_vector_type(8)));
typedef unsigned short ushortx4 __attribute__((ext_vector_type(4)));

static __device__ __forceinline__ unsigned short f2bf(float f) {
  unsigned int u = __builtin_bit_cast(unsigned int, f);
  u += 0x7FFFu + ((u >> 16) & 1u);
  return (unsigned short)(u >> 16);
}
static __device__ __forceinline__ unsigned short f2bf_fast(float f) {  // round-half-up
  unsigned int u = __builtin_bit_cast(unsigned int, f);
  return (unsigned short)((u + 0x8000u) >> 16);
}

#define GLL16(gp, lp) __builtin_amdgcn_global_load_lds(                       \
    (const __attribute__((address_space(1))) void*)(gp),                      \
    (__attribute__((address_space(3))) void*)(lp), 16, 0, 0)

// ---------------- prep: z<4 -> transpose+cast W; z>=4 -> cast X fp32->bf16 ----------------
__global__ __launch_bounds__(256) void prep_kernel(const float* __restrict__ X,
                                                   const float* __restrict__ W0,
                                                   const float* __restrict__ W1,
                                                   const float* __restrict__ W2,
                                                   const float* __restrict__ W3,
                                                   unsigned short* __restrict__ Xbf,
                                                   unsigned short* __restrict__ D0,
                                                   unsigned short* __restrict__ D1,
                                                   unsigned short* __restrict__ D2,
                                                   unsigned short* __restrict__ D3) {
  int z = blockIdx.z;
  if (z >= 4) {  // cast 4096x1024 fp32 -> bf16; z in {4,5}
    long bid = (long)(z - 4) * 1024 + blockIdx.y * 32 + blockIdx.x;
    int tl = threadIdx.y * 32 + threadIdx.x;
    long i = bid * 2048 + (long)tl * 8;
    float4 f0 = *(const float4*)(X + i);
    float4 f1 = *(const float4*)(X + i + 4);
    ushortx8 u;
    u[0] = f2bf(f0.x); u[1] = f2bf(f0.y); u[2] = f2bf(f0.z); u[3] = f2bf(f0.w);
    u[4] = f2bf(f1.x); u[5] = f2bf(f1.y); u[6] = f2bf(f1.z); u[7] = f2bf(f1.w);
    *(ushortx8*)(Xbf + i) = u;
    return;
  }
  const float* src = (z == 0) ? W0 : (z == 1) ? W1 : (z == 2) ? W2 : W3;
  unsigned short* dst = (z == 0) ? D0 : (z == 1) ? D1 : (z == 2) ? D2 : D3;
  const int R = 1024, C = 1024;
  __shared__ unsigned short t[32][33];
  int c = blockIdx.x * 32 + threadIdx.x;
#pragma unroll
  for (int i = 0; i < 4; ++i) {
    int r = blockIdx.y * 32 + threadIdx.y + i * 8;
    t[threadIdx.y + i * 8][threadIdx.x] = f2bf(src[(size_t)r * C + c]);
  }
  __syncthreads();
  int rr = blockIdx.y * 32 + threadIdx.x;
#pragma unroll
  for (int i = 0; i < 4; ++i) {
    int cc = blockIdx.x * 32 + threadIdx.y + i * 8;
    dst[(size_t)cc * R + rr] = t[threadIdx.x][threadIdx.y + i * 8];
  }
}

// ---------------- transpose bf16: src [R][C] -> dst [C][R] (for V) ----------------
__global__ __launch_bounds__(256) void tpose_kernel(const unsigned short* __restrict__ src,
                                                    unsigned short* __restrict__ dst,
                                                    int R, int C) {
  size_t moff = (size_t)blockIdx.z * (size_t)R * (size_t)C;
  src += moff; dst += moff;
  __shared__ unsigned short t[32][33];
  int c = blockIdx.x * 32 + threadIdx.x;
#pragma unroll
  for (int i = 0; i < 4; ++i) {
    int r = blockIdx.y * 32 + threadIdx.y + i * 8;
    t[threadIdx.y + i * 8][threadIdx.x] = src[(size_t)r * C + c];
  }
  __syncthreads();
  int rr = blockIdx.y * 32 + threadIdx.x;
#pragma unroll
  for (int i = 0; i < 4; ++i) {
    int cc = blockIdx.x * 32 + threadIdx.y + i * 8;
    dst[(size_t)cc * R + rr] = t[threadIdx.x][threadIdx.y + i * 8];
  }
}

// ---------------- GEMM: 128x128 tile, BK=64, static-dbuf async prefetch, XOR-swizzled LDS ----
template <int MODE>
__global__ __launch_bounds__(256) void gemm128_kernel(
    const unsigned short* __restrict__ A,
    const unsigned short* __restrict__ BT0,
    const unsigned short* __restrict__ BT1,
    const unsigned short* __restrict__ BT2,
    float* __restrict__ outF,
    unsigned short* __restrict__ outQ,
    unsigned short* __restrict__ outK,
    unsigned short* __restrict__ outV,
    const int* __restrict__ pos_ids,
    const float* __restrict__ cosb,
    const float* __restrict__ sinb) {
  const int K = 1024, N = 1024;
  int z = blockIdx.z;
  const unsigned short* BT = (MODE == 0 || z == 0) ? BT0 : (z == 1 ? BT1 : BT2);
  int n0 = blockIdx.x * 128, m0 = blockIdx.y * 128;
  int t = threadIdx.x, lane = t & 63, w = t >> 6;
  int wy = w >> 1, wx = w & 1;
  int n16 = lane & 15, quad = lane >> 4;
  __shared__ __align__(16) unsigned short sA0[128 * 64];
  __shared__ __align__(16) unsigned short sA1[128 * 64];
  __shared__ __align__(16) unsigned short sB0[128 * 64];
  __shared__ __align__(16) unsigned short sB1[128 * 64];

  int r8 = lane >> 3, c8 = lane & 7;
  int srow = w * 32 + r8;
  const char* gA = (const char*)(A + (size_t)(m0 + srow) * K) + (c8 ^ r8) * 16;
  const char* gB = (const char*)(BT + (size_t)(n0 + srow) * K) + (c8 ^ r8) * 16;

  f32x4 acc[4][4];
#pragma unroll
  for (int i = 0; i < 4; ++i)
#pragma unroll
    for (int j = 0; j < 4; ++j) acc[i][j] = f32x4{0.f, 0.f, 0.f, 0.f};

#define GSTAGE(kk_, SA, SB)                                                     \
  do {                                                                          \
    _Pragma("unroll") for (int i = 0; i < 4; ++i) {                             \
      GLL16(gA + (size_t)(kk_) * 2 + (size_t)i * 8 * K * 2,                     \
            SA + (w * 32 + i * 8) * 64);                                        \
      GLL16(gB + (size_t)(kk_) * 2 + (size_t)i * 8 * K * 2,                     \
            SB + (w * 32 + i * 8) * 64);                                        \
    }                                                                           \
  } while (0)

#define GCOMPUTE(SA, SB)                                                        \
  do {                                                                          \
    _Pragma("unroll") for (int kb = 0; kb < 2; ++kb) {                          \
      bf16x8 a[4], b[4];                                                        \
      _Pragma("unroll") for (int i = 0; i < 4; ++i) {                           \
        int ra = wy * 64 + i * 16 + n16;                                        \
        int rb = wx * 64 + i * 16 + n16;                                        \
        int cs = ((kb * 4 + quad) ^ (n16 & 7)) * 8;                             \
        a[i] = *(const bf16x8*)(&SA[ra * 64 + cs]);                             \
        b[i] = *(const bf16x8*)(&SB[rb * 64 + cs]);                             \
      }                                                                         \
      _Pragma("unroll") for (int mt = 0; mt < 4; ++mt)                          \
        _Pragma("unroll") for (int nt = 0; nt < 4; ++nt)                        \
          acc[mt][nt] =                                                         \
              __builtin_amdgcn_mfma_f32_16x16x32_bf16(a[mt], b[nt],             \
                                                      acc[mt][nt], 0, 0, 0);    \
    }                                                                           \
  } while (0)

  GSTAGE(0, sA0, sB0);
  for (int kk = 0; kk < K;) {
    __syncthreads();  // drains loads into sA0/sB0
    if (kk + 64 < K) GSTAGE(kk + 64, sA1, sB1);  // prefetch flies during compute
    GCOMPUTE(sA0, sB0);
    kk += 64;
    if (kk >= K) break;
    __syncthreads();  // drains loads into sA1/sB1
    if (kk + 64 < K) GSTAGE(kk + 64, sA0, sB0);
    GCOMPUTE(sA1, sB1);
    kk += 64;
  }
#undef GSTAGE
#undef GCOMPUTE

  if (MODE == 1 && z < 2) {  // fused RoPE on Q/K
#pragma unroll
    for (int mt = 0; mt < 4; ++mt)
#pragma unroll
      for (int r = 0; r < 4; ++r) {
        int row = m0 + wy * 64 + mt * 16 + quad * 4 + r;
        int b = row >> 11, s = row & 2047;
        int pos = pos_ids[b * 2048 + s];
        const float* cb = cosb + (size_t)pos * 64;
        const float* sb = sinb + (size_t)pos * 64;
#pragma unroll
        for (int nt = 0; nt < 2; ++nt) {
          int d0 = nt * 16 + n16;
          float c0 = cb[d0], s0 = sb[d0], c1 = cb[d0 + 32], s1 = sb[d0 + 32];
          float x0 = acc[mt][nt][r], x1 = acc[mt][nt + 2][r];
          acc[mt][nt][r]     = x0 * c0 - x1 * s0;
          acc[mt][nt + 2][r] = x1 * c1 + x0 * s1;
        }
      }
  }

#pragma unroll
  for (int mt = 0; mt < 4; ++mt)
#pragma unroll
    for (int nt = 0; nt < 4; ++nt)
#pragma unroll
      for (int r = 0; r < 4; ++r) {
        int row = m0 + wy * 64 + mt * 16 + quad * 4 + r;
        int col = n0 + wx * 64 + nt * 16 + n16;
        float v = acc[mt][nt][r];
        if (MODE == 0) {
          outF[(size_t)row * N + col] = v;
        } else {
          unsigned short* dst = (z == 0) ? outQ : (z == 1 ? outK : outV);
          int b = row >> 11, s = row & 2047, h = col >> 6, d = col & 63;
          dst[(((size_t)b * 16 + h) * 2048 + s) * 64 + d] = f2bf(v);
        }
      }
}

// ---------------- Flash attention v7: in-block split-k (8 waves), S^T orientation ----
// Group g in {0,1}: k-tiles [0,u) / [u,nk), u=ceil(nk/2). Partials merged via LDS.
// Q,K bf16 [B*NH, S, 64]; VT bf16 [B*NH, 64, S]; O bf16 [B*S, NH*64]
__global__ __launch_bounds__(512) void attn_kernel(const unsigned short* __restrict__ Q,
                                                   const unsigned short* __restrict__ Kk,
                                                   const unsigned short* __restrict__ VT,
                                                   unsigned short* __restrict__ O) {
  int bh = blockIdx.x;
  int qt = (int)(gridDim.y - 1 - blockIdx.y);  // LPT
  int t = threadIdx.x;
  int lane = t & 63;
  int w = t >> 6;          // 0..7
  int g = w >> 2;          // split group
  int w4 = w & 3;          // wave within group
  int n16 = lane & 15, quad = lane >> 4;
  int r8 = lane >> 3, c8 = lane & 7;
  const unsigned short* Qb = Q + (size_t)bh * 2048 * 64;
  const unsigned short* Kb = Kk + (size_t)bh * 2048 * 64;
  const unsigned short* Vb = VT + (size_t)bh * 64 * 2048;

  // [g][buf][K/V][64*64] flattened; per-wave accesses share the same g term, so
  // GLL(buf^1) vs ds_read(buf) differ by a constant -> provably disjoint.
  __shared__ __align__(16) unsigned short sKV[2 * 2 * 2 * 4096];
  __shared__ __align__(16) unsigned short sP[8][16 * 64];
  unsigned short* spW = sP[w];
  unsigned short* gBase = sKV + g * 16384;

  const float SCL2 = 0.125f * 1.44269504088896340736f;  // SCALE * log2(e)
  int b_ = bh >> 4, h_ = bh & 15;
  int nk = qt + 1;
  int u = (nk + 1) >> 1;
  int beg = g ? u : 0;
  int end = g ? nk : u;
  int qg = qt * 64 + w4 * 16 + n16;  // this lane's q-row

  bf16x8 aQ[2];
#pragma unroll
  for (int kb = 0; kb < 2; ++kb)
    aQ[kb] = *(const bf16x8*)(Qb + (size_t)qg * 64 + kb * 32 + quad * 8);

  f32x4 o[4];
  float mst = -3e38f, lst = 0.f;
#pragma unroll
  for (int ct = 0; ct < 4; ++ct) o[ct] = f32x4{0.f, 0.f, 0.f, 0.f};

#define ASTAGE(kt_, BUF)                                                                  \
  do {                                                                                    \
    const unsigned short* kg_ = Kb + (size_t)((kt_) * 64 + w4 * 16) * 64;                 \
    const unsigned short* vg_ = Vb + (size_t)(w4 * 16) * 2048 + (kt_) * 64;               \
    unsigned short* dK = gBase + (BUF) * 8192 + (w4 * 16) * 64;                           \
    unsigned short* dV = dK + 4096;                                                       \
    GLL16(kg_ + (size_t)r8 * 64 + (c8 ^ r8) * 8, dK);                                     \
    GLL16(kg_ + (size_t)(8 + r8) * 64 + (c8 ^ r8) * 8, dK + 8 * 64);                      \
    GLL16(vg_ + (size_t)r8 * 2048 + (c8 ^ r8) * 8, dV);                                   \
    GLL16(vg_ + (size_t)(8 + r8) * 2048 + (c8 ^ r8) * 8, dV + 8 * 64);                    \
  } while (0)

#define ACOMPUTE(kt_, BUF)                                                                \
  do {                                                                                    \
    const unsigned short* kB_ = gBase + (BUF) * 8192 + (w4 * 16) * 64 - (w4 * 16) * 64;   \
    const unsigned short* kT_ = gBase + (BUF) * 8192;                                     \
    const unsigned short* vT_ = kT_ + 4096;                                               \
    (void)kB_;                                                                            \
    f32x4 sc[4]; /* S^T: D[m=k][n=q], A=K-frag, B=Q-frag */                               \
    _Pragma("unroll") for (int mt = 0; mt < 4; ++mt) {                                    \
      const unsigned short* kr = &kT_[(mt * 16 + n16) * 64];                              \
      bf16x8 ka0 = *(const bf16x8*)(kr + ((quad ^ (n16 & 7)) * 8));                       \
      bf16x8 ka1 = *(const bf16x8*)(kr + (((4 + quad) ^ (n16 & 7)) * 8));                 \
      f32x4 zv = f32x4{0.f, 0.f, 0.f, 0.f};                                               \
      zv = __builtin_amdgcn_mfma_f32_16x16x32_bf16(ka0, aQ[0], zv, 0, 0, 0);              \
      sc[mt] = __builtin_amdgcn_mfma_f32_16x16x32_bf16(ka1, aQ[1], zv, 0, 0, 0);          \
    }                                                                                     \
    float p[4][4];                                                                        \
    _Pragma("unroll") for (int mt = 0; mt < 4; ++mt)                                      \
      _Pragma("unroll") for (int r = 0; r < 4; ++r) p[mt][r] = sc[mt][r] * SCL2;          \
    if ((kt_) == nk - 1) { /* diagonal tile: mask k > q */                                \
      int kb0 = (kt_) * 64 + quad * 4;                                                    \
      _Pragma("unroll") for (int mt = 0; mt < 4; ++mt)                                    \
        _Pragma("unroll") for (int r = 0; r < 4; ++r)                                     \
          if (kb0 + mt * 16 + r > qg) p[mt][r] = -3e38f;                                  \
    }                                                                                     \
    float rm = p[0][0];                                                                   \
    _Pragma("unroll") for (int mt = 0; mt < 4; ++mt)                                      \
      _Pragma("unroll") for (int r = 0; r < 4; ++r) rm = fmaxf(rm, p[mt][r]);             \
    rm = fmaxf(rm, __shfl_xor(rm, 16));                                                   \
    rm = fmaxf(rm, __shfl_xor(rm, 32));                                                   \
    float mn = fmaxf(mst, rm);                                                            \
    float al = exp2f(mst - mn);                                                           \
    mst = mn;                                                                             \
    float rs = 0.f;                                                                       \
    _Pragma("unroll") for (int mt = 0; mt < 4; ++mt)                                      \
      _Pragma("unroll") for (int r = 0; r < 4; ++r) {                                     \
        p[mt][r] = exp2f(p[mt][r] - mn);                                                  \
        rs += p[mt][r];                                                                   \
      }                                                                                   \
    lst = lst * al + rs;                                                                  \
    _Pragma("unroll") for (int ct = 0; ct < 4; ++ct)                                      \
      _Pragma("unroll") for (int r = 0; r < 4; ++r) o[ct][r] *= al;                       \
    _Pragma("unroll") for (int mt = 0; mt < 4; ++mt) {                                    \
      ushortx4 uu;                                                                        \
      _Pragma("unroll") for (int r = 0; r < 4; ++r) uu[r] = f2bf_fast(p[mt][r]);          \
      int ch = (mt * 2 + (quad >> 1)) ^ (n16 & 7);                                        \
      *(ushortx4*)(&spW[n16 * 64 + ch * 8 + (quad & 1) * 4]) = uu;                        \
    }                                                                                     \
    __builtin_amdgcn_s_waitcnt(0xC07F); /* lgkmcnt(0); GLL prefetch stays in flight */    \
    bf16x8 aP0 = *(const bf16x8*)(&spW[n16 * 64 + ((quad ^ (n16 & 7)) * 8)]);             \
    bf16x8 aP1 = *(const bf16x8*)(&spW[n16 * 64 + (((4 + quad) ^ (n16 & 7)) * 8)]);       \
    _Pragma("unroll") for (int ct = 0; ct < 4; ++ct) {                                    \
      const unsigned short* vr = &vT_[(ct * 16 + n16) * 64];                              \
      bf16x8 va0 = *(const bf16x8*)(vr + ((quad ^ (n16 & 7)) * 8));                       \
      bf16x8 va1 = *(const bf16x8*)(vr + (((4 + quad) ^ (n16 & 7)) * 8));                 \
      o[ct] = __builtin_amdgcn_mfma_f32_16x16x32_bf16(va0, aP0, o[ct], 0, 0, 0);          \
      o[ct] = __builtin_amdgcn_mfma_f32_16x16x32_bf16(va1, aP1, o[ct], 0, 0, 0);          \
    }                                                                                     \
  } while (0)

  if (beg < end) ASTAGE(beg, 0);
  int it = 0;
  while (it < u) {
    __syncthreads();  // drains loads into buf0 (uniform: u is block-uniform)
    {
      int kt = beg + it;
      if (kt + 1 < end) ASTAGE(kt + 1, 1);
      if (kt < end) ACOMPUTE(kt, 0);
    }
    if (++it >= u) break;
    __syncthreads();  // drains loads into buf1
    {
      int kt = beg + it;
      if (kt + 1 < end) ASTAGE(kt + 1, 0);
      if (kt < end) ACOMPUTE(kt, 1);
    }
    ++it;
  }
#undef ASTAGE
#undef ACOMPUTE

  // finish lane-partial l (cross-quad k-partials)
  lst += __shfl_xor(lst, 16);
  lst += __shfl_xor(lst, 32);

  // merge the two split-k partials via LDS
  __syncthreads();
  float* scratch = (float*)sKV;  // 18 floats per (w4,lane); stride 18 -> 2-way banks (free)
  int sidx = (w4 * 64 + lane) * 18;
  if (g == 1) {
#pragma unroll
    for (int ct = 0; ct < 4; ++ct)
#pragma unroll
      for (int r = 0; r < 4; ++r) scratch[sidx + ct * 4 + r] = o[ct][r];
    scratch[sidx + 16] = mst;
    scratch[sidx + 17] = lst;
  }
  __syncthreads();
  if (g == 0) {
    float m1 = scratch[sidx + 16], l1 = scratch[sidx + 17];
    float m = fmaxf(mst, m1);
    float a0 = exp2f(mst - m), a1 = exp2f(m1 - m);
    float inv = 1.0f / (lst * a0 + l1 * a1);
#pragma unroll
    for (int ct = 0; ct < 4; ++ct) {
      ushortx4 uo;
#pragma unroll
      for (int r = 0; r < 4; ++r) {
        float v = (o[ct][r] * a0 + scratch[sidx + ct * 4 + r] * a1) * inv;
        uo[r] = f2bf(v);
      }
      size_t addr = ((size_t)b_ * 2048 + qg) * 1024 + h_ * 64 + ct * 16 + quad * 4;
      *(ushortx4*)(&O[addr]) = uo;
    }
  }
}

// ---------------- launch ----------------
extern "C" void kernel_launch(void* const* d_in, const int* in_sizes, int n_in,
                              void* d_out, int out_size, void* d_ws, size_t ws_size,
                              hipStream_t stream) {
  const float* X    = (const float*)d_in[0];
  const int*   pos  = (const int*)d_in[2];
  const float* cosb = (const float*)d_in[3];
  const float* sinb = (const float*)d_in[4];
  const float* Wq   = (const float*)d_in[5];
  const float* Wk   = (const float*)d_in[6];
  const float* Wv   = (const float*)d_in[7];
  const float* Wo   = (const float*)d_in[8];
  float* out = (float*)d_out;

  char* ws = (char*)d_ws;
  const size_t SZ_X = 4096UL * 1024 * 2;
  const size_t SZ_W = 1024UL * 1024 * 2;
  unsigned short* Xbf = (unsigned short*)(ws);
  unsigned short* WTq = (unsigned short*)(ws + SZ_X);
  unsigned short* WTk = (unsigned short*)(ws + SZ_X + SZ_W);
  unsigned short* WTv = (unsigned short*)(ws + SZ_X + 2 * SZ_W);
  unsigned short* WTo = (unsigned short*)(ws + SZ_X + 3 * SZ_W);
  unsigned short* Qbf = (unsigned short*)(ws + SZ_X + 4 * SZ_W);
  unsigned short* Kbf = (unsigned short*)(ws + 2 * SZ_X + 4 * SZ_W);
  unsigned short* Vbf = (unsigned short*)(ws + 3 * SZ_X + 4 * SZ_W);
  unsigned short* VTr = (unsigned short*)(ws + 4 * SZ_X + 4 * SZ_W);
  unsigned short* Obf = (unsigned short*)(ws + 5 * SZ_X + 4 * SZ_W);

  prep_kernel<<<dim3(32, 32, 6), dim3(32, 8), 0, stream>>>(
      X, Wq, Wk, Wv, Wo, Xbf, WTq, WTk, WTv, WTo);

  gemm128_kernel<1><<<dim3(8, 32, 3), 256, 0, stream>>>(Xbf, WTq, WTk, WTv,
                                                        nullptr, Qbf, Kbf, Vbf,
                                                        pos, cosb, sinb);

  tpose_kernel<<<dim3(2, 64, 32), dim3(32, 8), 0, stream>>>(Vbf, VTr, 2048, 64);

  attn_kernel<<<dim3(32, 32), 512, 0, stream>>>(Qbf, Kbf, VTr, Obf);

  gemm128_kernel<0><<<dim3(8, 32, 1), 256, 0, stream>>>(Obf, WTo, nullptr, nullptr,
                                                        out, nullptr, nullptr, nullptr,
                                                        nullptr, nullptr, nullptr);
}

// Round 8
// 220.145 us; speedup vs baseline: 1.8926x; 1.0447x over previous
//
#include <hip/hip_runtime.h>

typedef __bf16 bf16x8 __attribute__((ext_vector_type(8)));
typedef float  f32x4  __attribute__((ext_vector_type(4)));
typedef unsigned short ushortx8 __attribute__((ext_vector_type(8)));
typedef unsigned short ushortx4 __attribute__((ext_vector_type(4)));

static __device__ __forceinline__ unsigned short f2bf(float f) {
  unsigned int u = __builtin_bit_cast(unsigned int, f);
  u += 0x7FFFu + ((u >> 16) & 1u);
  return (unsigned short)(u >> 16);
}
static __device__ __forceinline__ unsigned short f2bf_fast(float f) {  // round-half-up
  unsigned int u = __builtin_bit_cast(unsigned int, f);
  return (unsigned short)((u + 0x8000u) >> 16);
}

#define GLL16(gp, lp) __builtin_amdgcn_global_load_lds(                       \
    (const __attribute__((address_space(1))) void*)(gp),                      \
    (__attribute__((address_space(3))) void*)(lp), 16, 0, 0)

// ---------------- prep: z<4 -> transpose+cast W; z>=4 -> cast X fp32->bf16 ----------------
__global__ __launch_bounds__(256) void prep_kernel(const float* __restrict__ X,
                                                   const float* __restrict__ W0,
                                                   const float* __restrict__ W1,
                                                   const float* __restrict__ W2,
                                                   const float* __restrict__ W3,
                                                   unsigned short* __restrict__ Xbf,
                                                   unsigned short* __restrict__ D0,
                                                   unsigned short* __restrict__ D1,
                                                   unsigned short* __restrict__ D2,
                                                   unsigned short* __restrict__ D3) {
  int z = blockIdx.z;
  if (z >= 4) {  // cast 4096x1024 fp32 -> bf16; z in {4,5}
    long bid = (long)(z - 4) * 1024 + blockIdx.y * 32 + blockIdx.x;
    int tl = threadIdx.y * 32 + threadIdx.x;
    long i = bid * 2048 + (long)tl * 8;
    float4 f0 = *(const float4*)(X + i);
    float4 f1 = *(const float4*)(X + i + 4);
    ushortx8 u;
    u[0] = f2bf(f0.x); u[1] = f2bf(f0.y); u[2] = f2bf(f0.z); u[3] = f2bf(f0.w);
    u[4] = f2bf(f1.x); u[5] = f2bf(f1.y); u[6] = f2bf(f1.z); u[7] = f2bf(f1.w);
    *(ushortx8*)(Xbf + i) = u;
    return;
  }
  const float* src = (z == 0) ? W0 : (z == 1) ? W1 : (z == 2) ? W2 : W3;
  unsigned short* dst = (z == 0) ? D0 : (z == 1) ? D1 : (z == 2) ? D2 : D3;
  const int R = 1024, C = 1024;
  __shared__ unsigned short t[32][33];
  int c = blockIdx.x * 32 + threadIdx.x;
#pragma unroll
  for (int i = 0; i < 4; ++i) {
    int r = blockIdx.y * 32 + threadIdx.y + i * 8;
    t[threadIdx.y + i * 8][threadIdx.x] = f2bf(src[(size_t)r * C + c]);
  }
  __syncthreads();
  int rr = blockIdx.y * 32 + threadIdx.x;
#pragma unroll
  for (int i = 0; i < 4; ++i) {
    int cc = blockIdx.x * 32 + threadIdx.y + i * 8;
    dst[(size_t)cc * R + rr] = t[threadIdx.x][threadIdx.y + i * 8];
  }
}

// ---------------- GEMM: 128x128 tile, BK=64, single-buffer staging, XOR-swizzled LDS ----
// Block remap: id m-fastest so xcd(id%8)=m_idx%8 -> all (n,z) blocks of an A-row share one
// XCD's L2; A fetched once per row instead of 8-24x (FETCH_SIZE was 110MB for 14MB inputs).
// MODE 1, z==2 writes V^T directly (fused transpose): acc rows are contiguous s.
template <int MODE>
__global__ __launch_bounds__(256) void gemm128_kernel(
    const unsigned short* __restrict__ A,
    const unsigned short* __restrict__ BT0,
    const unsigned short* __restrict__ BT1,
    const unsigned short* __restrict__ BT2,
    float* __restrict__ outF,
    unsigned short* __restrict__ outQ,
    unsigned short* __restrict__ outK,
    unsigned short* __restrict__ outVT,
    const int* __restrict__ pos_ids,
    const float* __restrict__ cosb,
    const float* __restrict__ sinb) {
  const int K = 1024, N = 1024;
  int id = blockIdx.x + 8 * (blockIdx.y + 32 * blockIdx.z);
  int m_idx = id & 31;         // m fastest => xcd = id%8 = m_idx%8
  int nzi = id >> 5;
  int n_idx = (MODE == 1) ? (nzi & 7) : nzi;
  int z = (MODE == 1) ? (nzi >> 3) : 0;
  const unsigned short* BT = (MODE == 0 || z == 0) ? BT0 : (z == 1 ? BT1 : BT2);
  int n0 = n_idx * 128, m0 = m_idx * 128;
  int t = threadIdx.x, lane = t & 63, w = t >> 6;
  int wy = w >> 1, wx = w & 1;
  int n16 = lane & 15, quad = lane >> 4;
  __shared__ __align__(16) unsigned short sA[128 * 64];
  __shared__ __align__(16) unsigned short sB[128 * 64];

  int r8 = lane >> 3, c8 = lane & 7;
  int srow = w * 32 + r8;
  const char* gA = (const char*)(A + (size_t)(m0 + srow) * K) + (c8 ^ r8) * 16;
  const char* gB = (const char*)(BT + (size_t)(n0 + srow) * K) + (c8 ^ r8) * 16;

  f32x4 acc[4][4];
#pragma unroll
  for (int i = 0; i < 4; ++i)
#pragma unroll
    for (int j = 0; j < 4; ++j) acc[i][j] = f32x4{0.f, 0.f, 0.f, 0.f};

  for (int kk = 0; kk < K; kk += 64) {
    __syncthreads();
#pragma unroll
    for (int i = 0; i < 4; ++i) {
      GLL16(gA + (size_t)kk * 2 + (size_t)i * 8 * K * 2, sA + (w * 32 + i * 8) * 64);
      GLL16(gB + (size_t)kk * 2 + (size_t)i * 8 * K * 2, sB + (w * 32 + i * 8) * 64);
    }
    __syncthreads();
#pragma unroll
    for (int kb = 0; kb < 2; ++kb) {
      bf16x8 a[4], b[4];
#pragma unroll
      for (int i = 0; i < 4; ++i) {
        int ra = wy * 64 + i * 16 + n16;
        int rb = wx * 64 + i * 16 + n16;
        int cs = ((kb * 4 + quad) ^ (n16 & 7)) * 8;
        a[i] = *(const bf16x8*)(&sA[ra * 64 + cs]);
        b[i] = *(const bf16x8*)(&sB[rb * 64 + cs]);
      }
#pragma unroll
      for (int mt = 0; mt < 4; ++mt)
#pragma unroll
        for (int nt = 0; nt < 4; ++nt)
          acc[mt][nt] = __builtin_amdgcn_mfma_f32_16x16x32_bf16(a[mt], b[nt], acc[mt][nt], 0, 0, 0);
    }
  }

  if (MODE == 1 && z < 2) {  // fused RoPE on Q/K
#pragma unroll
    for (int mt = 0; mt < 4; ++mt)
#pragma unroll
      for (int r = 0; r < 4; ++r) {
        int row = m0 + wy * 64 + mt * 16 + quad * 4 + r;
        int b = row >> 11, s = row & 2047;
        int pos = pos_ids[b * 2048 + s];
        const float* cb = cosb + (size_t)pos * 64;
        const float* sb = sinb + (size_t)pos * 64;
#pragma unroll
        for (int nt = 0; nt < 2; ++nt) {
          int d0 = nt * 16 + n16;
          float c0 = cb[d0], s0 = sb[d0], c1 = cb[d0 + 32], s1 = sb[d0 + 32];
          float x0 = acc[mt][nt][r], x1 = acc[mt][nt + 2][r];
          acc[mt][nt][r]     = x0 * c0 - x1 * s0;
          acc[mt][nt + 2][r] = x1 * c1 + x0 * s1;
        }
      }
  }

  if (MODE == 1 && z == 2) {
    // V^T fused write: VT[((b*16+h)*64+d)*2048 + s]; 4 consecutive s per lane -> 8B stores
#pragma unroll
    for (int mt = 0; mt < 4; ++mt)
#pragma unroll
      for (int nt = 0; nt < 4; ++nt) {
        int row = m0 + wy * 64 + mt * 16 + quad * 4;  // +r, stays within one b
        int b = row >> 11, s = row & 2047;
        int col = n0 + wx * 64 + nt * 16 + n16;
        int h = col >> 6, d = col & 63;
        ushortx4 u;
#pragma unroll
        for (int r = 0; r < 4; ++r) u[r] = f2bf(acc[mt][nt][r]);
        *(ushortx4*)(&outVT[(((size_t)b * 16 + h) * 64 + d) * 2048 + s]) = u;
      }
    return;
  }

#pragma unroll
  for (int mt = 0; mt < 4; ++mt)
#pragma unroll
    for (int nt = 0; nt < 4; ++nt)
#pragma unroll
      for (int r = 0; r < 4; ++r) {
        int row = m0 + wy * 64 + mt * 16 + quad * 4 + r;
        int col = n0 + wx * 64 + nt * 16 + n16;
        float v = acc[mt][nt][r];
        if (MODE == 0) {
          outF[(size_t)row * N + col] = v;
        } else {
          unsigned short* dst = (z == 0) ? outQ : outK;
          int b = row >> 11, s = row & 2047, h = col >> 6, d = col & 63;
          dst[(((size_t)b * 16 + h) * 2048 + s) * 64 + d] = f2bf(v);
        }
      }
}

// ---------------- Flash attention: in-block split-k (8 waves), S^T orientation ----
// Group g in {0,1}: k-tiles [0,u) / [u,nk), u=ceil(nk/2). Partials merged via LDS.
// Q,K bf16 [B*NH, S, 64]; VT bf16 [B*NH, 64, S]; O bf16 [B*S, NH*64]
__global__ __launch_bounds__(512) void attn_kernel(const unsigned short* __restrict__ Q,
                                                   const unsigned short* __restrict__ Kk,
                                                   const unsigned short* __restrict__ VT,
                                                   unsigned short* __restrict__ O) {
  int bh = blockIdx.x;
  int qt = (int)(gridDim.y - 1 - blockIdx.y);  // LPT
  int t = threadIdx.x;
  int lane = t & 63;
  int w = t >> 6;          // 0..7
  int g = w >> 2;          // split group
  int w4 = w & 3;          // wave within group
  int n16 = lane & 15, quad = lane >> 4;
  int r8 = lane >> 3, c8 = lane & 7;
  const unsigned short* Qb = Q + (size_t)bh * 2048 * 64;
  const unsigned short* Kb = Kk + (size_t)bh * 2048 * 64;
  const unsigned short* Vb = VT + (size_t)bh * 64 * 2048;

  __shared__ __align__(16) unsigned short sKV[2 * 2 * 2 * 4096];
  __shared__ __align__(16) unsigned short sP[8][16 * 64];
  unsigned short* spW = sP[w];
  unsigned short* gBase = sKV + g * 16384;

  const float SCL2 = 0.125f * 1.44269504088896340736f;  // SCALE * log2(e)
  int b_ = bh >> 4, h_ = bh & 15;
  int nk = qt + 1;
  int u = (nk + 1) >> 1;
  int beg = g ? u : 0;
  int end = g ? nk : u;
  int qg = qt * 64 + w4 * 16 + n16;  // this lane's q-row

  bf16x8 aQ[2];
#pragma unroll
  for (int kb = 0; kb < 2; ++kb)
    aQ[kb] = *(const bf16x8*)(Qb + (size_t)qg * 64 + kb * 32 + quad * 8);

  f32x4 o[4];
  float mst = -3e38f, lst = 0.f;
#pragma unroll
  for (int ct = 0; ct < 4; ++ct) o[ct] = f32x4{0.f, 0.f, 0.f, 0.f};

#define ASTAGE(kt_, BUF)                                                                  \
  do {                                                                                    \
    const unsigned short* kg_ = Kb + (size_t)((kt_) * 64 + w4 * 16) * 64;                 \
    const unsigned short* vg_ = Vb + (size_t)(w4 * 16) * 2048 + (kt_) * 64;               \
    unsigned short* dK = gBase + (BUF) * 8192 + (w4 * 16) * 64;                           \
    unsigned short* dV = dK + 4096;                                                       \
    GLL16(kg_ + (size_t)r8 * 64 + (c8 ^ r8) * 8, dK);                                     \
    GLL16(kg_ + (size_t)(8 + r8) * 64 + (c8 ^ r8) * 8, dK + 8 * 64);                      \
    GLL16(vg_ + (size_t)r8 * 2048 + (c8 ^ r8) * 8, dV);                                   \
    GLL16(vg_ + (size_t)(8 + r8) * 2048 + (c8 ^ r8) * 8, dV + 8 * 64);                    \
  } while (0)

#define ACOMPUTE(kt_, BUF)                                                                \
  do {                                                                                    \
    const unsigned short* kT_ = gBase + (BUF) * 8192;                                     \
    const unsigned short* vT_ = kT_ + 4096;                                               \
    f32x4 sc[4]; /* S^T: D[m=k][n=q], A=K-frag, B=Q-frag */                               \
    _Pragma("unroll") for (int mt = 0; mt < 4; ++mt) {                                    \
      const unsigned short* kr = &kT_[(mt * 16 + n16) * 64];                              \
      bf16x8 ka0 = *(const bf16x8*)(kr + ((quad ^ (n16 & 7)) * 8));                       \
      bf16x8 ka1 = *(const bf16x8*)(kr + (((4 + quad) ^ (n16 & 7)) * 8));                 \
      f32x4 zv = f32x4{0.f, 0.f, 0.f, 0.f};                                               \
      zv = __builtin_amdgcn_mfma_f32_16x16x32_bf16(ka0, aQ[0], zv, 0, 0, 0);              \
      sc[mt] = __builtin_amdgcn_mfma_f32_16x16x32_bf16(ka1, aQ[1], zv, 0, 0, 0);          \
    }                                                                                     \
    float p[4][4];                                                                        \
    _Pragma("unroll") for (int mt = 0; mt < 4; ++mt)                                      \
      _Pragma("unroll") for (int r = 0; r < 4; ++r) p[mt][r] = sc[mt][r] * SCL2;          \
    if ((kt_) == nk - 1) { /* diagonal tile: mask k > q */                                \
      int kb0 = (kt_) * 64 + quad * 4;                                                    \
      _Pragma("unroll") for (int mt = 0; mt < 4; ++mt)                                    \
        _Pragma("unroll") for (int r = 0; r < 4; ++r)                                     \
          if (kb0 + mt * 16 + r > qg) p[mt][r] = -3e38f;                                  \
    }                                                                                     \
    float rm = p[0][0];                                                                   \
    _Pragma("unroll") for (int mt = 0; mt < 4; ++mt)                                      \
      _Pragma("unroll") for (int r = 0; r < 4; ++r) rm = fmaxf(rm, p[mt][r]);             \
    rm = fmaxf(rm, __shfl_xor(rm, 16));                                                   \
    rm = fmaxf(rm, __shfl_xor(rm, 32));                                                   \
    float mn = fmaxf(mst, rm);                                                            \
    float al = exp2f(mst - mn);                                                           \
    mst = mn;                                                                             \
    float rs = 0.f;                                                                       \
    _Pragma("unroll") for (int mt = 0; mt < 4; ++mt)                                      \
      _Pragma("unroll") for (int r = 0; r < 4; ++r) {                                     \
        p[mt][r] = exp2f(p[mt][r] - mn);                                                  \
        rs += p[mt][r];                                                                   \
      }                                                                                   \
    lst = lst * al + rs;                                                                  \
    _Pragma("unroll") for (int ct = 0; ct < 4; ++ct)                                      \
      _Pragma("unroll") for (int r = 0; r < 4; ++r) o[ct][r] *= al;                       \
    _Pragma("unroll") for (int mt = 0; mt < 4; ++mt) {                                    \
      ushortx4 uu;                                                                        \
      _Pragma("unroll") for (int r = 0; r < 4; ++r) uu[r] = f2bf_fast(p[mt][r]);          \
      int ch = (mt * 2 + (quad >> 1)) ^ (n16 & 7);                                        \
      *(ushortx4*)(&spW[n16 * 64 + ch * 8 + (quad & 1) * 4]) = uu;                        \
    }                                                                                     \
    __builtin_amdgcn_s_waitcnt(0xC07F); /* lgkmcnt(0); GLL prefetch stays in flight */    \
    bf16x8 aP0 = *(const bf16x8*)(&spW[n16 * 64 + ((quad ^ (n16 & 7)) * 8)]);             \
    bf16x8 aP1 = *(const bf16x8*)(&spW[n16 * 64 + (((4 + quad) ^ (n16 & 7)) * 8)]);       \
    _Pragma("unroll") for (int ct = 0; ct < 4; ++ct) {                                    \
      const unsigned short* vr = &vT_[(ct * 16 + n16) * 64];                              \
      bf16x8 va0 = *(const bf16x8*)(vr + ((quad ^ (n16 & 7)) * 8));                       \
      bf16x8 va1 = *(const bf16x8*)(vr + (((4 + quad) ^ (n16 & 7)) * 8));                 \
      o[ct] = __builtin_amdgcn_mfma_f32_16x16x32_bf16(va0, aP0, o[ct], 0, 0, 0);          \
      o[ct] = __builtin_amdgcn_mfma_f32_16x16x32_bf16(va1, aP1, o[ct], 0, 0, 0);          \
    }                                                                                     \
  } while (0)

  if (beg < end) ASTAGE(beg, 0);
  int it = 0;
  while (it < u) {
    __syncthreads();  // drains loads into buf0 (u is block-uniform)
    {
      int kt = beg + it;
      if (kt + 1 < end) ASTAGE(kt + 1, 1);
      if (kt < end) ACOMPUTE(kt, 0);
    }
    if (++it >= u) break;
    __syncthreads();  // drains loads into buf1
    {
      int kt = beg + it;
      if (kt + 1 < end) ASTAGE(kt + 1, 0);
      if (kt < end) ACOMPUTE(kt, 1);
    }
    ++it;
  }
#undef ASTAGE
#undef ACOMPUTE

  // finish lane-partial l (cross-quad k-partials)
  lst += __shfl_xor(lst, 16);
  lst += __shfl_xor(lst, 32);

  // merge the two split-k partials via LDS
  __syncthreads();
  float* scratch = (float*)sKV;  // 18 floats per (w4,lane); stride 18 -> 2-way banks (free)
  int sidx = (w4 * 64 + lane) * 18;
  if (g == 1) {
#pragma unroll
    for (int ct = 0; ct < 4; ++ct)
#pragma unroll
      for (int r = 0; r < 4; ++r) scratch[sidx + ct * 4 + r] = o[ct][r];
    scratch[sidx + 16] = mst;
    scratch[sidx + 17] = lst;
  }
  __syncthreads();
  if (g == 0) {
    float m1 = scratch[sidx + 16], l1 = scratch[sidx + 17];
    float m = fmaxf(mst, m1);
    float a0 = exp2f(mst - m), a1 = exp2f(m1 - m);
    float inv = 1.0f / (lst * a0 + l1 * a1);
#pragma unroll
    for (int ct = 0; ct < 4; ++ct) {
      ushortx4 uo;
#pragma unroll
      for (int r = 0; r < 4; ++r) {
        float v = (o[ct][r] * a0 + scratch[sidx + ct * 4 + r] * a1) * inv;
        uo[r] = f2bf(v);
      }
      size_t addr = ((size_t)b_ * 2048 + qg) * 1024 + h_ * 64 + ct * 16 + quad * 4;
      *(ushortx4*)(&O[addr]) = uo;
    }
  }
}

// ---------------- launch ----------------
extern "C" void kernel_launch(void* const* d_in, const int* in_sizes, int n_in,
                              void* d_out, int out_size, void* d_ws, size_t ws_size,
                              hipStream_t stream) {
  const float* X    = (const float*)d_in[0];
  const int*   pos  = (const int*)d_in[2];
  const float* cosb = (const float*)d_in[3];
  const float* sinb = (const float*)d_in[4];
  const float* Wq   = (const float*)d_in[5];
  const float* Wk   = (const float*)d_in[6];
  const float* Wv   = (const float*)d_in[7];
  const float* Wo   = (const float*)d_in[8];
  float* out = (float*)d_out;

  char* ws = (char*)d_ws;
  const size_t SZ_X = 4096UL * 1024 * 2;
  const size_t SZ_W = 1024UL * 1024 * 2;
  unsigned short* Xbf = (unsigned short*)(ws);
  unsigned short* WTq = (unsigned short*)(ws + SZ_X);
  unsigned short* WTk = (unsigned short*)(ws + SZ_X + SZ_W);
  unsigned short* WTv = (unsigned short*)(ws + SZ_X + 2 * SZ_W);
  unsigned short* WTo = (unsigned short*)(ws + SZ_X + 3 * SZ_W);
  unsigned short* Qbf = (unsigned short*)(ws + SZ_X + 4 * SZ_W);
  unsigned short* Kbf = (unsigned short*)(ws + 2 * SZ_X + 4 * SZ_W);
  unsigned short* VTr = (unsigned short*)(ws + 3 * SZ_X + 4 * SZ_W);
  unsigned short* Obf = (unsigned short*)(ws + 4 * SZ_X + 4 * SZ_W);

  prep_kernel<<<dim3(32, 32, 6), dim3(32, 8), 0, stream>>>(
      X, Wq, Wk, Wv, Wo, Xbf, WTq, WTk, WTv, WTo);

  // QKV projections + fused RoPE + fused V-transpose (z: 0=Q,1=K,2=V^T)
  gemm128_kernel<1><<<dim3(8, 32, 3), 256, 0, stream>>>(Xbf, WTq, WTk, WTv,
                                                        nullptr, Qbf, Kbf, VTr,
                                                        pos, cosb, sinb);

  attn_kernel<<<dim3(32, 32), 512, 0, stream>>>(Qbf, Kbf, VTr, Obf);

  gemm128_kernel<0><<<dim3(8, 32, 1), 256, 0, stream>>>(Obf, WTo, nullptr, nullptr,
                                                        out, nullptr, nullptr, nullptr,
                                                        nullptr, nullptr, nullptr);
}

// Round 9
// 214.037 us; speedup vs baseline: 1.9467x; 1.0285x over previous
//
#include <hip/hip_runtime.h>

typedef __bf16 bf16x8 __attribute__((ext_vector_type(8)));
typedef float  f32x4  __attribute__((ext_vector_type(4)));
typedef unsigned short ushortx8 __attribute__((ext_vector_type(8)));
typedef unsigned short ushortx4 __attribute__((ext_vector_type(4)));

static __device__ __forceinline__ unsigned short f2bf(float f) {
  unsigned int u = __builtin_bit_cast(unsigned int, f);
  u += 0x7FFFu + ((u >> 16) & 1u);
  return (unsigned short)(u >> 16);
}
static __device__ __forceinline__ unsigned short f2bf_fast(float f) {  // round-half-up
  unsigned int u = __builtin_bit_cast(unsigned int, f);
  return (unsigned short)((u + 0x8000u) >> 16);
}

#define GLL16(gp, lp) __builtin_amdgcn_global_load_lds(                       \
    (const __attribute__((address_space(1))) void*)(gp),                      \
    (__attribute__((address_space(3))) void*)(lp), 16, 0, 0)

// ---------------- prep: z<4 -> transpose+cast W; z>=4 -> cast X fp32->bf16 ----------------
__global__ __launch_bounds__(256) void prep_kernel(const float* __restrict__ X,
                                                   const float* __restrict__ W0,
                                                   const float* __restrict__ W1,
                                                   const float* __restrict__ W2,
                                                   const float* __restrict__ W3,
                                                   unsigned short* __restrict__ Xbf,
                                                   unsigned short* __restrict__ D0,
                                                   unsigned short* __restrict__ D1,
                                                   unsigned short* __restrict__ D2,
                                                   unsigned short* __restrict__ D3) {
  int z = blockIdx.z;
  if (z >= 4) {  // cast 4096x1024 fp32 -> bf16; z in {4,5}
    long bid = (long)(z - 4) * 1024 + blockIdx.y * 32 + blockIdx.x;
    int tl = threadIdx.y * 32 + threadIdx.x;
    long i = bid * 2048 + (long)tl * 8;
    float4 f0 = *(const float4*)(X + i);
    float4 f1 = *(const float4*)(X + i + 4);
    ushortx8 u;
    u[0] = f2bf(f0.x); u[1] = f2bf(f0.y); u[2] = f2bf(f0.z); u[3] = f2bf(f0.w);
    u[4] = f2bf(f1.x); u[5] = f2bf(f1.y); u[6] = f2bf(f1.z); u[7] = f2bf(f1.w);
    *(ushortx8*)(Xbf + i) = u;
    return;
  }
  const float* src = (z == 0) ? W0 : (z == 1) ? W1 : (z == 2) ? W2 : W3;
  unsigned short* dst = (z == 0) ? D0 : (z == 1) ? D1 : (z == 2) ? D2 : D3;
  const int R = 1024, C = 1024;
  __shared__ unsigned short t[32][33];
  int c = blockIdx.x * 32 + threadIdx.x;
#pragma unroll
  for (int i = 0; i < 4; ++i) {
    int r = blockIdx.y * 32 + threadIdx.y + i * 8;
    t[threadIdx.y + i * 8][threadIdx.x] = f2bf(src[(size_t)r * C + c]);
  }
  __syncthreads();
  int rr = blockIdx.y * 32 + threadIdx.x;
#pragma unroll
  for (int i = 0; i < 4; ++i) {
    int cc = blockIdx.x * 32 + threadIdx.y + i * 8;
    dst[(size_t)cc * R + rr] = t[threadIdx.x][threadIdx.y + i * 8];
  }
}

// ---------------- GEMM: 128x128 tile, BK=32, static-dbuf async prefetch (attn-proven) ----
// 4x 8KB LDS buffers (32 KB total). Prefetch of tile k+1 issues after the barrier and
// completes during compute(k). XCD-aware remap: m fastest -> A-row stays on one XCD's L2.
// MODE 1, z==2 writes V^T directly (fused transpose).
template <int MODE>
__global__ __launch_bounds__(256) void gemm128_kernel(
    const unsigned short* __restrict__ A,
    const unsigned short* __restrict__ BT0,
    const unsigned short* __restrict__ BT1,
    const unsigned short* __restrict__ BT2,
    float* __restrict__ outF,
    unsigned short* __restrict__ outQ,
    unsigned short* __restrict__ outK,
    unsigned short* __restrict__ outVT,
    const int* __restrict__ pos_ids,
    const float* __restrict__ cosb,
    const float* __restrict__ sinb) {
  const int K = 1024, N = 1024;
  int id = blockIdx.x + 8 * (blockIdx.y + 32 * blockIdx.z);
  int m_idx = id & 31;         // m fastest => xcd = id%8 = m_idx%8
  int nzi = id >> 5;
  int n_idx = (MODE == 1) ? (nzi & 7) : nzi;
  int z = (MODE == 1) ? (nzi >> 3) : 0;
  const unsigned short* BT = (MODE == 0 || z == 0) ? BT0 : (z == 1 ? BT1 : BT2);
  int n0 = n_idx * 128, m0 = m_idx * 128;
  int t = threadIdx.x, lane = t & 63, w = t >> 6;
  int wy = w >> 1, wx = w & 1;
  int n16 = lane & 15, quad = lane >> 4;
  __shared__ __align__(16) unsigned short sA0[128 * 32];
  __shared__ __align__(16) unsigned short sA1[128 * 32];
  __shared__ __align__(16) unsigned short sB0[128 * 32];
  __shared__ __align__(16) unsigned short sB1[128 * 32];

  // staging: lane -> (row-in-16 = lane>>2, slot = lane&3); slot holds global chunk slot^(row&3)
  int r4 = lane >> 2, c4 = lane & 3;
  const char* gA = (const char*)(A + (size_t)(m0 + w * 32 + r4) * K) + ((c4 ^ (r4 & 3)) * 16);
  const char* gB = (const char*)(BT + (size_t)(n0 + w * 32 + r4) * K) + ((c4 ^ (r4 & 3)) * 16);
  const size_t row16 = (size_t)16 * K * 2;  // +16 rows in bytes

  f32x4 acc[4][4];
#pragma unroll
  for (int i = 0; i < 4; ++i)
#pragma unroll
    for (int j = 0; j < 4; ++j) acc[i][j] = f32x4{0.f, 0.f, 0.f, 0.f};

#define GSTAGE(kk_, SA, SB)                                                     \
  do {                                                                          \
    GLL16(gA + (size_t)(kk_) * 2, SA + (w * 32) * 32);                          \
    GLL16(gA + (size_t)(kk_) * 2 + row16, SA + (w * 32 + 16) * 32);             \
    GLL16(gB + (size_t)(kk_) * 2, SB + (w * 32) * 32);                          \
    GLL16(gB + (size_t)(kk_) * 2 + row16, SB + (w * 32 + 16) * 32);             \
  } while (0)

#define GCOMPUTE(SA, SB)                                                        \
  do {                                                                          \
    bf16x8 a[4], b[4];                                                          \
    int cs = (quad ^ (n16 & 3)) * 8;                                            \
    _Pragma("unroll") for (int i = 0; i < 4; ++i) {                             \
      a[i] = *(const bf16x8*)(&SA[(wy * 64 + i * 16 + n16) * 32 + cs]);         \
      b[i] = *(const bf16x8*)(&SB[(wx * 64 + i * 16 + n16) * 32 + cs]);         \
    }                                                                           \
    _Pragma("unroll") for (int mt = 0; mt < 4; ++mt)                            \
      _Pragma("unroll") for (int nt = 0; nt < 4; ++nt)                          \
        acc[mt][nt] = __builtin_amdgcn_mfma_f32_16x16x32_bf16(                  \
            a[mt], b[nt], acc[mt][nt], 0, 0, 0);                                \
  } while (0)

  GSTAGE(0, sA0, sB0);
  for (int kk = 0; kk < K;) {
    __syncthreads();  // drains loads into sA0/sB0 (prefetched during prior compute)
    if (kk + 32 < K) GSTAGE(kk + 32, sA1, sB1);
    GCOMPUTE(sA0, sB0);
    kk += 32;
    if (kk >= K) break;
    __syncthreads();  // drains loads into sA1/sB1
    if (kk + 32 < K) GSTAGE(kk + 32, sA0, sB0);
    GCOMPUTE(sA1, sB1);
    kk += 32;
  }
#undef GSTAGE
#undef GCOMPUTE

  if (MODE == 1 && z < 2) {  // fused RoPE on Q/K
#pragma unroll
    for (int mt = 0; mt < 4; ++mt)
#pragma unroll
      for (int r = 0; r < 4; ++r) {
        int row = m0 + wy * 64 + mt * 16 + quad * 4 + r;
        int b = row >> 11, s = row & 2047;
        int pos = pos_ids[b * 2048 + s];
        const float* cb = cosb + (size_t)pos * 64;
        const float* sb = sinb + (size_t)pos * 64;
#pragma unroll
        for (int nt = 0; nt < 2; ++nt) {
          int d0 = nt * 16 + n16;
          float c0 = cb[d0], s0 = sb[d0], c1 = cb[d0 + 32], s1 = sb[d0 + 32];
          float x0 = acc[mt][nt][r], x1 = acc[mt][nt + 2][r];
          acc[mt][nt][r]     = x0 * c0 - x1 * s0;
          acc[mt][nt + 2][r] = x1 * c1 + x0 * s1;
        }
      }
  }

  if (MODE == 1 && z == 2) {
    // V^T fused write: VT[((b*16+h)*64+d)*2048 + s]; 4 consecutive s per lane -> 8B stores
#pragma unroll
    for (int mt = 0; mt < 4; ++mt)
#pragma unroll
      for (int nt = 0; nt < 4; ++nt) {
        int row = m0 + wy * 64 + mt * 16 + quad * 4;  // +r, stays within one b
        int b = row >> 11, s = row & 2047;
        int col = n0 + wx * 64 + nt * 16 + n16;
        int h = col >> 6, d = col & 63;
        ushortx4 u;
#pragma unroll
        for (int r = 0; r < 4; ++r) u[r] = f2bf(acc[mt][nt][r]);
        *(ushortx4*)(&outVT[(((size_t)b * 16 + h) * 64 + d) * 2048 + s]) = u;
      }
    return;
  }

#pragma unroll
  for (int mt = 0; mt < 4; ++mt)
#pragma unroll
    for (int nt = 0; nt < 4; ++nt)
#pragma unroll
      for (int r = 0; r < 4; ++r) {
        int row = m0 + wy * 64 + mt * 16 + quad * 4 + r;
        int col = n0 + wx * 64 + nt * 16 + n16;
        float v = acc[mt][nt][r];
        if (MODE == 0) {
          outF[(size_t)row * N + col] = v;
        } else {
          unsigned short* dst = (z == 0) ? outQ : outK;
          int b = row >> 11, s = row & 2047, h = col >> 6, d = col & 63;
          dst[(((size_t)b * 16 + h) * 2048 + s) * 64 + d] = f2bf(v);
        }
      }
}

// ---------------- Flash attention: in-block split-k (8 waves), S^T orientation ----
// Group g in {0,1}: k-tiles [0,u) / [u,nk), u=ceil(nk/2). Partials merged via LDS.
// Q,K bf16 [B*NH, S, 64]; VT bf16 [B*NH, 64, S]; O bf16 [B*S, NH*64]
__global__ __launch_bounds__(512) void attn_kernel(const unsigned short* __restrict__ Q,
                                                   const unsigned short* __restrict__ Kk,
                                                   const unsigned short* __restrict__ VT,
                                                   unsigned short* __restrict__ O) {
  int bh = blockIdx.x;
  int qt = (int)(gridDim.y - 1 - blockIdx.y);  // LPT
  int t = threadIdx.x;
  int lane = t & 63;
  int w = t >> 6;          // 0..7
  int g = w >> 2;          // split group
  int w4 = w & 3;          // wave within group
  int n16 = lane & 15, quad = lane >> 4;
  int r8 = lane >> 3, c8 = lane & 7;
  const unsigned short* Qb = Q + (size_t)bh * 2048 * 64;
  const unsigned short* Kb = Kk + (size_t)bh * 2048 * 64;
  const unsigned short* Vb = VT + (size_t)bh * 64 * 2048;

  __shared__ __align__(16) unsigned short sKV[2 * 2 * 2 * 4096];
  __shared__ __align__(16) unsigned short sP[8][16 * 64];
  unsigned short* spW = sP[w];
  unsigned short* gBase = sKV + g * 16384;

  const float SCL2 = 0.125f * 1.44269504088896340736f;  // SCALE * log2(e)
  int b_ = bh >> 4, h_ = bh & 15;
  int nk = qt + 1;
  int u = (nk + 1) >> 1;
  int beg = g ? u : 0;
  int end = g ? nk : u;
  int qg = qt * 64 + w4 * 16 + n16;  // this lane's q-row

  bf16x8 aQ[2];
#pragma unroll
  for (int kb = 0; kb < 2; ++kb)
    aQ[kb] = *(const bf16x8*)(Qb + (size_t)qg * 64 + kb * 32 + quad * 8);

  f32x4 o[4];
  float mst = -3e38f, lst = 0.f;
#pragma unroll
  for (int ct = 0; ct < 4; ++ct) o[ct] = f32x4{0.f, 0.f, 0.f, 0.f};

#define ASTAGE(kt_, BUF)                                                                  \
  do {                                                                                    \
    const unsigned short* kg_ = Kb + (size_t)((kt_) * 64 + w4 * 16) * 64;                 \
    const unsigned short* vg_ = Vb + (size_t)(w4 * 16) * 2048 + (kt_) * 64;               \
    unsigned short* dK = gBase + (BUF) * 8192 + (w4 * 16) * 64;                           \
    unsigned short* dV = dK + 4096;                                                       \
    GLL16(kg_ + (size_t)r8 * 64 + (c8 ^ r8) * 8, dK);                                     \
    GLL16(kg_ + (size_t)(8 + r8) * 64 + (c8 ^ r8) * 8, dK + 8 * 64);                      \
    GLL16(vg_ + (size_t)r8 * 2048 + (c8 ^ r8) * 8, dV);                                   \
    GLL16(vg_ + (size_t)(8 + r8) * 2048 + (c8 ^ r8) * 8, dV + 8 * 64);                    \
  } while (0)

#define ACOMPUTE(kt_, BUF)                                                                \
  do {                                                                                    \
    const unsigned short* kT_ = gBase + (BUF) * 8192;                                     \
    const unsigned short* vT_ = kT_ + 4096;                                               \
    f32x4 sc[4]; /* S^T: D[m=k][n=q], A=K-frag, B=Q-frag */                               \
    _Pragma("unroll") for (int mt = 0; mt < 4; ++mt) {                                    \
      const unsigned short* kr = &kT_[(mt * 16 + n16) * 64];                              \
      bf16x8 ka0 = *(const bf16x8*)(kr + ((quad ^ (n16 & 7)) * 8));                       \
      bf16x8 ka1 = *(const bf16x8*)(kr + (((4 + quad) ^ (n16 & 7)) * 8));                 \
      f32x4 zv = f32x4{0.f, 0.f, 0.f, 0.f};                                               \
      zv = __builtin_amdgcn_mfma_f32_16x16x32_bf16(ka0, aQ[0], zv, 0, 0, 0);              \
      sc[mt] = __builtin_amdgcn_mfma_f32_16x16x32_bf16(ka1, aQ[1], zv, 0, 0, 0);          \
    }                                                                                     \
    float p[4][4];                                                                        \
    _Pragma("unroll") for (int mt = 0; mt < 4; ++mt)                                      \
      _Pragma("unroll") for (int r = 0; r < 4; ++r) p[mt][r] = sc[mt][r] * SCL2;          \
    if ((kt_) == nk - 1) { /* diagonal tile: mask k > q */                                \
      int kb0 = (kt_) * 64 + quad * 4;                                                    \
      _Pragma("unroll") for (int mt = 0; mt < 4; ++mt)                                    \
        _Pragma("unroll") for (int r = 0; r < 4; ++r)                                     \
          if (kb0 + mt * 16 + r > qg) p[mt][r] = -3e38f;                                  \
    }                                                                                     \
    float rm = p[0][0];                                                                   \
    _Pragma("unroll") for (int mt = 0; mt < 4; ++mt)                                      \
      _Pragma("unroll") for (int r = 0; r < 4; ++r) rm = fmaxf(rm, p[mt][r]);             \
    rm = fmaxf(rm, __shfl_xor(rm, 16));                                                   \
    rm = fmaxf(rm, __shfl_xor(rm, 32));                                                   \
    float mn = fmaxf(mst, rm);                                                            \
    float al = exp2f(mst - mn);                                                           \
    mst = mn;                                                                             \
    float rs = 0.f;                                                                       \
    _Pragma("unroll") for (int mt = 0; mt < 4; ++mt)                                      \
      _Pragma("unroll") for (int r = 0; r < 4; ++r) {                                     \
        p[mt][r] = exp2f(p[mt][r] - mn);                                                  \
        rs += p[mt][r];                                                                   \
      }                                                                                   \
    lst = lst * al + rs;                                                                  \
    _Pragma("unroll") for (int ct = 0; ct < 4; ++ct)                                      \
      _Pragma("unroll") for (int r = 0; r < 4; ++r) o[ct][r] *= al;                       \
    _Pragma("unroll") for (int mt = 0; mt < 4; ++mt) {                                    \
      ushortx4 uu;                                                                        \
      _Pragma("unroll") for (int r = 0; r < 4; ++r) uu[r] = f2bf_fast(p[mt][r]);          \
      int ch = (mt * 2 + (quad >> 1)) ^ (n16 & 7);                                        \
      *(ushortx4*)(&spW[n16 * 64 + ch * 8 + (quad & 1) * 4]) = uu;                        \
    }                                                                                     \
    __builtin_amdgcn_s_waitcnt(0xC07F); /* lgkmcnt(0); GLL prefetch stays in flight */    \
    bf16x8 aP0 = *(const bf16x8*)(&spW[n16 * 64 + ((quad ^ (n16 & 7)) * 8)]);             \
    bf16x8 aP1 = *(const bf16x8*)(&spW[n16 * 64 + (((4 + quad) ^ (n16 & 7)) * 8)]);       \
    _Pragma("unroll") for (int ct = 0; ct < 4; ++ct) {                                    \
      const unsigned short* vr = &vT_[(ct * 16 + n16) * 64];                              \
      bf16x8 va0 = *(const bf16x8*)(vr + ((quad ^ (n16 & 7)) * 8));                       \
      bf16x8 va1 = *(const bf16x8*)(vr + (((4 + quad) ^ (n16 & 7)) * 8));                 \
      o[ct] = __builtin_amdgcn_mfma_f32_16x16x32_bf16(va0, aP0, o[ct], 0, 0, 0);          \
      o[ct] = __builtin_amdgcn_mfma_f32_16x16x32_bf16(va1, aP1, o[ct], 0, 0, 0);          \
    }                                                                                     \
  } while (0)

  if (beg < end) ASTAGE(beg, 0);
  int it = 0;
  while (it < u) {
    __syncthreads();  // drains loads into buf0 (u is block-uniform)
    {
      int kt = beg + it;
      if (kt + 1 < end) ASTAGE(kt + 1, 1);
      if (kt < end) ACOMPUTE(kt, 0);
    }
    if (++it >= u) break;
    __syncthreads();  // drains loads into buf1
    {
      int kt = beg + it;
      if (kt + 1 < end) ASTAGE(kt + 1, 0);
      if (kt < end) ACOMPUTE(kt, 1);
    }
    ++it;
  }
#undef ASTAGE
#undef ACOMPUTE

  // finish lane-partial l (cross-quad k-partials)
  lst += __shfl_xor(lst, 16);
  lst += __shfl_xor(lst, 32);

  // merge the two split-k partials via LDS
  __syncthreads();
  float* scratch = (float*)sKV;  // 18 floats per (w4,lane); stride 18 -> 2-way banks (free)
  int sidx = (w4 * 64 + lane) * 18;
  if (g == 1) {
#pragma unroll
    for (int ct = 0; ct < 4; ++ct)
#pragma unroll
      for (int r = 0; r < 4; ++r) scratch[sidx + ct * 4 + r] = o[ct][r];
    scratch[sidx + 16] = mst;
    scratch[sidx + 17] = lst;
  }
  __syncthreads();
  if (g == 0) {
    float m1 = scratch[sidx + 16], l1 = scratch[sidx + 17];
    float m = fmaxf(mst, m1);
    float a0 = exp2f(mst - m), a1 = exp2f(m1 - m);
    float inv = 1.0f / (lst * a0 + l1 * a1);
#pragma unroll
    for (int ct = 0; ct < 4; ++ct) {
      ushortx4 uo;
#pragma unroll
      for (int r = 0; r < 4; ++r) {
        float v = (o[ct][r] * a0 + scratch[sidx + ct * 4 + r] * a1) * inv;
        uo[r] = f2bf(v);
      }
      size_t addr = ((size_t)b_ * 2048 + qg) * 1024 + h_ * 64 + ct * 16 + quad * 4;
      *(ushortx4*)(&O[addr]) = uo;
    }
  }
}

// ---------------- launch ----------------
extern "C" void kernel_launch(void* const* d_in, const int* in_sizes, int n_in,
                              void* d_out, int out_size, void* d_ws, size_t ws_size,
                              hipStream_t stream) {
  const float* X    = (const float*)d_in[0];
  const int*   pos  = (const int*)d_in[2];
  const float* cosb = (const float*)d_in[3];
  const float* sinb = (const float*)d_in[4];
  const float* Wq   = (const float*)d_in[5];
  const float* Wk   = (const float*)d_in[6];
  const float* Wv   = (const float*)d_in[7];
  const float* Wo   = (const float*)d_in[8];
  float* out = (float*)d_out;

  char* ws = (char*)d_ws;
  const size_t SZ_X = 4096UL * 1024 * 2;
  const size_t SZ_W = 1024UL * 1024 * 2;
  unsigned short* Xbf = (unsigned short*)(ws);
  unsigned short* WTq = (unsigned short*)(ws + SZ_X);
  unsigned short* WTk = (unsigned short*)(ws + SZ_X + SZ_W);
  unsigned short* WTv = (unsigned short*)(ws + SZ_X + 2 * SZ_W);
  unsigned short* WTo = (unsigned short*)(ws + SZ_X + 3 * SZ_W);
  unsigned short* Qbf = (unsigned short*)(ws + SZ_X + 4 * SZ_W);
  unsigned short* Kbf = (unsigned short*)(ws + 2 * SZ_X + 4 * SZ_W);
  unsigned short* VTr = (unsigned short*)(ws + 3 * SZ_X + 4 * SZ_W);
  unsigned short* Obf = (unsigned short*)(ws + 4 * SZ_X + 4 * SZ_W);

  prep_kernel<<<dim3(32, 32, 6), dim3(32, 8), 0, stream>>>(
      X, Wq, Wk, Wv, Wo, Xbf, WTq, WTk, WTv, WTo);

  // QKV projections + fused RoPE + fused V-transpose (z: 0=Q,1=K,2=V^T)
  gemm128_kernel<1><<<dim3(8, 32, 3), 256, 0, stream>>>(Xbf, WTq, WTk, WTv,
                                                        nullptr, Qbf, Kbf, VTr,
                                                        pos, cosb, sinb);

  attn_kernel<<<dim3(32, 32), 512, 0, stream>>>(Qbf, Kbf, VTr, Obf);

  gemm128_kernel<0><<<dim3(8, 32, 1), 256, 0, stream>>>(Obf, WTo, nullptr, nullptr,
                                                        out, nullptr, nullptr, nullptr,
                                                        nullptr, nullptr, nullptr);
}

// Round 10
// 208.907 us; speedup vs baseline: 1.9945x; 1.0246x over previous
//
#include <hip/hip_runtime.h>

typedef __bf16 bf16x8 __attribute__((ext_vector_type(8)));
typedef float  f32x4  __attribute__((ext_vector_type(4)));
typedef unsigned short ushortx8 __attribute__((ext_vector_type(8)));
typedef unsigned short ushortx4 __attribute__((ext_vector_type(4)));

static __device__ __forceinline__ unsigned short f2bf(float f) {
  unsigned int u = __builtin_bit_cast(unsigned int, f);
  u += 0x7FFFu + ((u >> 16) & 1u);
  return (unsigned short)(u >> 16);
}
static __device__ __forceinline__ unsigned short f2bf_fast(float f) {  // round-half-up
  unsigned int u = __builtin_bit_cast(unsigned int, f);
  return (unsigned short)((u + 0x8000u) >> 16);
}

#define GLL16(gp, lp) __builtin_amdgcn_global_load_lds(                       \
    (const __attribute__((address_space(1))) void*)(gp),                      \
    (__attribute__((address_space(3))) void*)(lp), 16, 0, 0)

// ---------------- prep: z<4 -> transpose+cast W; z>=4 -> cast X fp32->bf16 ----------------
__global__ __launch_bounds__(256) void prep_kernel(const float* __restrict__ X,
                                                   const float* __restrict__ W0,
                                                   const float* __restrict__ W1,
                                                   const float* __restrict__ W2,
                                                   const float* __restrict__ W3,
                                                   unsigned short* __restrict__ Xbf,
                                                   unsigned short* __restrict__ D0,
                                                   unsigned short* __restrict__ D1,
                                                   unsigned short* __restrict__ D2,
                                                   unsigned short* __restrict__ D3) {
  int z = blockIdx.z;
  if (z >= 4) {  // cast 4096x1024 fp32 -> bf16; z in {4,5}
    long bid = (long)(z - 4) * 1024 + blockIdx.y * 32 + blockIdx.x;
    int tl = threadIdx.y * 32 + threadIdx.x;
    long i = bid * 2048 + (long)tl * 8;
    float4 f0 = *(const float4*)(X + i);
    float4 f1 = *(const float4*)(X + i + 4);
    ushortx8 u;
    u[0] = f2bf(f0.x); u[1] = f2bf(f0.y); u[2] = f2bf(f0.z); u[3] = f2bf(f0.w);
    u[4] = f2bf(f1.x); u[5] = f2bf(f1.y); u[6] = f2bf(f1.z); u[7] = f2bf(f1.w);
    *(ushortx8*)(Xbf + i) = u;
    return;
  }
  const float* src = (z == 0) ? W0 : (z == 1) ? W1 : (z == 2) ? W2 : W3;
  unsigned short* dst = (z == 0) ? D0 : (z == 1) ? D1 : (z == 2) ? D2 : D3;
  const int R = 1024, C = 1024;
  __shared__ unsigned short t[32][33];
  int c = blockIdx.x * 32 + threadIdx.x;
#pragma unroll
  for (int i = 0; i < 4; ++i) {
    int r = blockIdx.y * 32 + threadIdx.y + i * 8;
    t[threadIdx.y + i * 8][threadIdx.x] = f2bf(src[(size_t)r * C + c]);
  }
  __syncthreads();
  int rr = blockIdx.y * 32 + threadIdx.x;
#pragma unroll
  for (int i = 0; i < 4; ++i) {
    int cc = blockIdx.x * 32 + threadIdx.y + i * 8;
    dst[(size_t)cc * R + rr] = t[threadIdx.x][threadIdx.y + i * 8];
  }
}

// ---------------- QKV GEMM: 128x128 tile, BK=32, static-dbuf async prefetch ----
// XCD remap (m fastest). z: 0=Q (RoPE, pre-scaled by SCALE*log2e), 1=K (RoPE), 2=V^T (fused tpose).
__global__ __launch_bounds__(256) void gemm128_kernel(
    const unsigned short* __restrict__ A,
    const unsigned short* __restrict__ BT0,
    const unsigned short* __restrict__ BT1,
    const unsigned short* __restrict__ BT2,
    unsigned short* __restrict__ outQ,
    unsigned short* __restrict__ outK,
    unsigned short* __restrict__ outVT,
    const int* __restrict__ pos_ids,
    const float* __restrict__ cosb,
    const float* __restrict__ sinb) {
  const int K = 1024;
  int id = blockIdx.x + 8 * (blockIdx.y + 32 * blockIdx.z);
  int m_idx = id & 31;         // m fastest => xcd = id%8 = m_idx%8
  int nzi = id >> 5;
  int n_idx = nzi & 7;
  int z = nzi >> 3;
  const unsigned short* BT = (z == 0) ? BT0 : (z == 1 ? BT1 : BT2);
  int n0 = n_idx * 128, m0 = m_idx * 128;
  int t = threadIdx.x, lane = t & 63, w = t >> 6;
  int wy = w >> 1, wx = w & 1;
  int n16 = lane & 15, quad = lane >> 4;
  __shared__ __align__(16) unsigned short sA0[128 * 32];
  __shared__ __align__(16) unsigned short sA1[128 * 32];
  __shared__ __align__(16) unsigned short sB0[128 * 32];
  __shared__ __align__(16) unsigned short sB1[128 * 32];

  int r4 = lane >> 2, c4 = lane & 3;
  const char* gA = (const char*)(A + (size_t)(m0 + w * 32 + r4) * K) + ((c4 ^ (r4 & 3)) * 16);
  const char* gB = (const char*)(BT + (size_t)(n0 + w * 32 + r4) * K) + ((c4 ^ (r4 & 3)) * 16);
  const size_t row16 = (size_t)16 * K * 2;

  f32x4 acc[4][4];
#pragma unroll
  for (int i = 0; i < 4; ++i)
#pragma unroll
    for (int j = 0; j < 4; ++j) acc[i][j] = f32x4{0.f, 0.f, 0.f, 0.f};

#define GSTAGE(kk_, SA, SB)                                                     \
  do {                                                                          \
    GLL16(gA + (size_t)(kk_) * 2, SA + (w * 32) * 32);                          \
    GLL16(gA + (size_t)(kk_) * 2 + row16, SA + (w * 32 + 16) * 32);             \
    GLL16(gB + (size_t)(kk_) * 2, SB + (w * 32) * 32);                          \
    GLL16(gB + (size_t)(kk_) * 2 + row16, SB + (w * 32 + 16) * 32);             \
  } while (0)

#define GCOMPUTE(SA, SB)                                                        \
  do {                                                                          \
    bf16x8 a[4], b[4];                                                          \
    int cs = (quad ^ (n16 & 3)) * 8;                                            \
    _Pragma("unroll") for (int i = 0; i < 4; ++i) {                             \
      a[i] = *(const bf16x8*)(&SA[(wy * 64 + i * 16 + n16) * 32 + cs]);         \
      b[i] = *(const bf16x8*)(&SB[(wx * 64 + i * 16 + n16) * 32 + cs]);         \
    }                                                                           \
    _Pragma("unroll") for (int mt = 0; mt < 4; ++mt)                            \
      _Pragma("unroll") for (int nt = 0; nt < 4; ++nt)                          \
        acc[mt][nt] = __builtin_amdgcn_mfma_f32_16x16x32_bf16(                  \
            a[mt], b[nt], acc[mt][nt], 0, 0, 0);                                \
  } while (0)

  GSTAGE(0, sA0, sB0);
  for (int kk = 0; kk < K;) {
    __syncthreads();
    if (kk + 32 < K) GSTAGE(kk + 32, sA1, sB1);
    GCOMPUTE(sA0, sB0);
    kk += 32;
    if (kk >= K) break;
    __syncthreads();
    if (kk + 32 < K) GSTAGE(kk + 32, sA0, sB0);
    GCOMPUTE(sA1, sB1);
    kk += 32;
  }
#undef GSTAGE
#undef GCOMPUTE

  if (z < 2) {  // fused RoPE on Q/K; Q additionally pre-scaled by SCALE*log2(e)
    const float qs = (z == 0) ? (0.125f * 1.44269504088896340736f) : 1.0f;
#pragma unroll
    for (int mt = 0; mt < 4; ++mt)
#pragma unroll
      for (int r = 0; r < 4; ++r) {
        int row = m0 + wy * 64 + mt * 16 + quad * 4 + r;
        int b = row >> 11, s = row & 2047;
        int pos = pos_ids[b * 2048 + s];
        const float* cb = cosb + (size_t)pos * 64;
        const float* sb = sinb + (size_t)pos * 64;
#pragma unroll
        for (int nt = 0; nt < 2; ++nt) {
          int d0 = nt * 16 + n16;
          float c0 = cb[d0] * qs, s0 = sb[d0] * qs;
          float c1 = cb[d0 + 32] * qs, s1 = sb[d0 + 32] * qs;
          float x0 = acc[mt][nt][r], x1 = acc[mt][nt + 2][r];
          acc[mt][nt][r]     = x0 * c0 - x1 * s0;
          acc[mt][nt + 2][r] = x1 * c1 + x0 * s1;
        }
      }
  }

  if (z == 2) {
    // V^T fused write: VT[((b*16+h)*64+d)*2048 + s]; 4 consecutive s per lane -> 8B stores
#pragma unroll
    for (int mt = 0; mt < 4; ++mt)
#pragma unroll
      for (int nt = 0; nt < 4; ++nt) {
        int row = m0 + wy * 64 + mt * 16 + quad * 4;  // +r, stays within one b
        int b = row >> 11, s = row & 2047;
        int col = n0 + wx * 64 + nt * 16 + n16;
        int h = col >> 6, d = col & 63;
        ushortx4 u;
#pragma unroll
        for (int r = 0; r < 4; ++r) u[r] = f2bf(acc[mt][nt][r]);
        *(ushortx4*)(&outVT[(((size_t)b * 16 + h) * 64 + d) * 2048 + s]) = u;
      }
    return;
  }

#pragma unroll
  for (int mt = 0; mt < 4; ++mt)
#pragma unroll
    for (int nt = 0; nt < 4; ++nt)
#pragma unroll
      for (int r = 0; r < 4; ++r) {
        int row = m0 + wy * 64 + mt * 16 + quad * 4 + r;
        int col = n0 + wx * 64 + nt * 16 + n16;
        unsigned short* dst = (z == 0) ? outQ : outK;
        int b = row >> 11, s = row & 2047, h = col >> 6, d = col & 63;
        dst[(((size_t)b * 16 + h) * 2048 + s) * 64 + d] = f2bf(acc[mt][nt][r]);
      }
}

// ---------------- Wo GEMM: 64x64 tile -> 1024 blocks (4/CU), BK=32 static-dbuf ----
// grid dim3(64,16): id = bx + 64*by -> xcd = id%8 = m_idx%8 (all n share the m-row's XCD).
__global__ __launch_bounds__(256) void gemm64_kernel(const unsigned short* __restrict__ A,
                                                     const unsigned short* __restrict__ BT,
                                                     float* __restrict__ outF) {
  const int K = 1024, N = 1024;
  int m0 = blockIdx.x * 64, n0 = blockIdx.y * 64;
  int t = threadIdx.x, lane = t & 63, w = t >> 6;
  int wy = w >> 1, wx = w & 1;
  int n16 = lane & 15, quad = lane >> 4;
  __shared__ __align__(16) unsigned short sA0[64 * 32];
  __shared__ __align__(16) unsigned short sA1[64 * 32];
  __shared__ __align__(16) unsigned short sB0[64 * 32];
  __shared__ __align__(16) unsigned short sB1[64 * 32];

  int r4 = lane >> 2, c4 = lane & 3;
  const char* gA = (const char*)(A + (size_t)(m0 + w * 16 + r4) * K) + ((c4 ^ (r4 & 3)) * 16);
  const char* gB = (const char*)(BT + (size_t)(n0 + w * 16 + r4) * K) + ((c4 ^ (r4 & 3)) * 16);

  f32x4 acc[2][2];
#pragma unroll
  for (int i = 0; i < 2; ++i)
#pragma unroll
    for (int j = 0; j < 2; ++j) acc[i][j] = f32x4{0.f, 0.f, 0.f, 0.f};

#define WSTAGE(kk_, SA, SB)                                                     \
  do {                                                                          \
    GLL16(gA + (size_t)(kk_) * 2, SA + (w * 16) * 32);                          \
    GLL16(gB + (size_t)(kk_) * 2, SB + (w * 16) * 32);                          \
  } while (0)

#define WCOMPUTE(SA, SB)                                                        \
  do {                                                                          \
    int cs = (quad ^ (n16 & 3)) * 8;                                            \
    bf16x8 a0 = *(const bf16x8*)(&SA[(wy * 32 + n16) * 32 + cs]);               \
    bf16x8 a1 = *(const bf16x8*)(&SA[(wy * 32 + 16 + n16) * 32 + cs]);          \
    bf16x8 b0 = *(const bf16x8*)(&SB[(wx * 32 + n16) * 32 + cs]);               \
    bf16x8 b1 = *(const bf16x8*)(&SB[(wx * 32 + 16 + n16) * 32 + cs]);          \
    acc[0][0] = __builtin_amdgcn_mfma_f32_16x16x32_bf16(a0, b0, acc[0][0], 0, 0, 0); \
    acc[0][1] = __builtin_amdgcn_mfma_f32_16x16x32_bf16(a0, b1, acc[0][1], 0, 0, 0); \
    acc[1][0] = __builtin_amdgcn_mfma_f32_16x16x32_bf16(a1, b0, acc[1][0], 0, 0, 0); \
    acc[1][1] = __builtin_amdgcn_mfma_f32_16x16x32_bf16(a1, b1, acc[1][1], 0, 0, 0); \
  } while (0)

  WSTAGE(0, sA0, sB0);
  for (int kk = 0; kk < K;) {
    __syncthreads();
    if (kk + 32 < K) WSTAGE(kk + 32, sA1, sB1);
    WCOMPUTE(sA0, sB0);
    kk += 32;
    if (kk >= K) break;
    __syncthreads();
    if (kk + 32 < K) WSTAGE(kk + 32, sA0, sB0);
    WCOMPUTE(sA1, sB1);
    kk += 32;
  }
#undef WSTAGE
#undef WCOMPUTE

#pragma unroll
  for (int mt = 0; mt < 2; ++mt)
#pragma unroll
    for (int nt = 0; nt < 2; ++nt)
#pragma unroll
      for (int r = 0; r < 4; ++r) {
        int row = m0 + wy * 32 + mt * 16 + quad * 4 + r;
        int col = n0 + wx * 32 + nt * 16 + n16;
        outF[(size_t)row * N + col] = acc[mt][nt][r];
      }
}

// ---------------- Flash attention: in-block split-k (8 waves), S^T orientation ----
// Q pre-scaled by SCALE*log2e in the QKV epilogue -> scores are already exp2-domain.
__global__ __launch_bounds__(512) void attn_kernel(const unsigned short* __restrict__ Q,
                                                   const unsigned short* __restrict__ Kk,
                                                   const unsigned short* __restrict__ VT,
                                                   unsigned short* __restrict__ O) {
  int bh = blockIdx.x;
  int qt = (int)(gridDim.y - 1 - blockIdx.y);  // LPT
  int t = threadIdx.x;
  int lane = t & 63;
  int w = t >> 6;          // 0..7
  int g = w >> 2;          // split group
  int w4 = w & 3;          // wave within group
  int n16 = lane & 15, quad = lane >> 4;
  int r8 = lane >> 3, c8 = lane & 7;
  const unsigned short* Qb = Q + (size_t)bh * 2048 * 64;
  const unsigned short* Kb = Kk + (size_t)bh * 2048 * 64;
  const unsigned short* Vb = VT + (size_t)bh * 64 * 2048;

  __shared__ __align__(16) unsigned short sKV[2 * 2 * 2 * 4096];
  __shared__ __align__(16) unsigned short sP[8][16 * 64];
  unsigned short* spW = sP[w];
  unsigned short* gBase = sKV + g * 16384;

  int b_ = bh >> 4, h_ = bh & 15;
  int nk = qt + 1;
  int u = (nk + 1) >> 1;
  int beg = g ? u : 0;
  int end = g ? nk : u;
  int qg = qt * 64 + w4 * 16 + n16;  // this lane's q-row

  bf16x8 aQ[2];
#pragma unroll
  for (int kb = 0; kb < 2; ++kb)
    aQ[kb] = *(const bf16x8*)(Qb + (size_t)qg * 64 + kb * 32 + quad * 8);

  f32x4 o[4];
  float mst = -3e38f, lst = 0.f;
#pragma unroll
  for (int ct = 0; ct < 4; ++ct) o[ct] = f32x4{0.f, 0.f, 0.f, 0.f};

#define ASTAGE(kt_, BUF)                                                                  \
  do {                                                                                    \
    const unsigned short* kg_ = Kb + (size_t)((kt_) * 64 + w4 * 16) * 64;                 \
    const unsigned short* vg_ = Vb + (size_t)(w4 * 16) * 2048 + (kt_) * 64;               \
    unsigned short* dK = gBase + (BUF) * 8192 + (w4 * 16) * 64;                           \
    unsigned short* dV = dK + 4096;                                                       \
    GLL16(kg_ + (size_t)r8 * 64 + (c8 ^ r8) * 8, dK);                                     \
    GLL16(kg_ + (size_t)(8 + r8) * 64 + (c8 ^ r8) * 8, dK + 8 * 64);                      \
    GLL16(vg_ + (size_t)r8 * 2048 + (c8 ^ r8) * 8, dV);                                   \
    GLL16(vg_ + (size_t)(8 + r8) * 2048 + (c8 ^ r8) * 8, dV + 8 * 64);                    \
  } while (0)

#define ACOMPUTE(kt_, BUF)                                                                \
  do {                                                                                    \
    const unsigned short* kT_ = gBase + (BUF) * 8192;                                     \
    const unsigned short* vT_ = kT_ + 4096;                                               \
    f32x4 sc[4]; /* S^T: D[m=k][n=q], A=K-frag, B=Q-frag */                               \
    _Pragma("unroll") for (int mt = 0; mt < 4; ++mt) {                                    \
      const unsigned short* kr = &kT_[(mt * 16 + n16) * 64];                              \
      bf16x8 ka0 = *(const bf16x8*)(kr + ((quad ^ (n16 & 7)) * 8));                       \
      bf16x8 ka1 = *(const bf16x8*)(kr + (((4 + quad) ^ (n16 & 7)) * 8));                 \
      f32x4 zv = f32x4{0.f, 0.f, 0.f, 0.f};                                               \
      zv = __builtin_amdgcn_mfma_f32_16x16x32_bf16(ka0, aQ[0], zv, 0, 0, 0);              \
      sc[mt] = __builtin_amdgcn_mfma_f32_16x16x32_bf16(ka1, aQ[1], zv, 0, 0, 0);          \
    }                                                                                     \
    float p[4][4];                                                                        \
    _Pragma("unroll") for (int mt = 0; mt < 4; ++mt)                                      \
      _Pragma("unroll") for (int r = 0; r < 4; ++r) p[mt][r] = sc[mt][r];                 \
    if ((kt_) == nk - 1) { /* diagonal tile: mask k > q */                                \
      int kb0 = (kt_) * 64 + quad * 4;                                                    \
      _Pragma("unroll") for (int mt = 0; mt < 4; ++mt)                                    \
        _Pragma("unroll") for (int r = 0; r < 4; ++r)                                     \
          if (kb0 + mt * 16 + r > qg) p[mt][r] = -3e38f;                                  \
    }                                                                                     \
    float rm = p[0][0];                                                                   \
    _Pragma("unroll") for (int mt = 0; mt < 4; ++mt)                                      \
      _Pragma("unroll") for (int r = 0; r < 4; ++r) rm = fmaxf(rm, p[mt][r]);             \
    rm = fmaxf(rm, __shfl_xor(rm, 16));                                                   \
    rm = fmaxf(rm, __shfl_xor(rm, 32));                                                   \
    float mn = fmaxf(mst, rm);                                                            \
    float al = exp2f(mst - mn);                                                           \
    mst = mn;                                                                             \
    float rs = 0.f;                                                                       \
    _Pragma("unroll") for (int mt = 0; mt < 4; ++mt)                                      \
      _Pragma("unroll") for (int r = 0; r < 4; ++r) {                                     \
        p[mt][r] = exp2f(p[mt][r] - mn);                                                  \
        rs += p[mt][r];                                                                   \
      }                                                                                   \
    lst = lst * al + rs;                                                                  \
    _Pragma("unroll") for (int ct = 0; ct < 4; ++ct)                                      \
      _Pragma("unroll") for (int r = 0; r < 4; ++r) o[ct][r] *= al;                       \
    _Pragma("unroll") for (int mt = 0; mt < 4; ++mt) {                                    \
      ushortx4 uu;                                                                        \
      _Pragma("unroll") for (int r = 0; r < 4; ++r) uu[r] = f2bf_fast(p[mt][r]);          \
      int ch = (mt * 2 + (quad >> 1)) ^ (n16 & 7);                                        \
      *(ushortx4*)(&spW[n16 * 64 + ch * 8 + (quad & 1) * 4]) = uu;                        \
    }                                                                                     \
    __builtin_amdgcn_s_waitcnt(0xC07F); /* lgkmcnt(0); GLL prefetch stays in flight */    \
    bf16x8 aP0 = *(const bf16x8*)(&spW[n16 * 64 + ((quad ^ (n16 & 7)) * 8)]);             \
    bf16x8 aP1 = *(const bf16x8*)(&spW[n16 * 64 + (((4 + quad) ^ (n16 & 7)) * 8)]);       \
    _Pragma("unroll") for (int ct = 0; ct < 4; ++ct) {                                    \
      const unsigned short* vr = &vT_[(ct * 16 + n16) * 64];                              \
      bf16x8 va0 = *(const bf16x8*)(vr + ((quad ^ (n16 & 7)) * 8));                       \
      bf16x8 va1 = *(const bf16x8*)(vr + (((4 + quad) ^ (n16 & 7)) * 8));                 \
      o[ct] = __builtin_amdgcn_mfma_f32_16x16x32_bf16(va0, aP0, o[ct], 0, 0, 0);          \
      o[ct] = __builtin_amdgcn_mfma_f32_16x16x32_bf16(va1, aP1, o[ct], 0, 0, 0);          \
    }                                                                                     \
  } while (0)

  if (beg < end) ASTAGE(beg, 0);
  int it = 0;
  while (it < u) {
    __syncthreads();  // drains loads into buf0 (u is block-uniform)
    {
      int kt = beg + it;
      if (kt + 1 < end) ASTAGE(kt + 1, 1);
      if (kt < end) ACOMPUTE(kt, 0);
    }
    if (++it >= u) break;
    __syncthreads();  // drains loads into buf1
    {
      int kt = beg + it;
      if (kt + 1 < end) ASTAGE(kt + 1, 0);
      if (kt < end) ACOMPUTE(kt, 1);
    }
    ++it;
  }
#undef ASTAGE
#undef ACOMPUTE

  // finish lane-partial l (cross-quad k-partials)
  lst += __shfl_xor(lst, 16);
  lst += __shfl_xor(lst, 32);

  // merge the two split-k partials via LDS
  __syncthreads();
  float* scratch = (float*)sKV;  // 18 floats per (w4,lane); stride 18 -> 2-way banks (free)
  int sidx = (w4 * 64 + lane) * 18;
  if (g == 1) {
#pragma unroll
    for (int ct = 0; ct < 4; ++ct)
#pragma unroll
      for (int r = 0; r < 4; ++r) scratch[sidx + ct * 4 + r] = o[ct][r];
    scratch[sidx + 16] = mst;
    scratch[sidx + 17] = lst;
  }
  __syncthreads();
  if (g == 0) {
    float m1 = scratch[sidx + 16], l1 = scratch[sidx + 17];
    float m = fmaxf(mst, m1);
    float a0 = exp2f(mst - m), a1 = exp2f(m1 - m);
    float inv = 1.0f / (lst * a0 + l1 * a1);
#pragma unroll
    for (int ct = 0; ct < 4; ++ct) {
      ushortx4 uo;
#pragma unroll
      for (int r = 0; r < 4; ++r) {
        float v = (o[ct][r] * a0 + scratch[sidx + ct * 4 + r] * a1) * inv;
        uo[r] = f2bf(v);
      }
      size_t addr = ((size_t)b_ * 2048 + qg) * 1024 + h_ * 64 + ct * 16 + quad * 4;
      *(ushortx4*)(&O[addr]) = uo;
    }
  }
}

// ---------------- launch ----------------
extern "C" void kernel_launch(void* const* d_in, const int* in_sizes, int n_in,
                              void* d_out, int out_size, void* d_ws, size_t ws_size,
                              hipStream_t stream) {
  const float* X    = (const float*)d_in[0];
  const int*   pos  = (const int*)d_in[2];
  const float* cosb = (const float*)d_in[3];
  const float* sinb = (const float*)d_in[4];
  const float* Wq   = (const float*)d_in[5];
  const float* Wk   = (const float*)d_in[6];
  const float* Wv   = (const float*)d_in[7];
  const float* Wo   = (const float*)d_in[8];
  float* out = (float*)d_out;

  char* ws = (char*)d_ws;
  const size_t SZ_X = 4096UL * 1024 * 2;
  const size_t SZ_W = 1024UL * 1024 * 2;
  unsigned short* Xbf = (unsigned short*)(ws);
  unsigned short* WTq = (unsigned short*)(ws + SZ_X);
  unsigned short* WTk = (unsigned short*)(ws + SZ_X + SZ_W);
  unsigned short* WTv = (unsigned short*)(ws + SZ_X + 2 * SZ_W);
  unsigned short* WTo = (unsigned short*)(ws + SZ_X + 3 * SZ_W);
  unsigned short* Qbf = (unsigned short*)(ws + SZ_X + 4 * SZ_W);
  unsigned short* Kbf = (unsigned short*)(ws + 2 * SZ_X + 4 * SZ_W);
  unsigned short* VTr = (unsigned short*)(ws + 3 * SZ_X + 4 * SZ_W);
  unsigned short* Obf = (unsigned short*)(ws + 4 * SZ_X + 4 * SZ_W);

  prep_kernel<<<dim3(32, 32, 6), dim3(32, 8), 0, stream>>>(
      X, Wq, Wk, Wv, Wo, Xbf, WTq, WTk, WTv, WTo);

  // QKV projections + fused RoPE (Q pre-scaled) + fused V-transpose
  gemm128_kernel<<<dim3(8, 32, 3), 256, 0, stream>>>(Xbf, WTq, WTk, WTv,
                                                     Qbf, Kbf, VTr,
                                                     pos, cosb, sinb);

  attn_kernel<<<dim3(32, 32), 512, 0, stream>>>(Qbf, Kbf, VTr, Obf);

  gemm64_kernel<<<dim3(64, 16), 256, 0, stream>>>(Obf, WTo, out);
}